// Round 6
// baseline (329.115 us; speedup 1.0000x reference)
//
#include <hip/hip_runtime.h>

#define K49 49

// ============ dense (z @ W + b) + relu -> x0 [2,8,16,1024] ============
__global__ __launch_bounds__(256) void k_dense_relu(
    const float* __restrict__ z, const float* __restrict__ Wd,
    const float* __restrict__ bd, float* __restrict__ x0)
{
    const int D = 131072;
    __shared__ float zs[256];
    const int tid = threadIdx.x;
    zs[tid] = z[tid];                 // z is [2,128] = 256 floats
    __syncthreads();
    const int n = blockIdx.x * 256 + tid;
    const float bb = bd[n];
    float a0 = bb, a1 = bb;
    #pragma unroll 8
    for (int kk = 0; kk < 128; ++kk) {
        const float w = Wd[kk * D + n];
        a0 = fmaf(zs[kk], w, a0);
        a1 = fmaf(zs[128 + kk], w, a1);
    }
    x0[n]     = fmaxf(a0, 0.f);
    x0[D + n] = fmaxf(a1, 0.f);
}

// ============ stage-1 offset conv as 49 dense GEMMs =========================
// Z[ks][d][src,oc] = X[src, ks*512 : +512] . OW1[d][same c-slice][oc]
// Each (d,src) feeds exactly one output pixel -> scatter done in sparams_z1.
// Block: 256 thr = 4 waves; wave=16 m-rows; lane = oc-pair; TILE_M=64.
__global__ __launch_bounds__(256) void k_zgemm1(
    const float* __restrict__ X,    // [256,1024]
    const float* __restrict__ OW,   // [49,1024,98] flat
    float* __restrict__ Zp)         // [2][49][256][98]
{
    const int tid = threadIdx.x;
    const int wv  = tid >> 6;
    const int lk  = tid & 63;
    const int kc  = (lk < 48) ? lk : 48;
    const int mb  = blockIdx.x << 6;    // 0..3 -> m base
    const int d   = blockIdx.y;         // tap
    const int ks  = blockIdx.z;         // K-split half

    __shared__ float OWs[32 * 98];      // 3136 floats
    __shared__ float Xs[32][68];        // padded: b128-aligned, 2-way-max banks
    float2* ows2 = (float2*)OWs;

    float accy[16], accx[16];
    #pragma unroll
    for (int p = 0; p < 16; ++p) { accy[p] = 0.f; accx[p] = 0.f; }

    float2 pfw[7];
    float4 pfx[2];
    const int c00 = ks * 512;

    auto PF = [&](int c0) {
        const float2* wsrc = (const float2*)(OW + (size_t)(d * 1024 + c0) * 98);
        #pragma unroll
        for (int i = 0; i < 7; ++i) {
            int e = tid + i * 256; if (e > 1567) e = 1567;
            pfw[i] = wsrc[e];
        }
        #pragma unroll
        for (int i = 0; i < 2; ++i) {
            const int e = tid + i * 256;          // < 512
            const int c4g = e & 7, m = e >> 3;
            pfx[i] = *(const float4*)&X[(size_t)(mb + m) * 1024 + c0 + c4g * 4];
        }
    };
    PF(c00);
    for (int ch = 0; ch < 16; ++ch) {
        __syncthreads();
        #pragma unroll
        for (int i = 0; i < 7; ++i) {
            const int e = tid + i * 256;
            if (e < 1568) ows2[e] = pfw[i];
        }
        #pragma unroll
        for (int i = 0; i < 2; ++i) {
            const int e = tid + i * 256;
            const int c4g = e & 7, m = e >> 3;
            Xs[c4g * 4 + 0][m] = pfx[i].x;
            Xs[c4g * 4 + 1][m] = pfx[i].y;
            Xs[c4g * 4 + 2][m] = pfx[i].z;
            Xs[c4g * 4 + 3][m] = pfx[i].w;
        }
        __syncthreads();
        if (ch + 1 < 16) PF(c00 + (ch + 1) * 32);
        const int m0 = wv * 16;
        #pragma unroll 4
        for (int c = 0; c < 32; ++c) {
            const float2 ow = ows2[c * 49 + kc];
            #pragma unroll
            for (int q = 0; q < 4; ++q) {
                const float4 xv = *(const float4*)&Xs[c][m0 + q * 4];
                accy[q*4+0] = fmaf(xv.x, ow.x, accy[q*4+0]);
                accx[q*4+0] = fmaf(xv.x, ow.y, accx[q*4+0]);
                accy[q*4+1] = fmaf(xv.y, ow.x, accy[q*4+1]);
                accx[q*4+1] = fmaf(xv.y, ow.y, accx[q*4+1]);
                accy[q*4+2] = fmaf(xv.z, ow.x, accy[q*4+2]);
                accx[q*4+2] = fmaf(xv.z, ow.y, accx[q*4+2]);
                accy[q*4+3] = fmaf(xv.w, ow.x, accy[q*4+3]);
                accx[q*4+3] = fmaf(xv.w, ow.y, accx[q*4+3]);
            }
        }
    }
    if (lk < 49) {
        const size_t base = ((size_t)(ks * 49 + d) * 256 + mb + wv * 16) * 98 + 2 * lk;
        #pragma unroll
        for (int p = 0; p < 16; ++p)
            *(float2*)&Zp[base + (size_t)p * 98] = make_float2(accy[p], accx[p]);
    }
}

// ============ stage-1: scatter-sum Zp + compute (s, src) ====================
__global__ __launch_bounds__(256) void k_sparams_z1(
    const float* __restrict__ Zp, const float* __restrict__ OB,
    float* __restrict__ SW, int* __restrict__ SIDX)
{
    const int gid = blockIdx.x * 256 + threadIdx.x;
    if (gid >= 1024 * K49) return;
    const int pixL = gid / K49;
    const int k = gid - pixL * K49;
    const int b   = pixL >> 9;          // Hp*Wp = 512
    const int rem = pixL & 511;
    const int hp  = rem >> 5;           // Wp = 32
    const int wp  = rem & 31;

    float accy = OB[2 * k], accx = OB[2 * k + 1];
    const int di0 = (hp + 1) & 1, dj0 = (wp + 1) & 1;
    for (int di = di0; di < 7; di += 2) {
        const int yp = hp + di - 3;
        if ((unsigned)yp >= 16u) continue;
        const int ys = yp >> 1;
        for (int dj = dj0; dj < 7; dj += 2) {
            const int xp = wp + dj - 3;
            if ((unsigned)xp >= 32u) continue;
            const int xs = xp >> 1;
            const size_t o = ((size_t)((di * 7 + dj) * 256 + (b * 8 + ys) * 16 + xs)) * 98 + 2 * k;
            accy += Zp[o]     + Zp[o + 1229312];
            accx += Zp[o + 1] + Zp[o + 1229313];
        }
    }
    const float y = (float)(hp + (k / 7) - 3) + accy;
    const float x = (float)(wp + (k % 7) - 3) + accx;
    const float fy0 = floorf(y), fx0 = floorf(x);
    const int iy0 = (int)fy0, ix0 = (int)fx0;
    const float wy1 = y - fy0, wx1 = x - fx0;
    int ye, xe; float wy, wx;
    if (iy0 & 1) { ye = iy0 + 1; wy = wy1; } else { ye = iy0; wy = 1.f - wy1; }
    if (ix0 & 1) { xe = ix0 + 1; wx = wx1; } else { xe = ix0; wx = 1.f - wx1; }
    float s = wy * wx;
    int src = 0;
    if (ye >= 0 && ye < 16 && xe >= 0 && xe < 32)
        src = (b * 8 + (ye >> 1)) * 16 + (xe >> 1);
    else
        s = 0.f;
    SW[gid] = s;
    SIDX[gid] = src;
}

// ============ offset conv v4 (stages 2-4): 2 jobs/block share OW ============
// part_off layout: [CG][npix][98]
template<int C, int CC>
__global__ __launch_bounds__(256) void k_offgemm4(
    const float* __restrict__ X, const int H, const int W,
    const float* __restrict__ OW,      // [7,7,C,98]
    float* __restrict__ part_off,
    const int Hp, const int Wp, const int pix0, const int npix)
{
    constexpr int P = 16;
    constexpr int CW = CC / 4;
    constexpr int NPF = (CC * 49 + 255) / 256;
    constexpr int NEED = CC * 98 + 2 * 76 * CC;
    constexpr int LDSZ = NEED > 6272 ? NEED : 6272;

    const int tid = threadIdx.x;
    const int wv  = tid >> 6;
    const int k   = tid & 63;
    const int kc  = (k < 48) ? k : 48;
    const int cg  = blockIdx.y;

    const int W2  = W / P;
    const int R   = npix / Wp;
    const int jpc = (R / 2) * W2;
    const int hb  = jpc / 2;
    const int cls = blockIdx.x / hb;
    const int jb  = (blockIdx.x - cls * hb) * 2;
    const int pi  = cls >> 1;
    const int rho = cls & 1;
    const int NR = pi ? 4 : 3, di0 = pi ? 0 : 1;
    const int NC = rho ? 4 : 3, dj0 = rho ? 0 : 1;
    const int T = NR * NC;

    int rJ[2], w0J[2], bJ[2], ysJ[2];
    #pragma unroll
    for (int j = 0; j < 2; ++j) {
        const int jc = jb + j;
        const int rr = jc / W2, wt = jc - rr * W2;
        rJ[j] = 2 * rr + pi;
        w0J[j] = wt * P;
        const int grow = pix0 / Wp + rJ[j];
        bJ[j] = grow / Hp;
        const int hp = grow - bJ[j] * Hp;
        ysJ[j] = (hp - 2) >> 1;
    }

    __shared__ float lds[LDSZ];
    float*  OWs  = lds;
    float*  Xs   = lds + CC * 98;       // [2][4][19][CC]
    float2* owf2 = (float2*)OWs;
    float2* red2 = (float2*)lds;

    const int cbase = cg * CC;
    {
        constexpr int CCq = CC / 4;
        for (int e = tid; e < 2 * 76 * CCq; e += 256) {
            const int j  = e / (76 * CCq);
            const int rm = e - j * (76 * CCq);
            const int tr = rm / (19 * CCq);
            const int rm2 = rm - tr * (19 * CCq);
            const int tc = rm2 / CCq;
            const int c4 = (rm2 - tc * CCq) * 4;
            const int ys = ysJ[j] + tr;
            const int xs = w0J[j] - 1 + tc;
            float4 v = make_float4(0.f, 0.f, 0.f, 0.f);
            if (ys >= 0 && ys < H && xs >= 0 && xs < W)
                v = *(const float4*)&X[((size_t)((bJ[j] * H + ys) * W + xs)) * C + cbase + c4];
            *(float4*)&Xs[((j * 4 + tr) * 19 + tc) * CC + c4] = v;
        }
    }

    float accy[2][P], accx[2][P];
    #pragma unroll
    for (int j = 0; j < 2; ++j)
        #pragma unroll
        for (int p = 0; p < P; ++p) { accy[j][p] = 0.f; accx[j][p] = 0.f; }

    const int NE = CC * 49;
    float2 pf[NPF];
    {
        const float2* src = (const float2*)(OW + ((size_t)((di0 * 7 + dj0) * C + cbase)) * 98);
        #pragma unroll
        for (int i = 0; i < NPF; ++i) {
            int e = tid + i * 256; if (e > NE - 1) e = NE - 1;
            pf[i] = src[e];
        }
    }

    int tr = 0, tcp = 0;
    for (int t = 0; t < T; ++t) {
        __syncthreads();
        #pragma unroll
        for (int i = 0; i < NPF; ++i) {
            const int e = tid + i * 256;
            if (e < NE) owf2[e] = pf[i];
        }
        __syncthreads();
        if (t + 1 < T) {
            int tcn = tcp + 1, trn = tr;
            if (tcn == NC) { tcn = 0; trn = tr + 1; }
            const int di = di0 + 2 * trn, dj = dj0 + 2 * tcn;
            const float2* src = (const float2*)(OW + ((size_t)((di * 7 + dj) * C + cbase)) * 98);
            #pragma unroll
            for (int i = 0; i < NPF; ++i) {
                int e = tid + i * 256; if (e > NE - 1) e = NE - 1;
                pf[i] = src[e];
            }
        }
        #pragma unroll
        for (int s = 0; s < CW / 4; ++s) {
            const int cc4 = wv * CW + s * 4;
            const float2 o0 = owf2[(cc4 + 0) * 49 + kc];
            const float2 o1 = owf2[(cc4 + 1) * 49 + kc];
            const float2 o2 = owf2[(cc4 + 2) * 49 + kc];
            const float2 o3 = owf2[(cc4 + 3) * 49 + kc];
            #pragma unroll
            for (int j = 0; j < 2; ++j)
                #pragma unroll
                for (int p = 0; p < P; ++p) {
                    const float4 xv = *(const float4*)&Xs[((j * 4 + tr) * 19 + p + tcp) * CC + cc4];
                    accy[j][p] = fmaf(xv.x, o0.x, accy[j][p]);
                    accx[j][p] = fmaf(xv.x, o0.y, accx[j][p]);
                    accy[j][p] = fmaf(xv.y, o1.x, accy[j][p]);
                    accx[j][p] = fmaf(xv.y, o1.y, accx[j][p]);
                    accy[j][p] = fmaf(xv.z, o2.x, accy[j][p]);
                    accx[j][p] = fmaf(xv.z, o2.y, accx[j][p]);
                    accy[j][p] = fmaf(xv.w, o3.x, accy[j][p]);
                    accx[j][p] = fmaf(xv.w, o3.y, accx[j][p]);
                }
        }
        if (++tcp == NC) { tcp = 0; ++tr; }
    }

    // per-job cross-wave reduce + coalesced write
    #pragma unroll
    for (int j = 0; j < 2; ++j) {
        __syncthreads();
        if (k < 49) {
            #pragma unroll
            for (int p = 0; p < P; ++p)
                red2[(wv * 16 + p) * 49 + k] = make_float2(accy[j][p], accx[j][p]);
        }
        __syncthreads();
        const size_t rowbase = (size_t)cg * npix + (size_t)rJ[j] * Wp;
        for (int e = tid; e < 784; e += 256) {
            const int p  = e / 49;
            const int kk = e - p * 49;
            const float2 v0 = red2[e];
            const float2 v1 = red2[784 + e];
            const float2 v2 = red2[1568 + e];
            const float2 v3 = red2[2352 + e];
            const float2 v = make_float2(v0.x + v1.x + v2.x + v3.x,
                                         v0.y + v1.y + v2.y + v3.y);
            const int wp_p = 2 * (w0J[j] + p) + rho;
            *(float2*)&part_off[(rowbase + wp_p) * 98 + 2 * kk] = v;
        }
    }
}

// ============ reduce offset partials + compute (s, src) per (pixel, tap) ====
__global__ __launch_bounds__(256) void k_sparams(
    const float* __restrict__ part_off, const float* __restrict__ OB,
    float* __restrict__ SW, int* __restrict__ SIDX,
    const int npix, const int CG,
    const int H, const int W, const int Hp, const int Wp, const int pix0)
{
    const int gid = blockIdx.x * 256 + threadIdx.x;
    if (gid >= npix * K49) return;
    const int pixL = gid / K49;
    const int k = gid - pixL * K49;
    float accy = OB[2 * k], accx = OB[2 * k + 1];
    for (int g = 0; g < CG; ++g) {
        const size_t base = ((size_t)g * npix + pixL) * 98 + 2 * k;
        accy += part_off[base];
        accx += part_off[base + 1];
    }
    const int pixg = pix0 + pixL;
    const int HWp = Hp * Wp;
    const int b = pixg / HWp;
    const int rem = pixg - b * HWp;
    const int hp = rem / Wp;
    const int wp = rem - hp * Wp;

    const float y = (float)(hp + (k / 7) - 3) + accy;
    const float x = (float)(wp + (k % 7) - 3) + accx;
    const float fy0 = floorf(y), fx0 = floorf(x);
    const int iy0 = (int)fy0, ix0 = (int)fx0;
    const float wy1 = y - fy0, wx1 = x - fx0;
    int ye, xe; float wy, wx;
    if (iy0 & 1) { ye = iy0 + 1; wy = wy1; } else { ye = iy0; wy = 1.f - wy1; }
    if (ix0 & 1) { xe = ix0 + 1; wx = wx1; } else { xe = ix0; wx = 1.f - wx1; }
    float s = wy * wx;
    int src = 0;
    if (ye >= 0 && ye < Hp && xe >= 0 && xe < Wp)
        src = (b * H + (ye >> 1)) * W + (xe >> 1);
    else
        s = 0.f;
    SW[gid] = s;
    SIDX[gid] = src;
}

// ============ per-tap GEMM: Y[kg][k][m*F+f] = X[m,:] . W[k][:,f] ============
template<int C, int F, int KSPLIT>
__global__ __launch_bounds__(256) void k_ygemm(
    const float* __restrict__ X,    // [M, C]
    const float* __restrict__ Wt,   // [49, C, F]
    float* __restrict__ Yout,       // [KSPLIT][49][M*F]
    const int M)
{
    constexpr int TILE_M = 4096 / F;
    constexpr int CC = 32;
    constexpr int KC = C / KSPLIT;
    constexpr int NF = F / 4;
    constexpr int LDM = TILE_M + 4;

    __shared__ float Xs[CC][LDM];
    __shared__ float Ws[CC][F];

    const int tid = threadIdx.x;
    const int f0 = (tid % NF) * 4;
    const int m0 = (tid / NF) * 4;
    const int mb = blockIdx.x * TILE_M;
    const int k  = blockIdx.y;
    const int cg = blockIdx.z;
    const int cbase = cg * KC;

    float acc[4][4];
    #pragma unroll
    for (int j = 0; j < 4; ++j)
        #pragma unroll
        for (int i = 0; i < 4; ++i) acc[j][i] = 0.f;

    for (int c0 = 0; c0 < KC; c0 += CC) {
        for (int e = tid; e < TILE_M * (CC / 4); e += 256) {
            const int m = e / (CC / 4);
            const int c4 = (e % (CC / 4)) * 4;
            const float4 v = *(const float4*)&X[(size_t)(mb + m) * C + cbase + c0 + c4];
            Xs[c4 + 0][m] = v.x;
            Xs[c4 + 1][m] = v.y;
            Xs[c4 + 2][m] = v.z;
            Xs[c4 + 3][m] = v.w;
        }
        const float* wg = Wt + ((size_t)k * C + cbase + c0) * F;
        for (int t = tid; t < CC * F / 4; t += 256)
            ((float4*)Ws)[t] = ((const float4*)wg)[t];
        __syncthreads();
        #pragma unroll
        for (int cc = 0; cc < CC; ++cc) {
            const float4 xv = *(const float4*)&Xs[cc][m0];
            const float4 wv = *(const float4*)&Ws[cc][f0];
            acc[0][0] = fmaf(xv.x, wv.x, acc[0][0]);
            acc[0][1] = fmaf(xv.x, wv.y, acc[0][1]);
            acc[0][2] = fmaf(xv.x, wv.z, acc[0][2]);
            acc[0][3] = fmaf(xv.x, wv.w, acc[0][3]);
            acc[1][0] = fmaf(xv.y, wv.x, acc[1][0]);
            acc[1][1] = fmaf(xv.y, wv.y, acc[1][1]);
            acc[1][2] = fmaf(xv.y, wv.z, acc[1][2]);
            acc[1][3] = fmaf(xv.y, wv.w, acc[1][3]);
            acc[2][0] = fmaf(xv.z, wv.x, acc[2][0]);
            acc[2][1] = fmaf(xv.z, wv.y, acc[2][1]);
            acc[2][2] = fmaf(xv.z, wv.z, acc[2][2]);
            acc[2][3] = fmaf(xv.z, wv.w, acc[2][3]);
            acc[3][0] = fmaf(xv.w, wv.x, acc[3][0]);
            acc[3][1] = fmaf(xv.w, wv.y, acc[3][1]);
            acc[3][2] = fmaf(xv.w, wv.z, acc[3][2]);
            acc[3][3] = fmaf(xv.w, wv.w, acc[3][3]);
        }
        __syncthreads();
    }
    float* yb = Yout + ((size_t)(cg * K49 + k)) * M * F;
    #pragma unroll
    for (int j = 0; j < 4; ++j) {
        float4 o = make_float4(acc[j][0], acc[j][1], acc[j][2], acc[j][3]);
        *(float4*)&yb[(size_t)(mb + m0 + j) * F + f0] = o;
    }
}

// ============ sum KSPLIT partial Y slabs ============
__global__ __launch_bounds__(256) void k_reduceY(
    const float* __restrict__ partial, float* __restrict__ Y,
    const int n, const int G)
{
    const int gid = blockIdx.x * 256 + threadIdx.x;
    if (gid >= n) return;
    float a = 0.f;
    for (int g = 0; g < G; ++g) a += partial[(size_t)g * n + gid];
    Y[gid] = a;
}

// ============ combine: out[pix,f] = relu(b_f + sum_k s_k * Y[k][src_k*F+f]) =
template<int F>
__global__ __launch_bounds__(256) void k_combine(
    const float* __restrict__ Y,   // [49][nsrc*F]
    const float* __restrict__ SW, const int* __restrict__ SIDX,
    const float* __restrict__ bias, float* __restrict__ out,
    const int nsrc, const int do_relu)
{
    constexpr int PPB = 256 / F;
    const int tid = threadIdx.x;
    const int f = tid % F;
    const int pix = blockIdx.x * PPB + tid / F;
    const size_t strideY = (size_t)nsrc * F;
    float acc = bias[f];
    #pragma unroll 7
    for (int k = 0; k < K49; ++k) {
        const float s = SW[(size_t)pix * K49 + k];
        const int src = SIDX[(size_t)pix * K49 + k];
        acc = fmaf(s, Y[(size_t)k * strideY + (size_t)src * F + f], acc);
    }
    out[(size_t)pix * F + f] = do_relu ? fmaxf(acc, 0.f) : acc;
}

// ============ stage 4 Y: Y4[k][src] = X3[src,:16] . W4[k,:16] ============
__global__ __launch_bounds__(256) void k_y4(
    const float* __restrict__ X,   // [M,16]
    const float* __restrict__ Wt,  // [49,16]
    float* __restrict__ Y,         // [49][M]
    const int M)
{
    __shared__ float Ws[K49 * 16];
    const int tid = threadIdx.x;
    for (int t = tid; t < K49 * 16; t += 256) Ws[t] = Wt[t];
    __syncthreads();
    const int src = blockIdx.x * 256 + tid;
    const float4* xr = (const float4*)(X + (size_t)src * 16);
    const float4 a0 = xr[0], a1 = xr[1], a2 = xr[2], a3 = xr[3];
    for (int k = 0; k < K49; ++k) {
        const float* wr = Ws + k * 16;
        float d = a0.x*wr[0]  + a0.y*wr[1]  + a0.z*wr[2]  + a0.w*wr[3]
                + a1.x*wr[4]  + a1.y*wr[5]  + a1.z*wr[6]  + a1.w*wr[7]
                + a2.x*wr[8]  + a2.y*wr[9]  + a2.z*wr[10] + a2.w*wr[11]
                + a3.x*wr[12] + a3.y*wr[13] + a3.z*wr[14] + a3.w*wr[15];
        Y[(size_t)k * M + src] = d;
    }
}

// ============ stage 4: fused sparams + gather-combine via Y4, 4-lane split ===
__global__ __launch_bounds__(256) void k_dconv_f1_y(
    const float* __restrict__ Y4,       // [49][nsrc]
    const float* __restrict__ part,     // [npix, 98] raw offset conv (no bias)
    const float* __restrict__ OB,       // [98]
    const float* __restrict__ bias, float* __restrict__ out,
    const int H, const int W, const int Hp, const int Wp,
    const int pix0, const int nsrc)
{
    __shared__ float OBs[98];
    const int tid = threadIdx.x;
    if (tid < 98) OBs[tid] = OB[tid];
    __syncthreads();

    const int pixL = blockIdx.x * 64 + (tid >> 2);
    const int tq = tid & 3;
    const int t0 = (tq == 0) ? 0 : 13 + (tq - 1) * 12;
    const int t1 = t0 + ((tq == 0) ? 13 : 12);

    const int pixg = pix0 + pixL;
    const int HWp = Hp * Wp;
    const int b = pixg / HWp;
    const int rem = pixg - b * HWp;
    const int hp = rem / Wp;
    const int wp = rem - hp * Wp;

    float acc = 0.f;
    for (int k = t0; k < t1; ++k) {
        const float offy = part[(size_t)pixL * 98 + 2 * k]     + OBs[2 * k];
        const float offx = part[(size_t)pixL * 98 + 2 * k + 1] + OBs[2 * k + 1];
        const float y = (float)(hp + (k / 7) - 3) + offy;
        const float x = (float)(wp + (k % 7) - 3) + offx;
        const float fy0 = floorf(y), fx0 = floorf(x);
        const int iy0 = (int)fy0, ix0 = (int)fx0;
        const float wy1 = y - fy0, wx1 = x - fx0;
        int ye, xe; float wy, wx;
        if (iy0 & 1) { ye = iy0 + 1; wy = wy1; } else { ye = iy0; wy = 1.f - wy1; }
        if (ix0 & 1) { xe = ix0 + 1; wx = wx1; } else { xe = ix0; wx = 1.f - wx1; }
        float s = wy * wx;
        int src = 0;
        if (ye >= 0 && ye < Hp && xe >= 0 && xe < Wp)
            src = (b * H + (ye >> 1)) * W + (xe >> 1);
        else
            s = 0.f;
        acc = fmaf(s, Y4[(size_t)k * nsrc + src], acc);
    }
    acc += __shfl_xor(acc, 1);
    acc += __shfl_xor(acc, 2);
    if (tq == 0) out[pixg] = acc + bias[0];
}

extern "C" void kernel_launch(void* const* d_in, const int* in_sizes, int n_in,
                              void* d_out, int out_size, void* d_ws, size_t ws_size,
                              hipStream_t stream) {
    const float* z   = (const float*)d_in[0];
    const float* dw  = (const float*)d_in[1];
    const float* db  = (const float*)d_in[2];
    const float* ow1 = (const float*)d_in[3];
    const float* ob1 = (const float*)d_in[4];
    const float* w1  = (const float*)d_in[5];
    const float* b1  = (const float*)d_in[6];
    const float* ow2 = (const float*)d_in[7];
    const float* ob2 = (const float*)d_in[8];
    const float* w2  = (const float*)d_in[9];
    const float* b2  = (const float*)d_in[10];
    const float* ow3 = (const float*)d_in[11];
    const float* ob3 = (const float*)d_in[12];
    const float* w3  = (const float*)d_in[13];
    const float* b3  = (const float*)d_in[14];
    const float* ow4 = (const float*)d_in[15];
    const float* ob4 = (const float*)d_in[16];
    const float* w4  = (const float*)d_in[17];
    const float* b4  = (const float*)d_in[18];

    // workspace layout (floats): total 6,537,216 floats = 26.1 MB
    float* ws   = (float*)d_ws;
    float* x0   = ws;                      // 262144  [2,8,16,1024]
    float* x1   = x0 + 262144;             // 65536   [2,16,32,64]
    float* x2   = x1 + 65536;              // 131072  [2,32,64,32]
    float* x3   = x2 + 131072;             // 262144  [2,64,128,16]
    float* sw   = x3 + 262144;             // 802816  (16384 pix * 49)
    int*   sidx = (int*)(sw + 802816);     // 802816
    float* part = (float*)(sidx + 802816); // 3407872 (Zp / off-partials / Y-partials / Y2 / Y3)
    float* Ybuf = part + 3407872;          // 802816  (Y1: 49*256*64; Y4: 49*16384)

    float* out = (float*)d_out;

    // ---- dense + relu ----
    k_dense_relu<<<512, 256, 0, stream>>>(z, dw, db, x0);

    // ---- stage 1: x0 [2,8,16,1024] -> x1 [2,16,32,64] (nsrc=256, npix=1024) ----
    {
        const int npix = 1024, nsrc = 256;
        k_zgemm1<<<dim3(4, 49, 2), 256, 0, stream>>>(x0, ow1, part);   // Zp in part (9.8 MB)
        k_sparams_z1<<<(npix * K49 + 255) / 256, 256, 0, stream>>>(part, ob1, sw, sidx);
        dim3 gy(nsrc * 64 / 4096, K49, 4);
        k_ygemm<1024, 64, 4><<<gy, 256, 0, stream>>>(x0, w1, part, nsrc);
        const int nY = K49 * nsrc * 64;
        k_reduceY<<<(nY + 255) / 256, 256, 0, stream>>>(part, Ybuf, nY, 4);
        k_combine<64><<<npix * 64 / 256, 256, 0, stream>>>(Ybuf, sw, sidx, b1, x1, nsrc, 1);
    }

    // ---- stage 2: x1 [2,16,32,64] -> x2 [2,32,64,32] (nsrc=1024, npix=4096) ----
    {
        const int H = 16, W = 32, Hp = 32, Wp = 64, npix = 4096, nsrc = 1024, CG = 4;
        // jpc = 64 -> hb = 32 -> grid (4*32, 4)
        dim3 go(128, CG);
        k_offgemm4<64, 16><<<go, 256, 0, stream>>>(x1, H, W, ow2, part, Hp, Wp, 0, npix);
        k_sparams<<<(npix * K49 + 255) / 256, 256, 0, stream>>>(part, ob2, sw, sidx, npix, CG, H, W, Hp, Wp, 0);
        dim3 gy(nsrc * 32 / 4096, K49, 1);
        k_ygemm<64, 32, 1><<<gy, 256, 0, stream>>>(x1, w2, part, nsrc);   // Y2 lives in part
        k_combine<32><<<npix * 32 / 256, 256, 0, stream>>>(part, sw, sidx, b2, x2, nsrc, 1);
    }

    // ---- stage 3: x2 [2,32,64,32] -> x3 [2,64,128,16] (nsrc=4096, npix=16384) ----
    {
        const int H = 32, W = 64, Hp = 64, Wp = 128, npix = 16384, nsrc = 4096, CG = 1;
        // jpc = 256 -> hb = 128 -> grid (512, 1)
        dim3 go(512, CG);
        k_offgemm4<32, 32><<<go, 256, 0, stream>>>(x2, H, W, ow3, part, Hp, Wp, 0, npix);
        k_sparams<<<(npix * K49 + 255) / 256, 256, 0, stream>>>(part, ob3, sw, sidx, npix, CG, H, W, Hp, Wp, 0);
        dim3 gy(nsrc * 16 / 4096, K49, 1);
        k_ygemm<32, 16, 1><<<gy, 256, 0, stream>>>(x2, w3, part, nsrc);   // Y3 lives in part
        k_combine<16><<<npix * 16 / 256, 256, 0, stream>>>(part, sw, sidx, b3, x3, nsrc, 1);
    }

    // ---- stage 4: x3 [2,64,128,16] -> out [2,128,256,1] (nsrc=16384), 2 chunks ----
    {
        const int H = 64, W = 128, Hp = 128, Wp = 256, CHUNK = 32768, nsrc = 16384;
        k_y4<<<nsrc / 256, 256, 0, stream>>>(x3, w4, Ybuf, nsrc);
        for (int c = 0; c < 2; ++c) {
            const int pix0 = c * CHUNK;
            // jpc = (128/2)*8 = 512 -> hb = 256 -> grid (1024, 1)
            dim3 go(1024, 1);
            k_offgemm4<16, 16><<<go, 256, 0, stream>>>(x3, H, W, ow4, part, Hp, Wp, pix0, CHUNK);
            k_dconv_f1_y<<<CHUNK / 64, 256, 0, stream>>>(Ybuf, part, ob4, b4, out, H, W, Hp, Wp, pix0, nsrc);
        }
    }
}

// Round 7
// 294.895 us; speedup vs baseline: 1.1160x; 1.1160x over previous
//
#include <hip/hip_runtime.h>
#include <hip/hip_bf16.h>

#define K49 49

typedef short bf16x8 __attribute__((ext_vector_type(8)));
typedef float f32x4 __attribute__((ext_vector_type(4)));

__device__ __forceinline__ short f2bf(float x) {
    __hip_bfloat16 h = __float2bfloat16(x);
    return __builtin_bit_cast(short, h);
}
__device__ __forceinline__ float bf2f(short s) {
    unsigned u = ((unsigned)(unsigned short)s) << 16;
    return __builtin_bit_cast(float, u);
}

// ============ dense (z @ W + b) + relu -> x0 [2,8,16,1024] ============
__global__ __launch_bounds__(256) void k_dense_relu(
    const float* __restrict__ z, const float* __restrict__ Wd,
    const float* __restrict__ bd, float* __restrict__ x0)
{
    const int D = 131072;
    __shared__ float zs[256];
    const int tid = threadIdx.x;
    zs[tid] = z[tid];
    __syncthreads();
    const int n = blockIdx.x * 256 + tid;
    const float bb = bd[n];
    float a0 = bb, a1 = bb;
    #pragma unroll 8
    for (int kk = 0; kk < 128; ++kk) {
        const float w = Wd[kk * D + n];
        a0 = fmaf(zs[kk], w, a0);
        a1 = fmaf(zs[128 + kk], w, a1);
    }
    x0[n]     = fmaxf(a0, 0.f);
    x0[D + n] = fmaxf(a1, 0.f);
}

// ============ convert x0 -> fragment-packed bf16 hi/lo planes ============
// Xf layout (bf16): [plane(2)][mtile(16)][kb(32)][kg(4)][mi(16)][8]
__global__ __launch_bounds__(256) void k_cvt_x(
    const float* __restrict__ x0, short* __restrict__ Xf)
{
    const int gid = blockIdx.x * 256 + threadIdx.x;   // 32768 total
    const int m = gid >> 7;
    const int kg8 = gid & 127;
    const int mtile = m >> 4, mi = m & 15;
    const int kb = kg8 >> 2, kg = kg8 & 3;
    const size_t dst = ((((size_t)mtile * 32 + kb) * 4 + kg) * 16 + mi) * 8;
    const float4* src = (const float4*)(x0 + (size_t)m * 1024 + kg8 * 8);
    const float4 v0 = src[0], v1 = src[1];
    float vals[8] = {v0.x, v0.y, v0.z, v0.w, v1.x, v1.y, v1.z, v1.w};
    short hi[8], lo[8];
    #pragma unroll
    for (int j = 0; j < 8; ++j) {
        hi[j] = f2bf(vals[j]);
        lo[j] = f2bf(vals[j] - bf2f(hi[j]));
    }
    *(bf16x8*)(Xf + dst) = *(bf16x8*)hi;
    *(bf16x8*)(Xf + 262144 + dst) = *(bf16x8*)lo;
}

// ============ convert OW1 -> fragment-packed bf16 (transposed, padded) ======
// OWbf layout (bf16): [d(49)][nt(7)][kb(32)][kg(4)][ni(16)][8] ; oc = nt*16+ni
__global__ __launch_bounds__(256) void k_cvt_ow1(
    const float* __restrict__ OW, short* __restrict__ OWbf)
{
    const int gid = blockIdx.x * 256 + threadIdx.x;   // 702464 total
    if (gid >= 49 * 7 * 32 * 4 * 16) return;
    const int ni = gid & 15;
    int t = gid >> 4;
    const int kg = t & 3;  t >>= 2;
    const int kb = t & 31; t >>= 5;
    const int nt = t % 7;
    const int d  = t / 7;
    const int oc = nt * 16 + ni;
    short h[8];
    if (oc < 98) {
        const int c0 = kb * 32 + kg * 8;
        #pragma unroll
        for (int j = 0; j < 8; ++j)
            h[j] = f2bf(OW[((size_t)d * 1024 + c0 + j) * 98 + oc]);
    } else {
        #pragma unroll
        for (int j = 0; j < 8; ++j) h[j] = 0;
    }
    *(bf16x8*)(OWbf + (size_t)gid * 8) = *(bf16x8*)h;
}

// ============ stage-1 offset conv: MFMA GEMM ============
// Zp[d][m][oc] = sum_c X[m,c]*OW[d,c,oc]; X split hi+lo (2 MFMA terms), W=hi.
// grid (4, 49); wave = one 16-row m-tile x 112 cols (7 n-tiles).
__global__ __launch_bounds__(256) void k_zgemm1_mfma(
    const short* __restrict__ Xf, const short* __restrict__ OWbf,
    float* __restrict__ Zp)
{
    const int tid = threadIdx.x;
    const int wv = tid >> 6;
    const int l  = tid & 63;
    const int l15 = l & 15, l4 = l >> 4;
    const int mtile = blockIdx.x * 4 + wv;
    const int d = blockIdx.y;

    const bf16x8* Ah = (const bf16x8*)Xf + (size_t)mtile * 32 * 64 + l4 * 16 + l15;
    const bf16x8* Al = Ah + 32768;   // plane stride 262144 shorts = 32768 frags
    const bf16x8* Bb = (const bf16x8*)OWbf + (size_t)d * 7 * 32 * 64 + l4 * 16 + l15;

    f32x4 acc[7];
    #pragma unroll
    for (int nt = 0; nt < 7; ++nt) acc[nt] = (f32x4){0.f, 0.f, 0.f, 0.f};

    for (int kb = 0; kb < 32; ++kb) {
        const bf16x8 ah = Ah[kb * 64];
        const bf16x8 al = Al[kb * 64];
        #pragma unroll
        for (int nt = 0; nt < 7; ++nt) {
            const bf16x8 b = Bb[(size_t)nt * 32 * 64 + kb * 64];
            acc[nt] = __builtin_amdgcn_mfma_f32_16x16x32_bf16(ah, b, acc[nt], 0, 0, 0);
            acc[nt] = __builtin_amdgcn_mfma_f32_16x16x32_bf16(al, b, acc[nt], 0, 0, 0);
        }
    }

    const int m0 = mtile * 16 + l4 * 4;
    #pragma unroll
    for (int nt = 0; nt < 7; ++nt) {
        const int oc = nt * 16 + l15;
        if (oc < 98) {
            #pragma unroll
            for (int r = 0; r < 4; ++r)
                Zp[((size_t)d * 256 + m0 + r) * 98 + oc] = acc[nt][r];
        }
    }
}

// ============ stage-1: scatter-sum Zp + compute (s, src) ====================
__global__ __launch_bounds__(256) void k_sparams_z1(
    const float* __restrict__ Zp, const float* __restrict__ OB,
    float* __restrict__ SW, int* __restrict__ SIDX)
{
    const int gid = blockIdx.x * 256 + threadIdx.x;
    if (gid >= 1024 * K49) return;
    const int pixL = gid / K49;
    const int k = gid - pixL * K49;
    const int b   = pixL >> 9;
    const int rem = pixL & 511;
    const int hp  = rem >> 5;
    const int wp  = rem & 31;

    float accy = OB[2 * k], accx = OB[2 * k + 1];
    const int di0 = (hp + 1) & 1, dj0 = (wp + 1) & 1;
    for (int di = di0; di < 7; di += 2) {
        const int yp = hp + di - 3;
        if ((unsigned)yp >= 16u) continue;
        const int ys = yp >> 1;
        for (int dj = dj0; dj < 7; dj += 2) {
            const int xp = wp + dj - 3;
            if ((unsigned)xp >= 32u) continue;
            const int xs = xp >> 1;
            const size_t o = ((size_t)((di * 7 + dj) * 256 + (b * 8 + ys) * 16 + xs)) * 98 + 2 * k;
            accy += Zp[o];
            accx += Zp[o + 1];
        }
    }
    const float y = (float)(hp + (k / 7) - 3) + accy;
    const float x = (float)(wp + (k % 7) - 3) + accx;
    const float fy0 = floorf(y), fx0 = floorf(x);
    const int iy0 = (int)fy0, ix0 = (int)fx0;
    const float wy1 = y - fy0, wx1 = x - fx0;
    int ye, xe; float wy, wx;
    if (iy0 & 1) { ye = iy0 + 1; wy = wy1; } else { ye = iy0; wy = 1.f - wy1; }
    if (ix0 & 1) { xe = ix0 + 1; wx = wx1; } else { xe = ix0; wx = 1.f - wx1; }
    float s = wy * wx;
    int src = 0;
    if (ye >= 0 && ye < 16 && xe >= 0 && xe < 32)
        src = (b * 8 + (ye >> 1)) * 16 + (xe >> 1);
    else
        s = 0.f;
    SW[gid] = s;
    SIDX[gid] = src;
}

// ============ offset conv v4 (stages 2-4): 2 jobs/block share OW ============
// part_off layout: [CG][npix][98]
template<int C, int CC>
__global__ __launch_bounds__(256) void k_offgemm4(
    const float* __restrict__ X, const int H, const int W,
    const float* __restrict__ OW,      // [7,7,C,98]
    float* __restrict__ part_off,
    const int Hp, const int Wp, const int pix0, const int npix)
{
    constexpr int P = 16;
    constexpr int CW = CC / 4;
    constexpr int NPF = (CC * 49 + 255) / 256;
    constexpr int NEED = CC * 98 + 2 * 76 * CC;
    constexpr int LDSZ = NEED > 6272 ? NEED : 6272;

    const int tid = threadIdx.x;
    const int wv  = tid >> 6;
    const int k   = tid & 63;
    const int kc  = (k < 48) ? k : 48;
    const int cg  = blockIdx.y;

    const int W2  = W / P;
    const int R   = npix / Wp;
    const int jpc = (R / 2) * W2;
    const int hb  = jpc / 2;
    const int cls = blockIdx.x / hb;
    const int jb  = (blockIdx.x - cls * hb) * 2;
    const int pi  = cls >> 1;
    const int rho = cls & 1;
    const int NR = pi ? 4 : 3, di0 = pi ? 0 : 1;
    const int NC = rho ? 4 : 3, dj0 = rho ? 0 : 1;
    const int T = NR * NC;

    int rJ[2], w0J[2], bJ[2], ysJ[2];
    #pragma unroll
    for (int j = 0; j < 2; ++j) {
        const int jc = jb + j;
        const int rr = jc / W2, wt = jc - rr * W2;
        rJ[j] = 2 * rr + pi;
        w0J[j] = wt * P;
        const int grow = pix0 / Wp + rJ[j];
        bJ[j] = grow / Hp;
        const int hp = grow - bJ[j] * Hp;
        ysJ[j] = (hp - 2) >> 1;
    }

    __shared__ float lds[LDSZ];
    float*  OWs  = lds;
    float*  Xs   = lds + CC * 98;
    float2* owf2 = (float2*)OWs;
    float2* red2 = (float2*)lds;

    const int cbase = cg * CC;
    {
        constexpr int CCq = CC / 4;
        for (int e = tid; e < 2 * 76 * CCq; e += 256) {
            const int j  = e / (76 * CCq);
            const int rm = e - j * (76 * CCq);
            const int tr = rm / (19 * CCq);
            const int rm2 = rm - tr * (19 * CCq);
            const int tc = rm2 / CCq;
            const int c4 = (rm2 - tc * CCq) * 4;
            const int ys = ysJ[j] + tr;
            const int xs = w0J[j] - 1 + tc;
            float4 v = make_float4(0.f, 0.f, 0.f, 0.f);
            if (ys >= 0 && ys < H && xs >= 0 && xs < W)
                v = *(const float4*)&X[((size_t)((bJ[j] * H + ys) * W + xs)) * C + cbase + c4];
            *(float4*)&Xs[((j * 4 + tr) * 19 + tc) * CC + c4] = v;
        }
    }

    float accy[2][P], accx[2][P];
    #pragma unroll
    for (int j = 0; j < 2; ++j)
        #pragma unroll
        for (int p = 0; p < P; ++p) { accy[j][p] = 0.f; accx[j][p] = 0.f; }

    const int NE = CC * 49;
    float2 pf[NPF];
    {
        const float2* src = (const float2*)(OW + ((size_t)((di0 * 7 + dj0) * C + cbase)) * 98);
        #pragma unroll
        for (int i = 0; i < NPF; ++i) {
            int e = tid + i * 256; if (e > NE - 1) e = NE - 1;
            pf[i] = src[e];
        }
    }

    int tr = 0, tcp = 0;
    for (int t = 0; t < T; ++t) {
        __syncthreads();
        #pragma unroll
        for (int i = 0; i < NPF; ++i) {
            const int e = tid + i * 256;
            if (e < NE) owf2[e] = pf[i];
        }
        __syncthreads();
        if (t + 1 < T) {
            int tcn = tcp + 1, trn = tr;
            if (tcn == NC) { tcn = 0; trn = tr + 1; }
            const int di = di0 + 2 * trn, dj = dj0 + 2 * tcn;
            const float2* src = (const float2*)(OW + ((size_t)((di * 7 + dj) * C + cbase)) * 98);
            #pragma unroll
            for (int i = 0; i < NPF; ++i) {
                int e = tid + i * 256; if (e > NE - 1) e = NE - 1;
                pf[i] = src[e];
            }
        }
        #pragma unroll
        for (int s = 0; s < CW / 4; ++s) {
            const int cc4 = wv * CW + s * 4;
            const float2 o0 = owf2[(cc4 + 0) * 49 + kc];
            const float2 o1 = owf2[(cc4 + 1) * 49 + kc];
            const float2 o2 = owf2[(cc4 + 2) * 49 + kc];
            const float2 o3 = owf2[(cc4 + 3) * 49 + kc];
            #pragma unroll
            for (int j = 0; j < 2; ++j)
                #pragma unroll
                for (int p = 0; p < P; ++p) {
                    const float4 xv = *(const float4*)&Xs[((j * 4 + tr) * 19 + p + tcp) * CC + cc4];
                    accy[j][p] = fmaf(xv.x, o0.x, accy[j][p]);
                    accx[j][p] = fmaf(xv.x, o0.y, accx[j][p]);
                    accy[j][p] = fmaf(xv.y, o1.x, accy[j][p]);
                    accx[j][p] = fmaf(xv.y, o1.y, accx[j][p]);
                    accy[j][p] = fmaf(xv.z, o2.x, accy[j][p]);
                    accx[j][p] = fmaf(xv.z, o2.y, accx[j][p]);
                    accy[j][p] = fmaf(xv.w, o3.x, accy[j][p]);
                    accx[j][p] = fmaf(xv.w, o3.y, accx[j][p]);
                }
        }
        if (++tcp == NC) { tcp = 0; ++tr; }
    }

    #pragma unroll
    for (int j = 0; j < 2; ++j) {
        __syncthreads();
        if (k < 49) {
            #pragma unroll
            for (int p = 0; p < P; ++p)
                red2[(wv * 16 + p) * 49 + k] = make_float2(accy[j][p], accx[j][p]);
        }
        __syncthreads();
        const size_t rowbase = (size_t)cg * npix + (size_t)rJ[j] * Wp;
        for (int e = tid; e < 784; e += 256) {
            const int p  = e / 49;
            const int kk = e - p * 49;
            const float2 v0 = red2[e];
            const float2 v1 = red2[784 + e];
            const float2 v2 = red2[1568 + e];
            const float2 v3 = red2[2352 + e];
            const float2 v = make_float2(v0.x + v1.x + v2.x + v3.x,
                                         v0.y + v1.y + v2.y + v3.y);
            const int wp_p = 2 * (w0J[j] + p) + rho;
            *(float2*)&part_off[(rowbase + wp_p) * 98 + 2 * kk] = v;
        }
    }
}

// ============ reduce offset partials + compute (s, src) per (pixel, tap) ====
__global__ __launch_bounds__(256) void k_sparams(
    const float* __restrict__ part_off, const float* __restrict__ OB,
    float* __restrict__ SW, int* __restrict__ SIDX,
    const int npix, const int CG,
    const int H, const int W, const int Hp, const int Wp, const int pix0)
{
    const int gid = blockIdx.x * 256 + threadIdx.x;
    if (gid >= npix * K49) return;
    const int pixL = gid / K49;
    const int k = gid - pixL * K49;
    float accy = OB[2 * k], accx = OB[2 * k + 1];
    for (int g = 0; g < CG; ++g) {
        const size_t base = ((size_t)g * npix + pixL) * 98 + 2 * k;
        accy += part_off[base];
        accx += part_off[base + 1];
    }
    const int pixg = pix0 + pixL;
    const int HWp = Hp * Wp;
    const int b = pixg / HWp;
    const int rem = pixg - b * HWp;
    const int hp = rem / Wp;
    const int wp = rem - hp * Wp;

    const float y = (float)(hp + (k / 7) - 3) + accy;
    const float x = (float)(wp + (k % 7) - 3) + accx;
    const float fy0 = floorf(y), fx0 = floorf(x);
    const int iy0 = (int)fy0, ix0 = (int)fx0;
    const float wy1 = y - fy0, wx1 = x - fx0;
    int ye, xe; float wy, wx;
    if (iy0 & 1) { ye = iy0 + 1; wy = wy1; } else { ye = iy0; wy = 1.f - wy1; }
    if (ix0 & 1) { xe = ix0 + 1; wx = wx1; } else { xe = ix0; wx = 1.f - wx1; }
    float s = wy * wx;
    int src = 0;
    if (ye >= 0 && ye < Hp && xe >= 0 && xe < Wp)
        src = (b * H + (ye >> 1)) * W + (xe >> 1);
    else
        s = 0.f;
    SW[gid] = s;
    SIDX[gid] = src;
}

// ============ per-tap GEMM: Y[kg][k][m*F+f] = X[m,:] . W[k][:,f] ============
template<int C, int F, int KSPLIT>
__global__ __launch_bounds__(256) void k_ygemm(
    const float* __restrict__ X,    // [M, C]
    const float* __restrict__ Wt,   // [49, C, F]
    float* __restrict__ Yout,       // [KSPLIT][49][M*F]
    const int M)
{
    constexpr int TILE_M = 4096 / F;
    constexpr int CC = 32;
    constexpr int KC = C / KSPLIT;
    constexpr int NF = F / 4;
    constexpr int LDM = TILE_M + 4;

    __shared__ float Xs[CC][LDM];
    __shared__ float Ws[CC][F];

    const int tid = threadIdx.x;
    const int f0 = (tid % NF) * 4;
    const int m0 = (tid / NF) * 4;
    const int mb = blockIdx.x * TILE_M;
    const int k  = blockIdx.y;
    const int cg = blockIdx.z;
    const int cbase = cg * KC;

    float acc[4][4];
    #pragma unroll
    for (int j = 0; j < 4; ++j)
        #pragma unroll
        for (int i = 0; i < 4; ++i) acc[j][i] = 0.f;

    for (int c0 = 0; c0 < KC; c0 += CC) {
        for (int e = tid; e < TILE_M * (CC / 4); e += 256) {
            const int m = e / (CC / 4);
            const int c4 = (e % (CC / 4)) * 4;
            const float4 v = *(const float4*)&X[(size_t)(mb + m) * C + cbase + c0 + c4];
            Xs[c4 + 0][m] = v.x;
            Xs[c4 + 1][m] = v.y;
            Xs[c4 + 2][m] = v.z;
            Xs[c4 + 3][m] = v.w;
        }
        const float* wg = Wt + ((size_t)k * C + cbase + c0) * F;
        for (int t = tid; t < CC * F / 4; t += 256)
            ((float4*)Ws)[t] = ((const float4*)wg)[t];
        __syncthreads();
        #pragma unroll
        for (int cc = 0; cc < CC; ++cc) {
            const float4 xv = *(const float4*)&Xs[cc][m0];
            const float4 wv = *(const float4*)&Ws[cc][f0];
            acc[0][0] = fmaf(xv.x, wv.x, acc[0][0]);
            acc[0][1] = fmaf(xv.x, wv.y, acc[0][1]);
            acc[0][2] = fmaf(xv.x, wv.z, acc[0][2]);
            acc[0][3] = fmaf(xv.x, wv.w, acc[0][3]);
            acc[1][0] = fmaf(xv.y, wv.x, acc[1][0]);
            acc[1][1] = fmaf(xv.y, wv.y, acc[1][1]);
            acc[1][2] = fmaf(xv.y, wv.z, acc[1][2]);
            acc[1][3] = fmaf(xv.y, wv.w, acc[1][3]);
            acc[2][0] = fmaf(xv.z, wv.x, acc[2][0]);
            acc[2][1] = fmaf(xv.z, wv.y, acc[2][1]);
            acc[2][2] = fmaf(xv.z, wv.z, acc[2][2]);
            acc[2][3] = fmaf(xv.z, wv.w, acc[2][3]);
            acc[3][0] = fmaf(xv.w, wv.x, acc[3][0]);
            acc[3][1] = fmaf(xv.w, wv.y, acc[3][1]);
            acc[3][2] = fmaf(xv.w, wv.z, acc[3][2]);
            acc[3][3] = fmaf(xv.w, wv.w, acc[3][3]);
        }
        __syncthreads();
    }
    float* yb = Yout + ((size_t)(cg * K49 + k)) * M * F;
    #pragma unroll
    for (int j = 0; j < 4; ++j) {
        float4 o = make_float4(acc[j][0], acc[j][1], acc[j][2], acc[j][3]);
        *(float4*)&yb[(size_t)(mb + m0 + j) * F + f0] = o;
    }
}

// ============ sum KSPLIT partial Y slabs ============
__global__ __launch_bounds__(256) void k_reduceY(
    const float* __restrict__ partial, float* __restrict__ Y,
    const int n, const int G)
{
    const int gid = blockIdx.x * 256 + threadIdx.x;
    if (gid >= n) return;
    float a = 0.f;
    for (int g = 0; g < G; ++g) a += partial[(size_t)g * n + gid];
    Y[gid] = a;
}

// ============ combine: out[pix,f] = relu(b_f + sum_k s_k * Y[k][src_k*F+f]) =
template<int F>
__global__ __launch_bounds__(256) void k_combine(
    const float* __restrict__ Y,   // [49][nsrc*F]
    const float* __restrict__ SW, const int* __restrict__ SIDX,
    const float* __restrict__ bias, float* __restrict__ out,
    const int nsrc, const int do_relu)
{
    constexpr int PPB = 256 / F;
    const int tid = threadIdx.x;
    const int f = tid % F;
    const int pix = blockIdx.x * PPB + tid / F;
    const size_t strideY = (size_t)nsrc * F;
    float acc = bias[f];
    #pragma unroll 7
    for (int k = 0; k < K49; ++k) {
        const float s = SW[(size_t)pix * K49 + k];
        const int src = SIDX[(size_t)pix * K49 + k];
        acc = fmaf(s, Y[(size_t)k * strideY + (size_t)src * F + f], acc);
    }
    out[(size_t)pix * F + f] = do_relu ? fmaxf(acc, 0.f) : acc;
}

// ============ stage 4 Y: Y4[k][src] = X3[src,:16] . W4[k,:16] ============
__global__ __launch_bounds__(256) void k_y4(
    const float* __restrict__ X,   // [M,16]
    const float* __restrict__ Wt,  // [49,16]
    float* __restrict__ Y,         // [49][M]
    const int M)
{
    __shared__ float Ws[K49 * 16];
    const int tid = threadIdx.x;
    for (int t = tid; t < K49 * 16; t += 256) Ws[t] = Wt[t];
    __syncthreads();
    const int src = blockIdx.x * 256 + tid;
    const float4* xr = (const float4*)(X + (size_t)src * 16);
    const float4 a0 = xr[0], a1 = xr[1], a2 = xr[2], a3 = xr[3];
    for (int k = 0; k < K49; ++k) {
        const float* wr = Ws + k * 16;
        float d = a0.x*wr[0]  + a0.y*wr[1]  + a0.z*wr[2]  + a0.w*wr[3]
                + a1.x*wr[4]  + a1.y*wr[5]  + a1.z*wr[6]  + a1.w*wr[7]
                + a2.x*wr[8]  + a2.y*wr[9]  + a2.z*wr[10] + a2.w*wr[11]
                + a3.x*wr[12] + a3.y*wr[13] + a3.z*wr[14] + a3.w*wr[15];
        Y[(size_t)k * M + src] = d;
    }
}

// ============ stage 4: fused sparams + gather-combine via Y4, 4-lane split ===
__global__ __launch_bounds__(256) void k_dconv_f1_y(
    const float* __restrict__ Y4,       // [49][nsrc]
    const float* __restrict__ part,     // [npix, 98] raw offset conv (no bias)
    const float* __restrict__ OB,       // [98]
    const float* __restrict__ bias, float* __restrict__ out,
    const int H, const int W, const int Hp, const int Wp,
    const int pix0, const int nsrc)
{
    __shared__ float OBs[98];
    const int tid = threadIdx.x;
    if (tid < 98) OBs[tid] = OB[tid];
    __syncthreads();

    const int pixL = blockIdx.x * 64 + (tid >> 2);
    const int tq = tid & 3;
    const int t0 = (tq == 0) ? 0 : 13 + (tq - 1) * 12;
    const int t1 = t0 + ((tq == 0) ? 13 : 12);

    const int pixg = pix0 + pixL;
    const int HWp = Hp * Wp;
    const int b = pixg / HWp;
    const int rem = pixg - b * HWp;
    const int hp = rem / Wp;
    const int wp = rem - hp * Wp;

    float acc = 0.f;
    for (int k = t0; k < t1; ++k) {
        const float offy = part[(size_t)pixL * 98 + 2 * k]     + OBs[2 * k];
        const float offx = part[(size_t)pixL * 98 + 2 * k + 1] + OBs[2 * k + 1];
        const float y = (float)(hp + (k / 7) - 3) + offy;
        const float x = (float)(wp + (k % 7) - 3) + offx;
        const float fy0 = floorf(y), fx0 = floorf(x);
        const int iy0 = (int)fy0, ix0 = (int)fx0;
        const float wy1 = y - fy0, wx1 = x - fx0;
        int ye, xe; float wy, wx;
        if (iy0 & 1) { ye = iy0 + 1; wy = wy1; } else { ye = iy0; wy = 1.f - wy1; }
        if (ix0 & 1) { xe = ix0 + 1; wx = wx1; } else { xe = ix0; wx = 1.f - wx1; }
        float s = wy * wx;
        int src = 0;
        if (ye >= 0 && ye < Hp && xe >= 0 && xe < Wp)
            src = (b * H + (ye >> 1)) * W + (xe >> 1);
        else
            s = 0.f;
        acc = fmaf(s, Y4[(size_t)k * nsrc + src], acc);
    }
    acc += __shfl_xor(acc, 1);
    acc += __shfl_xor(acc, 2);
    if (tq == 0) out[pixg] = acc + bias[0];
}

extern "C" void kernel_launch(void* const* d_in, const int* in_sizes, int n_in,
                              void* d_out, int out_size, void* d_ws, size_t ws_size,
                              hipStream_t stream) {
    const float* z   = (const float*)d_in[0];
    const float* dw  = (const float*)d_in[1];
    const float* db  = (const float*)d_in[2];
    const float* ow1 = (const float*)d_in[3];
    const float* ob1 = (const float*)d_in[4];
    const float* w1  = (const float*)d_in[5];
    const float* b1  = (const float*)d_in[6];
    const float* ow2 = (const float*)d_in[7];
    const float* ob2 = (const float*)d_in[8];
    const float* w2  = (const float*)d_in[9];
    const float* b2  = (const float*)d_in[10];
    const float* ow3 = (const float*)d_in[11];
    const float* ob3 = (const float*)d_in[12];
    const float* w3  = (const float*)d_in[13];
    const float* b3  = (const float*)d_in[14];
    const float* ow4 = (const float*)d_in[15];
    const float* ob4 = (const float*)d_in[16];
    const float* w4  = (const float*)d_in[17];
    const float* b4  = (const float*)d_in[18];

    // workspace layout (floats): total 6,537,216 floats = 26.1 MB
    float* ws   = (float*)d_ws;
    float* x0   = ws;                      // 262144  [2,8,16,1024]
    float* x1   = x0 + 262144;             // 65536
    float* x2   = x1 + 65536;              // 131072
    float* x3   = x2 + 131072;             // 262144
    float* sw   = x3 + 262144;             // 802816  (also hosts Xf bf16 frags pre-sparams)
    int*   sidx = (int*)(sw + 802816);     // 802816
    float* part = (float*)(sidx + 802816); // 3407872 (OWbf+Zp / off-partials / Y-partials)
    float* Ybuf = part + 3407872;          // 802816

    float* out = (float*)d_out;

    // ---- dense + relu ----
    k_dense_relu<<<512, 256, 0, stream>>>(z, dw, db, x0);

    // ---- stage 1: x0 [2,8,16,1024] -> x1 [2,16,32,64] (nsrc=256, npix=1024) ----
    {
        const int npix = 1024, nsrc = 256;
        short* Xf   = (short*)sw;                    // 524288 bf16 = 262144 floats
        short* OWbf = (short*)part;                  // 5,619,712 bf16 = 2,809,856 floats
        float* Zp   = part + 2809856;                // 1,229,312 floats (ends at 4,039,168 < 4,210,688)
        k_cvt_x<<<128, 256, 0, stream>>>(x0, Xf);
        k_cvt_ow1<<<2744, 256, 0, stream>>>(ow1, OWbf);
        k_zgemm1_mfma<<<dim3(4, 49), 256, 0, stream>>>(Xf, OWbf, Zp);
        k_sparams_z1<<<(npix * K49 + 255) / 256, 256, 0, stream>>>(Zp, ob1, sw, sidx);
        dim3 gy(nsrc * 64 / 4096, K49, 4);
        k_ygemm<1024, 64, 4><<<gy, 256, 0, stream>>>(x0, w1, part, nsrc);
        const int nY = K49 * nsrc * 64;
        k_reduceY<<<(nY + 255) / 256, 256, 0, stream>>>(part, Ybuf, nY, 4);
        k_combine<64><<<npix * 64 / 256, 256, 0, stream>>>(Ybuf, sw, sidx, b1, x1, nsrc, 1);
    }

    // ---- stage 2: x1 [2,16,32,64] -> x2 [2,32,64,32] (nsrc=1024, npix=4096) ----
    {
        const int H = 16, W = 32, Hp = 32, Wp = 64, npix = 4096, nsrc = 1024, CG = 4;
        dim3 go(128, CG);
        k_offgemm4<64, 16><<<go, 256, 0, stream>>>(x1, H, W, ow2, part, Hp, Wp, 0, npix);
        k_sparams<<<(npix * K49 + 255) / 256, 256, 0, stream>>>(part, ob2, sw, sidx, npix, CG, H, W, Hp, Wp, 0);
        dim3 gy(nsrc * 32 / 4096, K49, 1);
        k_ygemm<64, 32, 1><<<gy, 256, 0, stream>>>(x1, w2, part, nsrc);
        k_combine<32><<<npix * 32 / 256, 256, 0, stream>>>(part, sw, sidx, b2, x2, nsrc, 1);
    }

    // ---- stage 3: x2 [2,32,64,32] -> x3 [2,64,128,16] (nsrc=4096, npix=16384) ----
    {
        const int H = 32, W = 64, Hp = 64, Wp = 128, npix = 16384, nsrc = 4096, CG = 1;
        dim3 go(512, CG);
        k_offgemm4<32, 32><<<go, 256, 0, stream>>>(x2, H, W, ow3, part, Hp, Wp, 0, npix);
        k_sparams<<<(npix * K49 + 255) / 256, 256, 0, stream>>>(part, ob3, sw, sidx, npix, CG, H, W, Hp, Wp, 0);
        dim3 gy(nsrc * 16 / 4096, K49, 1);
        k_ygemm<32, 16, 1><<<gy, 256, 0, stream>>>(x2, w3, part, nsrc);
        k_combine<16><<<npix * 16 / 256, 256, 0, stream>>>(part, sw, sidx, b3, x3, nsrc, 1);
    }

    // ---- stage 4: x3 [2,64,128,16] -> out [2,128,256,1] (nsrc=16384), 2 chunks ----
    {
        const int H = 64, W = 128, Hp = 128, Wp = 256, CHUNK = 32768, nsrc = 16384;
        k_y4<<<nsrc / 256, 256, 0, stream>>>(x3, w4, Ybuf, nsrc);
        for (int c = 0; c < 2; ++c) {
            const int pix0 = c * CHUNK;
            dim3 go(1024, 1);
            k_offgemm4<16, 16><<<go, 256, 0, stream>>>(x3, H, W, ow4, part, Hp, Wp, pix0, CHUNK);
            k_dconv_f1_y<<<CHUNK / 64, 256, 0, stream>>>(Ybuf, part, ob4, b4, out, H, W, Hp, Wp, pix0, nsrc);
        }
    }
}

// Round 8
// 268.508 us; speedup vs baseline: 1.2257x; 1.0983x over previous
//
#include <hip/hip_runtime.h>
#include <hip/hip_bf16.h>

#define K49 49

typedef short bf16x8 __attribute__((ext_vector_type(8)));
typedef float f32x4 __attribute__((ext_vector_type(4)));

__device__ __forceinline__ short f2bf(float x) {
    __hip_bfloat16 h = __float2bfloat16(x);
    return __builtin_bit_cast(short, h);
}
__device__ __forceinline__ float bf2f(short s) {
    unsigned u = ((unsigned)(unsigned short)s) << 16;
    return __builtin_bit_cast(float, u);
}

// ============ dense (z @ W + b) + relu -> x0 [2,8,16,1024] ============
__global__ __launch_bounds__(256) void k_dense_relu(
    const float* __restrict__ z, const float* __restrict__ Wd,
    const float* __restrict__ bd, float* __restrict__ x0)
{
    const int D = 131072;
    __shared__ float zs[256];
    const int tid = threadIdx.x;
    zs[tid] = z[tid];
    __syncthreads();
    const int n = blockIdx.x * 256 + tid;
    const float bb = bd[n];
    float a0 = bb, a1 = bb;
    #pragma unroll 8
    for (int kk = 0; kk < 128; ++kk) {
        const float w = Wd[kk * D + n];
        a0 = fmaf(zs[kk], w, a0);
        a1 = fmaf(zs[128 + kk], w, a1);
    }
    x0[n]     = fmaxf(a0, 0.f);
    x0[D + n] = fmaxf(a1, 0.f);
}

// ============ convert x0 -> fragment-packed bf16 hi/lo planes (stage 1) =====
// Xf layout (bf16): [plane(2)][mtile(16)][kb(32)][kg(4)][mi(16)][8]
__global__ __launch_bounds__(256) void k_cvt_x(
    const float* __restrict__ x0, short* __restrict__ Xf)
{
    const int gid = blockIdx.x * 256 + threadIdx.x;   // 32768 total
    const int m = gid >> 7;
    const int kg8 = gid & 127;
    const int mtile = m >> 4, mi = m & 15;
    const int kb = kg8 >> 2, kg = kg8 & 3;
    const size_t dst = ((((size_t)mtile * 32 + kb) * 4 + kg) * 16 + mi) * 8;
    const float4* src = (const float4*)(x0 + (size_t)m * 1024 + kg8 * 8);
    const float4 v0 = src[0], v1 = src[1];
    float vals[8] = {v0.x, v0.y, v0.z, v0.w, v1.x, v1.y, v1.z, v1.w};
    short hi[8], lo[8];
    #pragma unroll
    for (int j = 0; j < 8; ++j) {
        hi[j] = f2bf(vals[j]);
        lo[j] = f2bf(vals[j] - bf2f(hi[j]));
    }
    *(bf16x8*)(Xf + dst) = *(bf16x8*)hi;
    *(bf16x8*)(Xf + 262144 + dst) = *(bf16x8*)lo;
}

// ============ convert OW1 -> fragment-packed bf16 (stage 1) ======
// OWbf layout (bf16): [d(49)][nt(7)][kb(32)][kg(4)][ni(16)][8] ; oc = nt*16+ni
__global__ __launch_bounds__(256) void k_cvt_ow1(
    const float* __restrict__ OW, short* __restrict__ OWbf)
{
    const int gid = blockIdx.x * 256 + threadIdx.x;   // 702464 total
    if (gid >= 49 * 7 * 32 * 4 * 16) return;
    const int ni = gid & 15;
    int t = gid >> 4;
    const int kg = t & 3;  t >>= 2;
    const int kb = t & 31; t >>= 5;
    const int nt = t % 7;
    const int d  = t / 7;
    const int oc = nt * 16 + ni;
    short h[8];
    if (oc < 98) {
        const int c0 = kb * 32 + kg * 8;
        #pragma unroll
        for (int j = 0; j < 8; ++j)
            h[j] = f2bf(OW[((size_t)d * 1024 + c0 + j) * 98 + oc]);
    } else {
        #pragma unroll
        for (int j = 0; j < 8; ++j) h[j] = 0;
    }
    *(bf16x8*)(OWbf + (size_t)gid * 8) = *(bf16x8*)h;
}

// ============ stage-1 offset conv: MFMA GEMM over taps ============
__global__ __launch_bounds__(256) void k_zgemm1_mfma(
    const short* __restrict__ Xf, const short* __restrict__ OWbf,
    float* __restrict__ Zp)
{
    const int tid = threadIdx.x;
    const int wv = tid >> 6;
    const int l  = tid & 63;
    const int l15 = l & 15, l4 = l >> 4;
    const int mtile = blockIdx.x * 4 + wv;
    const int d = blockIdx.y;

    const bf16x8* Ah = (const bf16x8*)Xf + (size_t)mtile * 32 * 64 + l4 * 16 + l15;
    const bf16x8* Al = Ah + 32768;
    const bf16x8* Bb = (const bf16x8*)OWbf + (size_t)d * 7 * 32 * 64 + l4 * 16 + l15;

    f32x4 acc[7];
    #pragma unroll
    for (int nt = 0; nt < 7; ++nt) acc[nt] = (f32x4){0.f, 0.f, 0.f, 0.f};

    for (int kb = 0; kb < 32; ++kb) {
        const bf16x8 ah = Ah[kb * 64];
        const bf16x8 al = Al[kb * 64];
        #pragma unroll
        for (int nt = 0; nt < 7; ++nt) {
            const bf16x8 b = Bb[(size_t)nt * 32 * 64 + kb * 64];
            acc[nt] = __builtin_amdgcn_mfma_f32_16x16x32_bf16(ah, b, acc[nt], 0, 0, 0);
            acc[nt] = __builtin_amdgcn_mfma_f32_16x16x32_bf16(al, b, acc[nt], 0, 0, 0);
        }
    }

    const int m0 = mtile * 16 + l4 * 4;
    #pragma unroll
    for (int nt = 0; nt < 7; ++nt) {
        const int oc = nt * 16 + l15;
        if (oc < 98) {
            #pragma unroll
            for (int r = 0; r < 4; ++r)
                Zp[((size_t)d * 256 + m0 + r) * 98 + oc] = acc[nt][r];
        }
    }
}

// ============ stage-1: scatter-sum Zp + compute (s, src) ====================
__global__ __launch_bounds__(256) void k_sparams_z1(
    const float* __restrict__ Zp, const float* __restrict__ OB,
    float* __restrict__ SW, int* __restrict__ SIDX)
{
    const int gid = blockIdx.x * 256 + threadIdx.x;
    if (gid >= 1024 * K49) return;
    const int pixL = gid / K49;
    const int k = gid - pixL * K49;
    const int b   = pixL >> 9;
    const int rem = pixL & 511;
    const int hp  = rem >> 5;
    const int wp  = rem & 31;

    float accy = OB[2 * k], accx = OB[2 * k + 1];
    const int di0 = (hp + 1) & 1, dj0 = (wp + 1) & 1;
    for (int di = di0; di < 7; di += 2) {
        const int yp = hp + di - 3;
        if ((unsigned)yp >= 16u) continue;
        const int ys = yp >> 1;
        for (int dj = dj0; dj < 7; dj += 2) {
            const int xp = wp + dj - 3;
            if ((unsigned)xp >= 32u) continue;
            const int xs = xp >> 1;
            const size_t o = ((size_t)((di * 7 + dj) * 256 + (b * 8 + ys) * 16 + xs)) * 98 + 2 * k;
            accy += Zp[o];
            accx += Zp[o + 1];
        }
    }
    const float y = (float)(hp + (k / 7) - 3) + accy;
    const float x = (float)(wp + (k % 7) - 3) + accx;
    const float fy0 = floorf(y), fx0 = floorf(x);
    const int iy0 = (int)fy0, ix0 = (int)fx0;
    const float wy1 = y - fy0, wx1 = x - fx0;
    int ye, xe; float wy, wx;
    if (iy0 & 1) { ye = iy0 + 1; wy = wy1; } else { ye = iy0; wy = 1.f - wy1; }
    if (ix0 & 1) { xe = ix0 + 1; wx = wx1; } else { xe = ix0; wx = 1.f - wx1; }
    float s = wy * wx;
    int src = 0;
    if (ye >= 0 && ye < 16 && xe >= 0 && xe < 32)
        src = (b * 8 + (ye >> 1)) * 16 + (xe >> 1);
    else
        s = 0.f;
    SW[gid] = s;
    SIDX[gid] = src;
}

// ============ generic fp32 -> bf16 hi/lo planes (natural [pix][c] order) ====
__global__ __launch_bounds__(256) void k_cvt_xbf(
    const float* __restrict__ x, short* __restrict__ dst, const int n)
{
    const int gid = blockIdx.x * 256 + threadIdx.x;
    if (gid >= n) return;
    const float v = x[gid];
    const short hi = f2bf(v);
    dst[gid] = hi;
    dst[n + gid] = f2bf(v - bf2f(hi));
}

// ============ pack OW (7,7,C,98) into per-class B-fragments =================
// OWf layout: [kbg][nt(7)][kg(4)][ni(16)][8] ; kbg runs over classes' K-blocks
template<int C>
__global__ __launch_bounds__(256) void k_cvt_owf(
    const float* __restrict__ OW, short* __restrict__ OWf, const int total)
{
    const int gid = blockIdx.x * 256 + threadIdx.x;
    if (gid >= total) return;
    const int j = gid & 7;
    int t = gid >> 3;
    const int fi = t & 63; t >>= 6;
    const int nt = t % 7;
    const int kbg = t / 7;
    const int ni = fi & 15, kg = fi >> 4;

    // class cumulative kb offsets
    int cum1, cum2, cum3;
    if (C == 64)      { cum1 = 18; cum2 = 42; cum3 = 66; }
    else if (C == 32) { cum1 = 9;  cum2 = 21; cum3 = 33; }
    else              { cum1 = 5;  cum2 = 11; cum3 = 17; }
    int cls, kb0;
    if (kbg < cum1)      { cls = 0; kb0 = 0; }
    else if (kbg < cum2) { cls = 1; kb0 = cum1; }
    else if (kbg < cum3) { cls = 2; kb0 = cum2; }
    else                 { cls = 3; kb0 = cum3; }
    const int kbl = kbg - kb0;
    const int pi = cls >> 1, rho = cls & 1;
    const int NRc = pi ? 4 : 3, NCc = rho ? 4 : 3;
    const int T = NRc * NCc;

    const int k = kbl * 32 + kg * 8 + j;
    const int tl = k / C, c = k - tl * C;
    const int oc = nt * 16 + ni;
    float v = 0.f;
    if (tl < T && oc < 98) {
        const int iy = tl / NCc, ix = tl - iy * NCc;
        const int d = (1 - pi + 2 * iy) * 7 + (1 - rho + 2 * ix);
        v = OW[((size_t)d * C + c) * 98 + oc];
    }
    OWf[gid] = f2bf(v);
}

// ============ offset conv via implicit-GEMM MFMA (stages 2-4) ===============
// Per class (grid.y): off[pix][98] = sum_{t in class} X[src_t] . OW[d_t]
// A gathered per-lane from global bf16 hi/lo planes; B pre-packed fragments.
template<int C>
__global__ __launch_bounds__(256) void k_offmfma(
    const short* __restrict__ Xbf,    // hi plane, lo plane at +nX
    const short* __restrict__ OWf,
    float* __restrict__ off,          // [npix_chunk][98]
    const int H, const int W, const int Hp, const int Wp,
    const int rowbase, const int pix0off, const int nX)
{
    const int tid = threadIdx.x;
    const int wv = tid >> 6;
    const int l  = tid & 63;
    const int l15 = l & 15, l4 = l >> 4;
    const int cls = blockIdx.y;
    const int pi = cls >> 1, rho = cls & 1;
    const int NRc = pi ? 4 : 3, NCc = rho ? 4 : 3;
    const int T = NRc * NCc;
    int nkb, clsoff;
    if (C == 64)      { nkb = T * 2;        clsoff = cls == 0 ? 0 : cls == 1 ? 18 : cls == 2 ? 42 : 66; }
    else if (C == 32) { nkb = T;            clsoff = cls == 0 ? 0 : cls == 1 ? 9  : cls == 2 ? 21 : 33; }
    else              { nkb = (T + 1) >> 1; clsoff = cls == 0 ? 0 : cls == 1 ? 5  : cls == 2 ? 11 : 17; }

    const int Wt16 = W >> 4;
    const int mt = blockIdx.x * 4 + wv;
    const int rloc = mt / Wt16, xt = mt - rloc * Wt16;
    const int g = rowbase + rloc;
    const int b = g / H;
    const int ysp = g - b * H;

    f32x4 acc[7];
    #pragma unroll
    for (int nt = 0; nt < 7; ++nt) acc[nt] = (f32x4){0.f, 0.f, 0.f, 0.f};

    const bf16x8* Bbase = (const bf16x8*)OWf + ((size_t)clsoff * 7) * 64 + l4 * 16 + l15;

    for (int kb = 0; kb < nkb; ++kb) {
        int tl, c0;
        if (C == 64)      { tl = kb >> 1;            c0 = ((kb & 1) << 5) + l4 * 8; }
        else if (C == 32) { tl = kb;                 c0 = l4 * 8; }
        else              { tl = kb * 2 + (l4 >> 1); c0 = (l4 & 1) * 8; if (tl >= T) tl = T - 1; }
        int iy, ix;
        if (NCc == 4) { iy = tl >> 2; ix = tl & 3; }
        else          { iy = tl / 3;  ix = tl - iy * 3; }
        const int ys = ysp + iy - 1;
        const int xs = xt * 16 + l15 + ix - 1;
        bf16x8 ah = {0, 0, 0, 0, 0, 0, 0, 0};
        bf16x8 al = {0, 0, 0, 0, 0, 0, 0, 0};
        if ((unsigned)ys < (unsigned)H && (unsigned)xs < (unsigned)W) {
            const size_t a = ((size_t)(b * H + ys) * W + xs) * C + c0;
            ah = *(const bf16x8*)(Xbf + a);
            al = *(const bf16x8*)(Xbf + nX + a);
        }
        const bf16x8* Bb = Bbase + (size_t)kb * 7 * 64;
        #pragma unroll
        for (int nt = 0; nt < 7; ++nt) {
            const bf16x8 bf = Bb[nt * 64];
            acc[nt] = __builtin_amdgcn_mfma_f32_16x16x32_bf16(ah, bf, acc[nt], 0, 0, 0);
            acc[nt] = __builtin_amdgcn_mfma_f32_16x16x32_bf16(al, bf, acc[nt], 0, 0, 0);
        }
    }

    const int hp = 2 * ysp + pi;
    const int wpbase = (xt << 5) + rho;
    const int pixrow = (b * Hp + hp) * Wp + wpbase - pix0off;
    #pragma unroll
    for (int nt = 0; nt < 7; ++nt) {
        const int oc = nt * 16 + l15;
        if (oc < 98) {
            #pragma unroll
            for (int r = 0; r < 4; ++r) {
                const int m = l4 * 4 + r;
                off[(size_t)(pixrow + 2 * m) * 98 + oc] = acc[nt][r];
            }
        }
    }
}

// ============ reduce offset + compute (s, src) per (pixel, tap) ====
__global__ __launch_bounds__(256) void k_sparams(
    const float* __restrict__ part_off, const float* __restrict__ OB,
    float* __restrict__ SW, int* __restrict__ SIDX,
    const int npix, const int CG,
    const int H, const int W, const int Hp, const int Wp, const int pix0)
{
    const int gid = blockIdx.x * 256 + threadIdx.x;
    if (gid >= npix * K49) return;
    const int pixL = gid / K49;
    const int k = gid - pixL * K49;
    float accy = OB[2 * k], accx = OB[2 * k + 1];
    for (int g = 0; g < CG; ++g) {
        const size_t base = ((size_t)g * npix + pixL) * 98 + 2 * k;
        accy += part_off[base];
        accx += part_off[base + 1];
    }
    const int pixg = pix0 + pixL;
    const int HWp = Hp * Wp;
    const int b = pixg / HWp;
    const int rem = pixg - b * HWp;
    const int hp = rem / Wp;
    const int wp = rem - hp * Wp;

    const float y = (float)(hp + (k / 7) - 3) + accy;
    const float x = (float)(wp + (k % 7) - 3) + accx;
    const float fy0 = floorf(y), fx0 = floorf(x);
    const int iy0 = (int)fy0, ix0 = (int)fx0;
    const float wy1 = y - fy0, wx1 = x - fx0;
    int ye, xe; float wy, wx;
    if (iy0 & 1) { ye = iy0 + 1; wy = wy1; } else { ye = iy0; wy = 1.f - wy1; }
    if (ix0 & 1) { xe = ix0 + 1; wx = wx1; } else { xe = ix0; wx = 1.f - wx1; }
    float s = wy * wx;
    int src = 0;
    if (ye >= 0 && ye < Hp && xe >= 0 && xe < Wp)
        src = (b * H + (ye >> 1)) * W + (xe >> 1);
    else
        s = 0.f;
    SW[gid] = s;
    SIDX[gid] = src;
}

// ============ per-tap GEMM: Y[kg][k][m*F+f] = X[m,:] . W[k][:,f] ============
template<int C, int F, int KSPLIT>
__global__ __launch_bounds__(256) void k_ygemm(
    const float* __restrict__ X,    // [M, C]
    const float* __restrict__ Wt,   // [49, C, F]
    float* __restrict__ Yout,       // [KSPLIT][49][M*F]
    const int M)
{
    constexpr int TILE_M = 4096 / F;
    constexpr int CC = 32;
    constexpr int KC = C / KSPLIT;
    constexpr int NF = F / 4;
    constexpr int LDM = TILE_M + 4;

    __shared__ float Xs[CC][LDM];
    __shared__ float Ws[CC][F];

    const int tid = threadIdx.x;
    const int f0 = (tid % NF) * 4;
    const int m0 = (tid / NF) * 4;
    const int mb = blockIdx.x * TILE_M;
    const int k  = blockIdx.y;
    const int cg = blockIdx.z;
    const int cbase = cg * KC;

    float acc[4][4];
    #pragma unroll
    for (int j = 0; j < 4; ++j)
        #pragma unroll
        for (int i = 0; i < 4; ++i) acc[j][i] = 0.f;

    for (int c0 = 0; c0 < KC; c0 += CC) {
        for (int e = tid; e < TILE_M * (CC / 4); e += 256) {
            const int m = e / (CC / 4);
            const int c4 = (e % (CC / 4)) * 4;
            const float4 v = *(const float4*)&X[(size_t)(mb + m) * C + cbase + c0 + c4];
            Xs[c4 + 0][m] = v.x;
            Xs[c4 + 1][m] = v.y;
            Xs[c4 + 2][m] = v.z;
            Xs[c4 + 3][m] = v.w;
        }
        const float* wg = Wt + ((size_t)k * C + cbase + c0) * F;
        for (int t = tid; t < CC * F / 4; t += 256)
            ((float4*)Ws)[t] = ((const float4*)wg)[t];
        __syncthreads();
        #pragma unroll
        for (int cc = 0; cc < CC; ++cc) {
            const float4 xv = *(const float4*)&Xs[cc][m0];
            const float4 wv = *(const float4*)&Ws[cc][f0];
            acc[0][0] = fmaf(xv.x, wv.x, acc[0][0]);
            acc[0][1] = fmaf(xv.x, wv.y, acc[0][1]);
            acc[0][2] = fmaf(xv.x, wv.z, acc[0][2]);
            acc[0][3] = fmaf(xv.x, wv.w, acc[0][3]);
            acc[1][0] = fmaf(xv.y, wv.x, acc[1][0]);
            acc[1][1] = fmaf(xv.y, wv.y, acc[1][1]);
            acc[1][2] = fmaf(xv.y, wv.z, acc[1][2]);
            acc[1][3] = fmaf(xv.y, wv.w, acc[1][3]);
            acc[2][0] = fmaf(xv.z, wv.x, acc[2][0]);
            acc[2][1] = fmaf(xv.z, wv.y, acc[2][1]);
            acc[2][2] = fmaf(xv.z, wv.z, acc[2][2]);
            acc[2][3] = fmaf(xv.z, wv.w, acc[2][3]);
            acc[3][0] = fmaf(xv.w, wv.x, acc[3][0]);
            acc[3][1] = fmaf(xv.w, wv.y, acc[3][1]);
            acc[3][2] = fmaf(xv.w, wv.z, acc[3][2]);
            acc[3][3] = fmaf(xv.w, wv.w, acc[3][3]);
        }
        __syncthreads();
    }
    float* yb = Yout + ((size_t)(cg * K49 + k)) * M * F;
    #pragma unroll
    for (int j = 0; j < 4; ++j) {
        float4 o = make_float4(acc[j][0], acc[j][1], acc[j][2], acc[j][3]);
        *(float4*)&yb[(size_t)(mb + m0 + j) * F + f0] = o;
    }
}

// ============ sum KSPLIT partial Y slabs ============
__global__ __launch_bounds__(256) void k_reduceY(
    const float* __restrict__ partial, float* __restrict__ Y,
    const int n, const int G)
{
    const int gid = blockIdx.x * 256 + threadIdx.x;
    if (gid >= n) return;
    float a = 0.f;
    for (int g = 0; g < G; ++g) a += partial[(size_t)g * n + gid];
    Y[gid] = a;
}

// ============ combine: out[pix,f] = relu(b_f + sum_k s_k * Y[k][src_k*F+f]) =
template<int F>
__global__ __launch_bounds__(256) void k_combine(
    const float* __restrict__ Y,   // [49][nsrc*F]
    const float* __restrict__ SW, const int* __restrict__ SIDX,
    const float* __restrict__ bias, float* __restrict__ out,
    const int nsrc, const int do_relu)
{
    constexpr int PPB = 256 / F;
    const int tid = threadIdx.x;
    const int f = tid % F;
    const int pix = blockIdx.x * PPB + tid / F;
    const size_t strideY = (size_t)nsrc * F;
    float acc = bias[f];
    #pragma unroll 7
    for (int k = 0; k < K49; ++k) {
        const float s = SW[(size_t)pix * K49 + k];
        const int src = SIDX[(size_t)pix * K49 + k];
        acc = fmaf(s, Y[(size_t)k * strideY + (size_t)src * F + f], acc);
    }
    out[(size_t)pix * F + f] = do_relu ? fmaxf(acc, 0.f) : acc;
}

// ============ stage 4 Y: Y4[k][src] = X3[src,:16] . W4[k,:16] ============
__global__ __launch_bounds__(256) void k_y4(
    const float* __restrict__ X,   // [M,16]
    const float* __restrict__ Wt,  // [49,16]
    float* __restrict__ Y,         // [49][M]
    const int M)
{
    __shared__ float Ws[K49 * 16];
    const int tid = threadIdx.x;
    for (int t = tid; t < K49 * 16; t += 256) Ws[t] = Wt[t];
    __syncthreads();
    const int src = blockIdx.x * 256 + tid;
    const float4* xr = (const float4*)(X + (size_t)src * 16);
    const float4 a0 = xr[0], a1 = xr[1], a2 = xr[2], a3 = xr[3];
    for (int k = 0; k < K49; ++k) {
        const float* wr = Ws + k * 16;
        float d = a0.x*wr[0]  + a0.y*wr[1]  + a0.z*wr[2]  + a0.w*wr[3]
                + a1.x*wr[4]  + a1.y*wr[5]  + a1.z*wr[6]  + a1.w*wr[7]
                + a2.x*wr[8]  + a2.y*wr[9]  + a2.z*wr[10] + a2.w*wr[11]
                + a3.x*wr[12] + a3.y*wr[13] + a3.z*wr[14] + a3.w*wr[15];
        Y[(size_t)k * M + src] = d;
    }
}

// ============ stage 4: fused sparams + gather-combine via Y4, 4-lane split ===
__global__ __launch_bounds__(256) void k_dconv_f1_y(
    const float* __restrict__ Y4,       // [49][nsrc]
    const float* __restrict__ part,     // [npix_chunk, 98] raw offset conv
    const float* __restrict__ OB,       // [98]
    const float* __restrict__ bias, float* __restrict__ out,
    const int H, const int W, const int Hp, const int Wp,
    const int pix0, const int nsrc)
{
    __shared__ float OBs[98];
    const int tid = threadIdx.x;
    if (tid < 98) OBs[tid] = OB[tid];
    __syncthreads();

    const int pixL = blockIdx.x * 64 + (tid >> 2);
    const int tq = tid & 3;
    const int t0 = (tq == 0) ? 0 : 13 + (tq - 1) * 12;
    const int t1 = t0 + ((tq == 0) ? 13 : 12);

    const int pixg = pix0 + pixL;
    const int HWp = Hp * Wp;
    const int b = pixg / HWp;
    const int rem = pixg - b * HWp;
    const int hp = rem / Wp;
    const int wp = rem - hp * Wp;

    float acc = 0.f;
    for (int k = t0; k < t1; ++k) {
        const float offy = part[(size_t)pixL * 98 + 2 * k]     + OBs[2 * k];
        const float offx = part[(size_t)pixL * 98 + 2 * k + 1] + OBs[2 * k + 1];
        const float y = (float)(hp + (k / 7) - 3) + offy;
        const float x = (float)(wp + (k % 7) - 3) + offx;
        const float fy0 = floorf(y), fx0 = floorf(x);
        const int iy0 = (int)fy0, ix0 = (int)fx0;
        const float wy1 = y - fy0, wx1 = x - fx0;
        int ye, xe; float wy, wx;
        if (iy0 & 1) { ye = iy0 + 1; wy = wy1; } else { ye = iy0; wy = 1.f - wy1; }
        if (ix0 & 1) { xe = ix0 + 1; wx = wx1; } else { xe = ix0; wx = 1.f - wx1; }
        float s = wy * wx;
        int src = 0;
        if (ye >= 0 && ye < Hp && xe >= 0 && xe < Wp)
            src = (b * H + (ye >> 1)) * W + (xe >> 1);
        else
            s = 0.f;
        acc = fmaf(s, Y4[(size_t)k * nsrc + src], acc);
    }
    acc += __shfl_xor(acc, 1);
    acc += __shfl_xor(acc, 2);
    if (tq == 0) out[pixg] = acc + bias[0];
}

extern "C" void kernel_launch(void* const* d_in, const int* in_sizes, int n_in,
                              void* d_out, int out_size, void* d_ws, size_t ws_size,
                              hipStream_t stream) {
    const float* z   = (const float*)d_in[0];
    const float* dw  = (const float*)d_in[1];
    const float* db  = (const float*)d_in[2];
    const float* ow1 = (const float*)d_in[3];
    const float* ob1 = (const float*)d_in[4];
    const float* w1  = (const float*)d_in[5];
    const float* b1  = (const float*)d_in[6];
    const float* ow2 = (const float*)d_in[7];
    const float* ob2 = (const float*)d_in[8];
    const float* w2  = (const float*)d_in[9];
    const float* b2  = (const float*)d_in[10];
    const float* ow3 = (const float*)d_in[11];
    const float* ob3 = (const float*)d_in[12];
    const float* w3  = (const float*)d_in[13];
    const float* b3  = (const float*)d_in[14];
    const float* ow4 = (const float*)d_in[15];
    const float* ob4 = (const float*)d_in[16];
    const float* w4  = (const float*)d_in[17];
    const float* b4  = (const float*)d_in[18];

    // workspace layout (floats): total 6,537,216 floats = 26.1 MB
    float* ws   = (float*)d_ws;
    float* x0   = ws;                      // 262144
    float* x1   = x0 + 262144;             // 65536
    float* x2   = x1 + 65536;              // 131072
    float* x3   = x2 + 131072;             // 262144
    float* sw   = x3 + 262144;             // 802816  (also hosts stage-1 Xf pre-sparams)
    int*   sidx = (int*)(sw + 802816);     // 802816
    float* part = (float*)(sidx + 802816); // 3407872
    float* Ybuf = part + 3407872;          // 802816

    float* out = (float*)d_out;

    // ---- dense + relu ----
    k_dense_relu<<<512, 256, 0, stream>>>(z, dw, db, x0);

    // ---- stage 1: x0 -> x1 (nsrc=256, npix=1024) ----
    {
        const int npix = 1024, nsrc = 256;
        short* Xf   = (short*)sw;
        short* OWbf = (short*)part;                  // 5,619,712 shorts
        float* Zp   = part + 2809856;                // 1,229,312 floats (spills into Ybuf; OK)
        k_cvt_x<<<128, 256, 0, stream>>>(x0, Xf);
        k_cvt_ow1<<<2744, 256, 0, stream>>>(ow1, OWbf);
        k_zgemm1_mfma<<<dim3(4, 49), 256, 0, stream>>>(Xf, OWbf, Zp);
        k_sparams_z1<<<(npix * K49 + 255) / 256, 256, 0, stream>>>(Zp, ob1, sw, sidx);
        dim3 gy(nsrc * 64 / 4096, K49, 4);
        k_ygemm<1024, 64, 4><<<gy, 256, 0, stream>>>(x0, w1, part, nsrc);
        const int nY = K49 * nsrc * 64;
        k_reduceY<<<(nY + 255) / 256, 256, 0, stream>>>(part, Ybuf, nY, 4);
        k_combine<64><<<npix * 64 / 256, 256, 0, stream>>>(Ybuf, sw, sidx, b1, x1, nsrc, 1);
    }

    // ---- stage 2: x1 -> x2 (nsrc=1024, npix=4096, C=64) ----
    {
        const int H = 16, W = 32, Hp = 32, Wp = 64, npix = 4096, nsrc = 1024;
        float* off2  = part + 1703936;               // 401,408 f
        short* Xbf1  = (short*)(part + 2203648);     // 131,072 shorts
        short* OWf2  = (short*)(part + 2301952);     // 351,232 shorts
        k_cvt_xbf<<<(65536 + 255) / 256, 256, 0, stream>>>(x1, Xbf1, 65536);
        k_cvt_owf<64><<<(351232 + 255) / 256, 256, 0, stream>>>(ow2, OWf2, 351232);
        k_offmfma<64><<<dim3(16, 4), 256, 0, stream>>>(Xbf1, OWf2, off2, H, W, Hp, Wp, 0, 0, 65536);
        k_sparams<<<(npix * K49 + 255) / 256, 256, 0, stream>>>(off2, ob2, sw, sidx, npix, 1, H, W, Hp, Wp, 0);
        dim3 gy(nsrc * 32 / 4096, K49, 1);
        k_ygemm<64, 32, 1><<<gy, 256, 0, stream>>>(x1, w2, part, nsrc);   // Y2 at part+0
        k_combine<32><<<npix * 32 / 256, 256, 0, stream>>>(part, sw, sidx, b2, x2, nsrc, 1);
    }

    // ---- stage 3: x2 -> x3 (nsrc=4096, npix=16384, C=32) ----
    {
        const int H = 32, W = 64, Hp = 64, Wp = 128, npix = 16384, nsrc = 4096;
        float* off3  = part;                         // 1,605,632 f
        short* Xbf2  = (short*)(part + 1605632);     // 262,144 shorts
        short* OWf3  = (short*)(part + 1736704);     // 175,616 shorts
        k_cvt_xbf<<<(131072 + 255) / 256, 256, 0, stream>>>(x2, Xbf2, 131072);
        k_cvt_owf<32><<<(175616 + 255) / 256, 256, 0, stream>>>(ow3, OWf3, 175616);
        k_offmfma<32><<<dim3(64, 4), 256, 0, stream>>>(Xbf2, OWf3, off3, H, W, Hp, Wp, 0, 0, 131072);
        k_sparams<<<(npix * K49 + 255) / 256, 256, 0, stream>>>(off3, ob3, sw, sidx, npix, 1, H, W, Hp, Wp, 0);
        dim3 gy(nsrc * 16 / 4096, K49, 1);
        k_ygemm<32, 16, 1><<<gy, 256, 0, stream>>>(x2, w3, part, nsrc);   // Y3 at part+0 (3.2M f)
        k_combine<16><<<npix * 16 / 256, 256, 0, stream>>>(part, sw, sidx, b3, x3, nsrc, 1);
    }

    // ---- stage 4: x3 -> out (nsrc=16384, C=16), 4 chunks of 16384 px ----
    {
        const int H = 64, W = 128, Hp = 128, Wp = 256, CHUNK = 16384, nsrc = 16384;
        short* Xbf3 = (short*)part;                  // 524,288 shorts
        short* OWf4 = (short*)(part + 262144);       // 89,600 shorts
        float* off4 = part + 327680;                 // 1,605,632 f per chunk
        k_y4<<<nsrc / 256, 256, 0, stream>>>(x3, w4, Ybuf, nsrc);
        k_cvt_xbf<<<(262144 + 255) / 256, 256, 0, stream>>>(x3, Xbf3, 262144);
        k_cvt_owf<16><<<(89600 + 255) / 256, 256, 0, stream>>>(ow4, OWf4, 89600);
        for (int c = 0; c < 4; ++c) {
            const int pix0 = c * CHUNK;
            // chunk covers source rows [c*32, c*32+32) (global b*H+ys' index)
            k_offmfma<16><<<dim3(64, 4), 256, 0, stream>>>(Xbf3, OWf4, off4, H, W, Hp, Wp, c * 32, pix0, 262144);
            k_dconv_f1_y<<<CHUNK / 64, 256, 0, stream>>>(Ybuf, off4, ob4, b4, out, H, W, Hp, Wp, pix0, nsrc);
        }
    }
}

// Round 9
// 257.753 us; speedup vs baseline: 1.2769x; 1.0417x over previous
//
#include <hip/hip_runtime.h>
#include <hip/hip_bf16.h>

#define K49 49

typedef short bf16x8 __attribute__((ext_vector_type(8)));
typedef float f32x4 __attribute__((ext_vector_type(4)));

__device__ __forceinline__ short f2bf(float x) {
    __hip_bfloat16 h = __float2bfloat16(x);
    return __builtin_bit_cast(short, h);
}
__device__ __forceinline__ float bf2f(short s) {
    unsigned u = ((unsigned)(unsigned short)s) << 16;
    return __builtin_bit_cast(float, u);
}

// ============ dense (z @ W + b) + relu -> x0 [2,8,16,1024] ============
__global__ __launch_bounds__(256) void k_dense_relu(
    const float* __restrict__ z, const float* __restrict__ Wd,
    const float* __restrict__ bd, float* __restrict__ x0)
{
    const int D = 131072;
    __shared__ float zs[256];
    const int tid = threadIdx.x;
    zs[tid] = z[tid];
    __syncthreads();
    const int n = blockIdx.x * 256 + tid;
    const float bb = bd[n];
    float a0 = bb, a1 = bb;
    #pragma unroll 8
    for (int kk = 0; kk < 128; ++kk) {
        const float w = Wd[kk * D + n];
        a0 = fmaf(zs[kk], w, a0);
        a1 = fmaf(zs[128 + kk], w, a1);
    }
    x0[n]     = fmaxf(a0, 0.f);
    x0[D + n] = fmaxf(a1, 0.f);
}

// ============ convert x0 -> fragment-packed bf16 hi/lo planes (stage 1) =====
// Xf layout (bf16): [plane(2)][mtile(16)][kb(32)][kg(4)][mi(16)][8]
__global__ __launch_bounds__(256) void k_cvt_x(
    const float* __restrict__ x0, short* __restrict__ Xf)
{
    const int gid = blockIdx.x * 256 + threadIdx.x;   // 32768 total
    const int m = gid >> 7;
    const int kg8 = gid & 127;
    const int mtile = m >> 4, mi = m & 15;
    const int kb = kg8 >> 2, kg = kg8 & 3;
    const size_t dst = ((((size_t)mtile * 32 + kb) * 4 + kg) * 16 + mi) * 8;
    const float4* src = (const float4*)(x0 + (size_t)m * 1024 + kg8 * 8);
    const float4 v0 = src[0], v1 = src[1];
    float vals[8] = {v0.x, v0.y, v0.z, v0.w, v1.x, v1.y, v1.z, v1.w};
    short hi[8], lo[8];
    #pragma unroll
    for (int j = 0; j < 8; ++j) {
        hi[j] = f2bf(vals[j]);
        lo[j] = f2bf(vals[j] - bf2f(hi[j]));
    }
    *(bf16x8*)(Xf + dst) = *(bf16x8*)hi;
    *(bf16x8*)(Xf + 262144 + dst) = *(bf16x8*)lo;
}

// ============ convert OW1 -> fragment-packed bf16 (stage 1) ======
// OWbf layout (bf16): [d(49)][nt(7)][kb(32)][kg(4)][ni(16)][8] ; oc = nt*16+ni
__global__ __launch_bounds__(256) void k_cvt_ow1(
    const float* __restrict__ OW, short* __restrict__ OWbf)
{
    const int gid = blockIdx.x * 256 + threadIdx.x;   // 702464 total
    if (gid >= 49 * 7 * 32 * 4 * 16) return;
    const int ni = gid & 15;
    int t = gid >> 4;
    const int kg = t & 3;  t >>= 2;
    const int kb = t & 31; t >>= 5;
    const int nt = t % 7;
    const int d  = t / 7;
    const int oc = nt * 16 + ni;
    short h[8];
    if (oc < 98) {
        const int c0 = kb * 32 + kg * 8;
        #pragma unroll
        for (int j = 0; j < 8; ++j)
            h[j] = f2bf(OW[((size_t)d * 1024 + c0 + j) * 98 + oc]);
    } else {
        #pragma unroll
        for (int j = 0; j < 8; ++j) h[j] = 0;
    }
    *(bf16x8*)(OWbf + (size_t)gid * 8) = *(bf16x8*)h;
}

// ============ convert w1 -> fragment-packed bf16 hi/lo B-frags (stage 1) ====
// W1f layout (bf16): [plane(2)][d(49)][nt(4)][kb(32)][kg(4)][ni(16)][8]
__global__ __launch_bounds__(256) void k_cvt_w1(
    const float* __restrict__ Wt, short* __restrict__ W1f)
{
    const int gid = blockIdx.x * 256 + threadIdx.x;   // 401408 total
    if (gid >= 49 * 4 * 32 * 4 * 16) return;
    const int ni = gid & 15;
    int t = gid >> 4;
    const int kg = t & 3;  t >>= 2;
    const int kb = t & 31; t >>= 5;
    const int nt = t & 3;
    const int d  = t >> 2;
    const int f = nt * 16 + ni;
    const int c0 = kb * 32 + kg * 8;
    short hi[8], lo[8];
    #pragma unroll
    for (int j = 0; j < 8; ++j) {
        const float v = Wt[((size_t)d * 1024 + c0 + j) * 64 + f];
        hi[j] = f2bf(v);
        lo[j] = f2bf(v - bf2f(hi[j]));
    }
    *(bf16x8*)(W1f + (size_t)gid * 8) = *(bf16x8*)hi;
    *(bf16x8*)(W1f + 3211264 + (size_t)gid * 8) = *(bf16x8*)lo;
}

// ============ stage-1 offset conv: MFMA GEMM over taps ============
__global__ __launch_bounds__(256) void k_zgemm1_mfma(
    const short* __restrict__ Xf, const short* __restrict__ OWbf,
    float* __restrict__ Zp)
{
    const int tid = threadIdx.x;
    const int wv = tid >> 6;
    const int l  = tid & 63;
    const int l15 = l & 15, l4 = l >> 4;
    const int mtile = blockIdx.x * 4 + wv;
    const int d = blockIdx.y;

    const bf16x8* Ah = (const bf16x8*)Xf + (size_t)mtile * 32 * 64 + l4 * 16 + l15;
    const bf16x8* Al = Ah + 32768;
    const bf16x8* Bb = (const bf16x8*)OWbf + (size_t)d * 7 * 32 * 64 + l4 * 16 + l15;

    f32x4 acc[7];
    #pragma unroll
    for (int nt = 0; nt < 7; ++nt) acc[nt] = (f32x4){0.f, 0.f, 0.f, 0.f};

    for (int kb = 0; kb < 32; ++kb) {
        const bf16x8 ah = Ah[kb * 64];
        const bf16x8 al = Al[kb * 64];
        #pragma unroll
        for (int nt = 0; nt < 7; ++nt) {
            const bf16x8 b = Bb[(size_t)nt * 32 * 64 + kb * 64];
            acc[nt] = __builtin_amdgcn_mfma_f32_16x16x32_bf16(ah, b, acc[nt], 0, 0, 0);
            acc[nt] = __builtin_amdgcn_mfma_f32_16x16x32_bf16(al, b, acc[nt], 0, 0, 0);
        }
    }

    const int m0 = mtile * 16 + l4 * 4;
    #pragma unroll
    for (int nt = 0; nt < 7; ++nt) {
        const int oc = nt * 16 + l15;
        if (oc < 98) {
            #pragma unroll
            for (int r = 0; r < 4; ++r)
                Zp[((size_t)d * 256 + m0 + r) * 98 + oc] = acc[nt][r];
        }
    }
}

// ============ stage-1 Y GEMM via MFMA: Y[d][m][f], 3-term hi/lo ============
__global__ __launch_bounds__(256) void k_ygemm1_mfma(
    const short* __restrict__ Xf, const short* __restrict__ W1f,
    float* __restrict__ Y)
{
    const int tid = threadIdx.x;
    const int wv = tid >> 6;
    const int l  = tid & 63;
    const int l15 = l & 15, l4 = l >> 4;
    const int mtile = blockIdx.x * 4 + wv;
    const int d = blockIdx.y;

    const bf16x8* Ah = (const bf16x8*)Xf + (size_t)mtile * 2048 + l4 * 16 + l15;
    const bf16x8* Al = Ah + 32768;
    const bf16x8* Bh = (const bf16x8*)W1f + (size_t)d * 4 * 2048 + l4 * 16 + l15;
    const bf16x8* Bl = Bh + 401408;

    f32x4 acc[4];
    #pragma unroll
    for (int nt = 0; nt < 4; ++nt) acc[nt] = (f32x4){0.f, 0.f, 0.f, 0.f};

    for (int kb = 0; kb < 32; ++kb) {
        const bf16x8 ah = Ah[kb * 64];
        const bf16x8 al = Al[kb * 64];
        #pragma unroll
        for (int nt = 0; nt < 4; ++nt) {
            const bf16x8 bh = Bh[nt * 2048 + kb * 64];
            const bf16x8 bl = Bl[nt * 2048 + kb * 64];
            acc[nt] = __builtin_amdgcn_mfma_f32_16x16x32_bf16(ah, bh, acc[nt], 0, 0, 0);
            acc[nt] = __builtin_amdgcn_mfma_f32_16x16x32_bf16(ah, bl, acc[nt], 0, 0, 0);
            acc[nt] = __builtin_amdgcn_mfma_f32_16x16x32_bf16(al, bh, acc[nt], 0, 0, 0);
        }
    }

    const int m0 = mtile * 16 + l4 * 4;
    #pragma unroll
    for (int nt = 0; nt < 4; ++nt) {
        const int f = nt * 16 + l15;
        #pragma unroll
        for (int r = 0; r < 4; ++r)
            Y[((size_t)d * 256 + m0 + r) * 64 + f] = acc[nt][r];
    }
}

// ============ stage-1: scatter-sum Zp + compute (s, src) ====================
__global__ __launch_bounds__(256) void k_sparams_z1(
    const float* __restrict__ Zp, const float* __restrict__ OB,
    float* __restrict__ SW, int* __restrict__ SIDX)
{
    const int gid = blockIdx.x * 256 + threadIdx.x;
    if (gid >= 1024 * K49) return;
    const int pixL = gid / K49;
    const int k = gid - pixL * K49;
    const int b   = pixL >> 9;
    const int rem = pixL & 511;
    const int hp  = rem >> 5;
    const int wp  = rem & 31;

    float accy = OB[2 * k], accx = OB[2 * k + 1];
    const int di0 = (hp + 1) & 1, dj0 = (wp + 1) & 1;
    for (int di = di0; di < 7; di += 2) {
        const int yp = hp + di - 3;
        if ((unsigned)yp >= 16u) continue;
        const int ys = yp >> 1;
        for (int dj = dj0; dj < 7; dj += 2) {
            const int xp = wp + dj - 3;
            if ((unsigned)xp >= 32u) continue;
            const int xs = xp >> 1;
            const size_t o = ((size_t)((di * 7 + dj) * 256 + (b * 8 + ys) * 16 + xs)) * 98 + 2 * k;
            accy += Zp[o];
            accx += Zp[o + 1];
        }
    }
    const float y = (float)(hp + (k / 7) - 3) + accy;
    const float x = (float)(wp + (k % 7) - 3) + accx;
    const float fy0 = floorf(y), fx0 = floorf(x);
    const int iy0 = (int)fy0, ix0 = (int)fx0;
    const float wy1 = y - fy0, wx1 = x - fx0;
    int ye, xe; float wy, wx;
    if (iy0 & 1) { ye = iy0 + 1; wy = wy1; } else { ye = iy0; wy = 1.f - wy1; }
    if (ix0 & 1) { xe = ix0 + 1; wx = wx1; } else { xe = ix0; wx = 1.f - wx1; }
    float s = wy * wx;
    int src = 0;
    if (ye >= 0 && ye < 16 && xe >= 0 && xe < 32)
        src = (b * 8 + (ye >> 1)) * 16 + (xe >> 1);
    else
        s = 0.f;
    SW[gid] = s;
    SIDX[gid] = src;
}

// ============ generic fp32 -> bf16 hi/lo planes (natural [pix][c] order) ====
__global__ __launch_bounds__(256) void k_cvt_xbf(
    const float* __restrict__ x, short* __restrict__ dst, const int n)
{
    const int gid = blockIdx.x * 256 + threadIdx.x;
    if (gid >= n) return;
    const float v = x[gid];
    const short hi = f2bf(v);
    dst[gid] = hi;
    dst[n + gid] = f2bf(v - bf2f(hi));
}

// ============ pack OW (7,7,C,98) into per-class B-fragments =================
// OWf layout: [kbg][nt(7)][kg(4)][ni(16)][8] ; kbg runs over classes' K-blocks
template<int C>
__global__ __launch_bounds__(256) void k_cvt_owf(
    const float* __restrict__ OW, short* __restrict__ OWf, const int total)
{
    const int gid = blockIdx.x * 256 + threadIdx.x;
    if (gid >= total) return;
    const int j = gid & 7;
    int t = gid >> 3;
    const int fi = t & 63; t >>= 6;
    const int nt = t % 7;
    const int kbg = t / 7;
    const int ni = fi & 15, kg = fi >> 4;

    int cum1, cum2, cum3;
    if (C == 64)      { cum1 = 18; cum2 = 42; cum3 = 66; }
    else if (C == 32) { cum1 = 9;  cum2 = 21; cum3 = 33; }
    else              { cum1 = 5;  cum2 = 11; cum3 = 17; }
    int cls, kb0;
    if (kbg < cum1)      { cls = 0; kb0 = 0; }
    else if (kbg < cum2) { cls = 1; kb0 = cum1; }
    else if (kbg < cum3) { cls = 2; kb0 = cum2; }
    else                 { cls = 3; kb0 = cum3; }
    const int kbl = kbg - kb0;
    const int pi = cls >> 1, rho = cls & 1;
    const int NRc = pi ? 4 : 3, NCc = rho ? 4 : 3;
    const int T = NRc * NCc;

    const int k = kbl * 32 + kg * 8 + j;
    const int tl = k / C, c = k - tl * C;
    const int oc = nt * 16 + ni;
    float v = 0.f;
    if (tl < T && oc < 98) {
        const int iy = tl / NCc, ix = tl - iy * NCc;
        const int d = (1 - pi + 2 * iy) * 7 + (1 - rho + 2 * ix);
        v = OW[((size_t)d * C + c) * 98 + oc];
    }
    OWf[gid] = f2bf(v);
}

// ============ offset conv via implicit-GEMM MFMA (stages 2-4) ===============
template<int C>
__global__ __launch_bounds__(256) void k_offmfma(
    const short* __restrict__ Xbf,    // hi plane, lo plane at +nX
    const short* __restrict__ OWf,
    float* __restrict__ off,          // [npix_chunk][98]
    const int H, const int W, const int Hp, const int Wp,
    const int rowbase, const int pix0off, const int nX)
{
    const int tid = threadIdx.x;
    const int wv = tid >> 6;
    const int l  = tid & 63;
    const int l15 = l & 15, l4 = l >> 4;
    const int cls = blockIdx.y;
    const int pi = cls >> 1, rho = cls & 1;
    const int NRc = pi ? 4 : 3, NCc = rho ? 4 : 3;
    const int T = NRc * NCc;
    int nkb, clsoff;
    if (C == 64)      { nkb = T * 2;        clsoff = cls == 0 ? 0 : cls == 1 ? 18 : cls == 2 ? 42 : 66; }
    else if (C == 32) { nkb = T;            clsoff = cls == 0 ? 0 : cls == 1 ? 9  : cls == 2 ? 21 : 33; }
    else              { nkb = (T + 1) >> 1; clsoff = cls == 0 ? 0 : cls == 1 ? 5  : cls == 2 ? 11 : 17; }

    const int Wt16 = W >> 4;
    const int mt = blockIdx.x * 4 + wv;
    const int rloc = mt / Wt16, xt = mt - rloc * Wt16;
    const int g = rowbase + rloc;
    const int b = g / H;
    const int ysp = g - b * H;

    f32x4 acc[7];
    #pragma unroll
    for (int nt = 0; nt < 7; ++nt) acc[nt] = (f32x4){0.f, 0.f, 0.f, 0.f};

    const bf16x8* Bbase = (const bf16x8*)OWf + ((size_t)clsoff * 7) * 64 + l4 * 16 + l15;

    for (int kb = 0; kb < nkb; ++kb) {
        int tl, c0;
        if (C == 64)      { tl = kb >> 1;            c0 = ((kb & 1) << 5) + l4 * 8; }
        else if (C == 32) { tl = kb;                 c0 = l4 * 8; }
        else              { tl = kb * 2 + (l4 >> 1); c0 = (l4 & 1) * 8; if (tl >= T) tl = T - 1; }
        int iy, ix;
        if (NCc == 4) { iy = tl >> 2; ix = tl & 3; }
        else          { iy = tl / 3;  ix = tl - iy * 3; }
        const int ys = ysp + iy - 1;
        const int xs = xt * 16 + l15 + ix - 1;
        bf16x8 ah = {0, 0, 0, 0, 0, 0, 0, 0};
        bf16x8 al = {0, 0, 0, 0, 0, 0, 0, 0};
        if ((unsigned)ys < (unsigned)H && (unsigned)xs < (unsigned)W) {
            const size_t a = ((size_t)(b * H + ys) * W + xs) * C + c0;
            ah = *(const bf16x8*)(Xbf + a);
            al = *(const bf16x8*)(Xbf + nX + a);
        }
        const bf16x8* Bb = Bbase + (size_t)kb * 7 * 64;
        #pragma unroll
        for (int nt = 0; nt < 7; ++nt) {
            const bf16x8 bf = Bb[nt * 64];
            acc[nt] = __builtin_amdgcn_mfma_f32_16x16x32_bf16(ah, bf, acc[nt], 0, 0, 0);
            acc[nt] = __builtin_amdgcn_mfma_f32_16x16x32_bf16(al, bf, acc[nt], 0, 0, 0);
        }
    }

    const int hp = 2 * ysp + pi;
    const int wpbase = (xt << 5) + rho;
    const int pixrow = (b * Hp + hp) * Wp + wpbase - pix0off;
    #pragma unroll
    for (int nt = 0; nt < 7; ++nt) {
        const int oc = nt * 16 + l15;
        if (oc < 98) {
            #pragma unroll
            for (int r = 0; r < 4; ++r) {
                const int m = l4 * 4 + r;
                off[(size_t)(pixrow + 2 * m) * 98 + oc] = acc[nt][r];
            }
        }
    }
}

// ============ reduce offset + compute (s, src) per (pixel, tap) ====
__global__ __launch_bounds__(256) void k_sparams(
    const float* __restrict__ part_off, const float* __restrict__ OB,
    float* __restrict__ SW, int* __restrict__ SIDX,
    const int npix, const int CG,
    const int H, const int W, const int Hp, const int Wp, const int pix0)
{
    const int gid = blockIdx.x * 256 + threadIdx.x;
    if (gid >= npix * K49) return;
    const int pixL = gid / K49;
    const int k = gid - pixL * K49;
    float accy = OB[2 * k], accx = OB[2 * k + 1];
    for (int g = 0; g < CG; ++g) {
        const size_t base = ((size_t)g * npix + pixL) * 98 + 2 * k;
        accy += part_off[base];
        accx += part_off[base + 1];
    }
    const int pixg = pix0 + pixL;
    const int HWp = Hp * Wp;
    const int b = pixg / HWp;
    const int rem = pixg - b * HWp;
    const int hp = rem / Wp;
    const int wp = rem - hp * Wp;

    const float y = (float)(hp + (k / 7) - 3) + accy;
    const float x = (float)(wp + (k % 7) - 3) + accx;
    const float fy0 = floorf(y), fx0 = floorf(x);
    const int iy0 = (int)fy0, ix0 = (int)fx0;
    const float wy1 = y - fy0, wx1 = x - fx0;
    int ye, xe; float wy, wx;
    if (iy0 & 1) { ye = iy0 + 1; wy = wy1; } else { ye = iy0; wy = 1.f - wy1; }
    if (ix0 & 1) { xe = ix0 + 1; wx = wx1; } else { xe = ix0; wx = 1.f - wx1; }
    float s = wy * wx;
    int src = 0;
    if (ye >= 0 && ye < Hp && xe >= 0 && xe < Wp)
        src = (b * H + (ye >> 1)) * W + (xe >> 1);
    else
        s = 0.f;
    SW[gid] = s;
    SIDX[gid] = src;
}

// ============ per-tap GEMM (fp32, stages 2-3) ============
template<int C, int F, int KSPLIT>
__global__ __launch_bounds__(256) void k_ygemm(
    const float* __restrict__ X,    // [M, C]
    const float* __restrict__ Wt,   // [49, C, F]
    float* __restrict__ Yout,       // [KSPLIT][49][M*F]
    const int M)
{
    constexpr int TILE_M = 4096 / F;
    constexpr int CC = 32;
    constexpr int KC = C / KSPLIT;
    constexpr int NF = F / 4;
    constexpr int LDM = TILE_M + 4;

    __shared__ float Xs[CC][LDM];
    __shared__ float Ws[CC][F];

    const int tid = threadIdx.x;
    const int f0 = (tid % NF) * 4;
    const int m0 = (tid / NF) * 4;
    const int mb = blockIdx.x * TILE_M;
    const int k  = blockIdx.y;
    const int cg = blockIdx.z;
    const int cbase = cg * KC;

    float acc[4][4];
    #pragma unroll
    for (int j = 0; j < 4; ++j)
        #pragma unroll
        for (int i = 0; i < 4; ++i) acc[j][i] = 0.f;

    for (int c0 = 0; c0 < KC; c0 += CC) {
        for (int e = tid; e < TILE_M * (CC / 4); e += 256) {
            const int m = e / (CC / 4);
            const int c4 = (e % (CC / 4)) * 4;
            const float4 v = *(const float4*)&X[(size_t)(mb + m) * C + cbase + c0 + c4];
            Xs[c4 + 0][m] = v.x;
            Xs[c4 + 1][m] = v.y;
            Xs[c4 + 2][m] = v.z;
            Xs[c4 + 3][m] = v.w;
        }
        const float* wg = Wt + ((size_t)k * C + cbase + c0) * F;
        for (int t = tid; t < CC * F / 4; t += 256)
            ((float4*)Ws)[t] = ((const float4*)wg)[t];
        __syncthreads();
        #pragma unroll
        for (int cc = 0; cc < CC; ++cc) {
            const float4 xv = *(const float4*)&Xs[cc][m0];
            const float4 wv = *(const float4*)&Ws[cc][f0];
            acc[0][0] = fmaf(xv.x, wv.x, acc[0][0]);
            acc[0][1] = fmaf(xv.x, wv.y, acc[0][1]);
            acc[0][2] = fmaf(xv.x, wv.z, acc[0][2]);
            acc[0][3] = fmaf(xv.x, wv.w, acc[0][3]);
            acc[1][0] = fmaf(xv.y, wv.x, acc[1][0]);
            acc[1][1] = fmaf(xv.y, wv.y, acc[1][1]);
            acc[1][2] = fmaf(xv.y, wv.z, acc[1][2]);
            acc[1][3] = fmaf(xv.y, wv.w, acc[1][3]);
            acc[2][0] = fmaf(xv.z, wv.x, acc[2][0]);
            acc[2][1] = fmaf(xv.z, wv.y, acc[2][1]);
            acc[2][2] = fmaf(xv.z, wv.z, acc[2][2]);
            acc[2][3] = fmaf(xv.z, wv.w, acc[2][3]);
            acc[3][0] = fmaf(xv.w, wv.x, acc[3][0]);
            acc[3][1] = fmaf(xv.w, wv.y, acc[3][1]);
            acc[3][2] = fmaf(xv.w, wv.z, acc[3][2]);
            acc[3][3] = fmaf(xv.w, wv.w, acc[3][3]);
        }
        __syncthreads();
    }
    float* yb = Yout + ((size_t)(cg * K49 + k)) * M * F;
    #pragma unroll
    for (int j = 0; j < 4; ++j) {
        float4 o = make_float4(acc[j][0], acc[j][1], acc[j][2], acc[j][3]);
        *(float4*)&yb[(size_t)(mb + m0 + j) * F + f0] = o;
    }
}

// ============ combine: out[pix,f] = relu(b_f + sum_k s_k * Y[k][src_k*F+f]) =
template<int F>
__global__ __launch_bounds__(256) void k_combine(
    const float* __restrict__ Y,   // [49][nsrc*F]
    const float* __restrict__ SW, const int* __restrict__ SIDX,
    const float* __restrict__ bias, float* __restrict__ out,
    const int nsrc, const int do_relu)
{
    constexpr int PPB = 256 / F;
    const int tid = threadIdx.x;
    const int f = tid % F;
    const int pix = blockIdx.x * PPB + tid / F;
    const size_t strideY = (size_t)nsrc * F;
    float acc = bias[f];
    #pragma unroll 7
    for (int k = 0; k < K49; ++k) {
        const float s = SW[(size_t)pix * K49 + k];
        const int src = SIDX[(size_t)pix * K49 + k];
        acc = fmaf(s, Y[(size_t)k * strideY + (size_t)src * F + f], acc);
    }
    out[(size_t)pix * F + f] = do_relu ? fmaxf(acc, 0.f) : acc;
}

// ============ stage 4 Y: Y4[k][src] = X3[src,:16] . W4[k,:16] ============
__global__ __launch_bounds__(256) void k_y4(
    const float* __restrict__ X,   // [M,16]
    const float* __restrict__ Wt,  // [49,16]
    float* __restrict__ Y,         // [49][M]
    const int M)
{
    __shared__ float Ws[K49 * 16];
    const int tid = threadIdx.x;
    for (int t = tid; t < K49 * 16; t += 256) Ws[t] = Wt[t];
    __syncthreads();
    const int src = blockIdx.x * 256 + tid;
    const float4* xr = (const float4*)(X + (size_t)src * 16);
    const float4 a0 = xr[0], a1 = xr[1], a2 = xr[2], a3 = xr[3];
    for (int k = 0; k < K49; ++k) {
        const float* wr = Ws + k * 16;
        float d = a0.x*wr[0]  + a0.y*wr[1]  + a0.z*wr[2]  + a0.w*wr[3]
                + a1.x*wr[4]  + a1.y*wr[5]  + a1.z*wr[6]  + a1.w*wr[7]
                + a2.x*wr[8]  + a2.y*wr[9]  + a2.z*wr[10] + a2.w*wr[11]
                + a3.x*wr[12] + a3.y*wr[13] + a3.z*wr[14] + a3.w*wr[15];
        Y[(size_t)k * M + src] = d;
    }
}

// ============ stage 4: fused sparams + gather-combine via Y4, 4-lane split ===
__global__ __launch_bounds__(256) void k_dconv_f1_y(
    const float* __restrict__ Y4,       // [49][nsrc]
    const float* __restrict__ part,     // [npix_chunk, 98] raw offset conv
    const float* __restrict__ OB,       // [98]
    const float* __restrict__ bias, float* __restrict__ out,
    const int H, const int W, const int Hp, const int Wp,
    const int pix0, const int nsrc)
{
    __shared__ float OBs[98];
    const int tid = threadIdx.x;
    if (tid < 98) OBs[tid] = OB[tid];
    __syncthreads();

    const int pixL = blockIdx.x * 64 + (tid >> 2);
    const int tq = tid & 3;
    const int t0 = (tq == 0) ? 0 : 13 + (tq - 1) * 12;
    const int t1 = t0 + ((tq == 0) ? 13 : 12);

    const int pixg = pix0 + pixL;
    const int HWp = Hp * Wp;
    const int b = pixg / HWp;
    const int rem = pixg - b * HWp;
    const int hp = rem / Wp;
    const int wp = rem - hp * Wp;

    float acc = 0.f;
    for (int k = t0; k < t1; ++k) {
        const float offy = part[(size_t)pixL * 98 + 2 * k]     + OBs[2 * k];
        const float offx = part[(size_t)pixL * 98 + 2 * k + 1] + OBs[2 * k + 1];
        const float y = (float)(hp + (k / 7) - 3) + offy;
        const float x = (float)(wp + (k % 7) - 3) + offx;
        const float fy0 = floorf(y), fx0 = floorf(x);
        const int iy0 = (int)fy0, ix0 = (int)fx0;
        const float wy1 = y - fy0, wx1 = x - fx0;
        int ye, xe; float wy, wx;
        if (iy0 & 1) { ye = iy0 + 1; wy = wy1; } else { ye = iy0; wy = 1.f - wy1; }
        if (ix0 & 1) { xe = ix0 + 1; wx = wx1; } else { xe = ix0; wx = 1.f - wx1; }
        float s = wy * wx;
        int src = 0;
        if (ye >= 0 && ye < Hp && xe >= 0 && xe < Wp)
            src = (b * H + (ye >> 1)) * W + (xe >> 1);
        else
            s = 0.f;
        acc = fmaf(s, Y4[(size_t)k * nsrc + src], acc);
    }
    acc += __shfl_xor(acc, 1);
    acc += __shfl_xor(acc, 2);
    if (tq == 0) out[pixg] = acc + bias[0];
}

extern "C" void kernel_launch(void* const* d_in, const int* in_sizes, int n_in,
                              void* d_out, int out_size, void* d_ws, size_t ws_size,
                              hipStream_t stream) {
    const float* z   = (const float*)d_in[0];
    const float* dw  = (const float*)d_in[1];
    const float* db  = (const float*)d_in[2];
    const float* ow1 = (const float*)d_in[3];
    const float* ob1 = (const float*)d_in[4];
    const float* w1  = (const float*)d_in[5];
    const float* b1  = (const float*)d_in[6];
    const float* ow2 = (const float*)d_in[7];
    const float* ob2 = (const float*)d_in[8];
    const float* w2  = (const float*)d_in[9];
    const float* b2  = (const float*)d_in[10];
    const float* ow3 = (const float*)d_in[11];
    const float* ob3 = (const float*)d_in[12];
    const float* w3  = (const float*)d_in[13];
    const float* b3  = (const float*)d_in[14];
    const float* ow4 = (const float*)d_in[15];
    const float* ob4 = (const float*)d_in[16];
    const float* w4  = (const float*)d_in[17];
    const float* b4  = (const float*)d_in[18];

    // workspace layout (floats): total 6,537,216 floats = 26.1 MB
    float* ws   = (float*)d_ws;
    float* x0   = ws;                      // 262144
    float* x1   = x0 + 262144;             // 65536
    float* x2   = x1 + 65536;              // 131072
    float* x3   = x2 + 131072;             // 262144
    float* sw   = x3 + 262144;             // 802816  (stage-1: sw[0..50176) + Xf at +50176)
    int*   sidx = (int*)(sw + 802816);     // 802816
    float* part = (float*)(sidx + 802816); // 3407872
    float* Ybuf = part + 3407872;          // 802816

    float* out = (float*)d_out;

    // ---- dense + relu ----
    k_dense_relu<<<512, 256, 0, stream>>>(z, dw, db, x0);

    // ---- stage 1: x0 -> x1 (nsrc=256, npix=1024) ----
    {
        const int npix = 1024, nsrc = 256;
        short* Xf   = (short*)(sw + 50176);          // 524,288 shorts, clear of sw[0..50176)
        short* OWbf = (short*)part;                  // 5,619,712 shorts
        float* Zp   = part + 2809856;                // 1,229,312 floats (tail in Ybuf; dead before Y1 write)
        short* W1f  = (short*)part;                  // 6,422,528 shorts (after Zp is dead)
        k_cvt_x<<<128, 256, 0, stream>>>(x0, Xf);
        k_cvt_ow1<<<2744, 256, 0, stream>>>(ow1, OWbf);
        k_zgemm1_mfma<<<dim3(4, 49), 256, 0, stream>>>(Xf, OWbf, Zp);
        k_sparams_z1<<<(npix * K49 + 255) / 256, 256, 0, stream>>>(Zp, ob1, sw, sidx);
        k_cvt_w1<<<(401408 + 255) / 256, 256, 0, stream>>>(w1, W1f);
        k_ygemm1_mfma<<<dim3(4, 49), 256, 0, stream>>>(Xf, W1f, Ybuf);
        k_combine<64><<<npix * 64 / 256, 256, 0, stream>>>(Ybuf, sw, sidx, b1, x1, nsrc, 1);
    }

    // ---- stage 2: x1 -> x2 (nsrc=1024, npix=4096, C=64) ----
    {
        const int H = 16, W = 32, Hp = 32, Wp = 64, npix = 4096, nsrc = 1024;
        float* off2  = part + 1703936;               // 401,408 f
        short* Xbf1  = (short*)(part + 2203648);     // 131,072 shorts
        short* OWf2  = (short*)(part + 2301952);     // 351,232 shorts
        k_cvt_xbf<<<(65536 + 255) / 256, 256, 0, stream>>>(x1, Xbf1, 65536);
        k_cvt_owf<64><<<(351232 + 255) / 256, 256, 0, stream>>>(ow2, OWf2, 351232);
        k_offmfma<64><<<dim3(16, 4), 256, 0, stream>>>(Xbf1, OWf2, off2, H, W, Hp, Wp, 0, 0, 65536);
        k_sparams<<<(npix * K49 + 255) / 256, 256, 0, stream>>>(off2, ob2, sw, sidx, npix, 1, H, W, Hp, Wp, 0);
        dim3 gy(nsrc * 32 / 4096, K49, 1);
        k_ygemm<64, 32, 1><<<gy, 256, 0, stream>>>(x1, w2, part, nsrc);   // Y2 at part+0
        k_combine<32><<<npix * 32 / 256, 256, 0, stream>>>(part, sw, sidx, b2, x2, nsrc, 1);
    }

    // ---- stage 3: x2 -> x3 (nsrc=4096, npix=16384, C=32) ----
    {
        const int H = 32, W = 64, Hp = 64, Wp = 128, npix = 16384, nsrc = 4096;
        float* off3  = part;                         // 1,605,632 f
        short* Xbf2  = (short*)(part + 1605632);     // 262,144 shorts
        short* OWf3  = (short*)(part + 1736704);     // 175,616 shorts
        k_cvt_xbf<<<(131072 + 255) / 256, 256, 0, stream>>>(x2, Xbf2, 131072);
        k_cvt_owf<32><<<(175616 + 255) / 256, 256, 0, stream>>>(ow3, OWf3, 175616);
        k_offmfma<32><<<dim3(64, 4), 256, 0, stream>>>(Xbf2, OWf3, off3, H, W, Hp, Wp, 0, 0, 131072);
        k_sparams<<<(npix * K49 + 255) / 256, 256, 0, stream>>>(off3, ob3, sw, sidx, npix, 1, H, W, Hp, Wp, 0);
        dim3 gy(nsrc * 16 / 4096, K49, 1);
        k_ygemm<32, 16, 1><<<gy, 256, 0, stream>>>(x2, w3, part, nsrc);   // Y3 at part+0
        k_combine<16><<<npix * 16 / 256, 256, 0, stream>>>(part, sw, sidx, b3, x3, nsrc, 1);
    }

    // ---- stage 4: x3 -> out (nsrc=16384, C=16), 4 chunks of 16384 px ----
    {
        const int H = 64, W = 128, Hp = 128, Wp = 256, CHUNK = 16384, nsrc = 16384;
        short* Xbf3 = (short*)part;                  // 524,288 shorts
        short* OWf4 = (short*)(part + 262144);       // 89,600 shorts
        float* off4 = part + 327680;                 // 1,605,632 f per chunk
        k_y4<<<nsrc / 256, 256, 0, stream>>>(x3, w4, Ybuf, nsrc);
        k_cvt_xbf<<<(262144 + 255) / 256, 256, 0, stream>>>(x3, Xbf3, 262144);
        k_cvt_owf<16><<<(89600 + 255) / 256, 256, 0, stream>>>(ow4, OWf4, 89600);
        for (int c = 0; c < 4; ++c) {
            const int pix0 = c * CHUNK;
            k_offmfma<16><<<dim3(64, 4), 256, 0, stream>>>(Xbf3, OWf4, off4, H, W, Hp, Wp, c * 32, pix0, 262144);
            k_dconv_f1_y<<<CHUNK / 64, 256, 0, stream>>>(Ybuf, off4, ob4, b4, out, H, W, Hp, Wp, pix0, nsrc);
        }
    }
}

// Round 10
// 191.303 us; speedup vs baseline: 1.7204x; 1.3474x over previous
//
#include <hip/hip_runtime.h>
#include <hip/hip_bf16.h>

#define K49 49

typedef short bf16x8 __attribute__((ext_vector_type(8)));
typedef float f32x4 __attribute__((ext_vector_type(4)));

__device__ __forceinline__ short f2bf(float x) {
    __hip_bfloat16 h = __float2bfloat16(x);
    return __builtin_bit_cast(short, h);
}
__device__ __forceinline__ float bf2f(short s) {
    unsigned u = ((unsigned)(unsigned short)s) << 16;
    return __builtin_bit_cast(float, u);
}

// ==================== weight packing (device fns) ====================
// ow1 -> OWbf: [d(49)][nt(7)][kb(32)][kg(4)][ni(16)][8]
__device__ __forceinline__ void d_pack_ow1(
    const int gid, const float* __restrict__ OW, short* __restrict__ OWbf)
{
    const int ni = gid & 15;
    int t = gid >> 4;
    const int kg = t & 3;  t >>= 2;
    const int kb = t & 31; t >>= 5;
    const int nt = t % 7;
    const int d  = t / 7;
    const int oc = nt * 16 + ni;
    short h[8];
    if (oc < 98) {
        const int c0 = kb * 32 + kg * 8;
        #pragma unroll
        for (int j = 0; j < 8; ++j)
            h[j] = f2bf(OW[((size_t)d * 1024 + c0 + j) * 98 + oc]);
    } else {
        #pragma unroll
        for (int j = 0; j < 8; ++j) h[j] = 0;
    }
    *(bf16x8*)(OWbf + (size_t)gid * 8) = *(bf16x8*)h;
}

// w (49,C,F) -> Wf hi/lo: [plane][d][nt(F/16)][kb(C/32)][kg(4)][ni(16)][8]
template<int C, int F>
__device__ __forceinline__ void d_pack_w(
    const int gid, const float* __restrict__ Wt, short* __restrict__ Wf)
{
    constexpr int KB = C / 32;
    constexpr int NT = F / 16;
    constexpr int PLANE = 49 * NT * KB * 4 * 16 * 8;   // shorts
    const int ni = gid & 15;
    int t = gid >> 4;
    const int kg = t & 3; t >>= 2;
    const int kb = t % KB; t /= KB;
    const int nt = t % NT;
    const int d  = t / NT;
    const int f = nt * 16 + ni;
    const int c0 = kb * 32 + kg * 8;
    short hi[8], lo[8];
    #pragma unroll
    for (int j = 0; j < 8; ++j) {
        const float v = Wt[((size_t)d * C + c0 + j) * F + f];
        hi[j] = f2bf(v);
        lo[j] = f2bf(v - bf2f(hi[j]));
    }
    *(bf16x8*)(Wf + (size_t)gid * 8) = *(bf16x8*)hi;
    *(bf16x8*)(Wf + PLANE + (size_t)gid * 8) = *(bf16x8*)lo;
}

// ow (7,7,C,98) -> per-class OWf: [kbg][nt(7)][kg(4)][ni(16)][8] (one short/gid)
template<int C>
__device__ __forceinline__ void d_pack_owf(
    const int gid, const float* __restrict__ OW, short* __restrict__ OWf)
{
    const int j = gid & 7;
    int t = gid >> 3;
    const int fi = t & 63; t >>= 6;
    const int nt = t % 7;
    const int kbg = t / 7;
    const int ni = fi & 15, kg = fi >> 4;

    int cum1, cum2, cum3;
    if (C == 64)      { cum1 = 18; cum2 = 42; cum3 = 66; }
    else if (C == 32) { cum1 = 9;  cum2 = 21; cum3 = 33; }
    else              { cum1 = 5;  cum2 = 11; cum3 = 17; }
    int cls, kb0;
    if (kbg < cum1)      { cls = 0; kb0 = 0; }
    else if (kbg < cum2) { cls = 1; kb0 = cum1; }
    else if (kbg < cum3) { cls = 2; kb0 = cum2; }
    else                 { cls = 3; kb0 = cum3; }
    const int kbl = kbg - kb0;
    const int pi = cls >> 1, rho = cls & 1;
    const int NRc = pi ? 4 : 3, NCc = rho ? 4 : 3;
    const int T = NRc * NCc;

    const int k = kbl * 32 + kg * 8 + j;
    const int tl = k / C, c = k - tl * C;
    const int oc = nt * 16 + ni;
    float v = 0.f;
    if (tl < T && oc < 98) {
        const int iy = tl / NCc, ix = tl - iy * NCc;
        const int d = (1 - pi + 2 * iy) * 7 + (1 - rho + 2 * ix);
        v = OW[((size_t)d * C + c) * 98 + oc];
    }
    OWf[gid] = f2bf(v);
}

// ==================== mega weight-pack kernel ====================
__global__ __launch_bounds__(256) void k_pack_weights(
    const float* __restrict__ ow1, const float* __restrict__ w1,
    const float* __restrict__ ow2, const float* __restrict__ w2,
    const float* __restrict__ ow3, const float* __restrict__ w3,
    const float* __restrict__ ow4,
    short* OWbf, short* W1f, short* OWf2, short* W2f,
    short* OWf3, short* W3f, short* OWf4)
{
    const int bid = blockIdx.x;
    const int tid = threadIdx.x;
    if (bid < 2744)      d_pack_ow1((bid) * 256 + tid, ow1, OWbf);
    else if (bid < 4312) d_pack_w<1024, 64>((bid - 2744) * 256 + tid, w1, W1f);
    else if (bid < 5684) d_pack_owf<64>((bid - 4312) * 256 + tid, ow2, OWf2);
    else if (bid < 5733) d_pack_w<64, 32>((bid - 5684) * 256 + tid, w2, W2f);
    else if (bid < 6419) d_pack_owf<32>((bid - 5733) * 256 + tid, ow3, OWf3);
    else if (bid < 6432) { const int g = (bid - 6419) * 256 + tid; if (g < 3136) d_pack_w<32, 16>(g, w3, W3f); }
    else                 d_pack_owf<16>((bid - 6432) * 256 + tid, ow4, OWf4);
}

// ============ dense (z @ W + b) + relu -> Xf frag-packed hi/lo ============
// Xf layout (bf16): [plane(2)][mtile(16)][kb(32)][kg(4)][mi(16)][8]
__global__ __launch_bounds__(256) void k_dense_cvt(
    const float* __restrict__ z, const float* __restrict__ Wd,
    const float* __restrict__ bd, short* __restrict__ Xf)
{
    const int D = 131072;
    __shared__ float zs[256];
    const int tid = threadIdx.x;
    zs[tid] = z[tid];
    __syncthreads();
    const int n = blockIdx.x * 256 + tid;
    const float bb = bd[n];
    float a0 = bb, a1 = bb;
    #pragma unroll 8
    for (int kk = 0; kk < 128; ++kk) {
        const float w = Wd[kk * D + n];
        a0 = fmaf(zs[kk], w, a0);
        a1 = fmaf(zs[128 + kk], w, a1);
    }
    a0 = fmaxf(a0, 0.f);
    a1 = fmaxf(a1, 0.f);
    const int c = n & 1023;
    const int m0 = n >> 10;          // batch0 row; batch1 = m0+128
    const int kb = c >> 5, kg = (c >> 3) & 3, j = c & 7;
    const size_t base = ((size_t)kb * 4 + kg) * 16 * 8 + j;
    {
        const size_t dst = ((size_t)(m0 >> 4) * 32 * 4 * 16) * 8 + base + (size_t)(m0 & 15) * 8;
        const short h = f2bf(a0);
        Xf[dst] = h;
        Xf[262144 + dst] = f2bf(a0 - bf2f(h));
    }
    {
        const int m1 = m0 + 128;
        const size_t dst = ((size_t)(m1 >> 4) * 32 * 4 * 16) * 8 + base + (size_t)(m1 & 15) * 8;
        const short h = f2bf(a1);
        Xf[dst] = h;
        Xf[262144 + dst] = f2bf(a1 - bf2f(h));
    }
}

// ============ stage-1 offset conv: MFMA GEMM over taps ============
__global__ __launch_bounds__(256) void k_zgemm1_mfma(
    const short* __restrict__ Xf, const short* __restrict__ OWbf,
    float* __restrict__ Zp)
{
    const int tid = threadIdx.x;
    const int wv = tid >> 6;
    const int l  = tid & 63;
    const int l15 = l & 15, l4 = l >> 4;
    const int mtile = blockIdx.x * 4 + wv;
    const int d = blockIdx.y;

    const bf16x8* Ah = (const bf16x8*)Xf + (size_t)mtile * 2048 + l4 * 16 + l15;
    const bf16x8* Al = Ah + 32768;
    const bf16x8* Bb = (const bf16x8*)OWbf + (size_t)d * 7 * 2048 + l4 * 16 + l15;

    f32x4 acc[7];
    #pragma unroll
    for (int nt = 0; nt < 7; ++nt) acc[nt] = (f32x4){0.f, 0.f, 0.f, 0.f};

    for (int kb = 0; kb < 32; ++kb) {
        const bf16x8 ah = Ah[kb * 64];
        const bf16x8 al = Al[kb * 64];
        #pragma unroll
        for (int nt = 0; nt < 7; ++nt) {
            const bf16x8 b = Bb[(size_t)nt * 2048 + kb * 64];
            acc[nt] = __builtin_amdgcn_mfma_f32_16x16x32_bf16(ah, b, acc[nt], 0, 0, 0);
            acc[nt] = __builtin_amdgcn_mfma_f32_16x16x32_bf16(al, b, acc[nt], 0, 0, 0);
        }
    }

    const int m0 = mtile * 16 + l4 * 4;
    #pragma unroll
    for (int nt = 0; nt < 7; ++nt) {
        const int oc = nt * 16 + l15;
        if (oc < 98) {
            #pragma unroll
            for (int r = 0; r < 4; ++r)
                Zp[((size_t)d * 256 + m0 + r) * 98 + oc] = acc[nt][r];
        }
    }
}

// ============ stage-1 Y GEMM via MFMA: Y[d][m][f], 3-term hi/lo ============
__global__ __launch_bounds__(256) void k_ygemm1_mfma(
    const short* __restrict__ Xf, const short* __restrict__ W1f,
    float* __restrict__ Y)
{
    const int tid = threadIdx.x;
    const int wv = tid >> 6;
    const int l  = tid & 63;
    const int l15 = l & 15, l4 = l >> 4;
    const int mtile = blockIdx.x * 4 + wv;
    const int d = blockIdx.y;

    const bf16x8* Ah = (const bf16x8*)Xf + (size_t)mtile * 2048 + l4 * 16 + l15;
    const bf16x8* Al = Ah + 32768;
    const bf16x8* Bh = (const bf16x8*)W1f + (size_t)d * 4 * 2048 + l4 * 16 + l15;
    const bf16x8* Bl = Bh + 401408;

    f32x4 acc[4];
    #pragma unroll
    for (int nt = 0; nt < 4; ++nt) acc[nt] = (f32x4){0.f, 0.f, 0.f, 0.f};

    for (int kb = 0; kb < 32; ++kb) {
        const bf16x8 ah = Ah[kb * 64];
        const bf16x8 al = Al[kb * 64];
        #pragma unroll
        for (int nt = 0; nt < 4; ++nt) {
            const bf16x8 bh = Bh[nt * 2048 + kb * 64];
            const bf16x8 bl = Bl[nt * 2048 + kb * 64];
            acc[nt] = __builtin_amdgcn_mfma_f32_16x16x32_bf16(ah, bh, acc[nt], 0, 0, 0);
            acc[nt] = __builtin_amdgcn_mfma_f32_16x16x32_bf16(ah, bl, acc[nt], 0, 0, 0);
            acc[nt] = __builtin_amdgcn_mfma_f32_16x16x32_bf16(al, bh, acc[nt], 0, 0, 0);
        }
    }

    const int m0 = mtile * 16 + l4 * 4;
    #pragma unroll
    for (int nt = 0; nt < 4; ++nt) {
        const int f = nt * 16 + l15;
        #pragma unroll
        for (int r = 0; r < 4; ++r)
            Y[((size_t)d * 256 + m0 + r) * 64 + f] = acc[nt][r];
    }
}

// ============ stages 2-3 Y GEMM via MFMA, A from natural-layout planes =====
template<int C, int F>
__global__ __launch_bounds__(256) void k_ygemm23_mfma(
    const short* __restrict__ Xbf, const short* __restrict__ Wf,
    float* __restrict__ Y, const int M, const int nX)
{
    constexpr int KB = C / 32;
    constexpr int NT = F / 16;
    constexpr int PLANEFRAG = 49 * NT * KB * 64;
    const int tid = threadIdx.x;
    const int wv = tid >> 6;
    const int l  = tid & 63;
    const int l15 = l & 15, l4 = l >> 4;
    const int mtile = blockIdx.x * 4 + wv;
    const int d = blockIdx.y;

    const short* Arow = Xbf + (size_t)(mtile * 16 + l15) * C + l4 * 8;

    f32x4 acc[NT];
    #pragma unroll
    for (int nt = 0; nt < NT; ++nt) acc[nt] = (f32x4){0.f, 0.f, 0.f, 0.f};

    #pragma unroll
    for (int kb = 0; kb < KB; ++kb) {
        const bf16x8 ah = *(const bf16x8*)(Arow + kb * 32);
        const bf16x8 al = *(const bf16x8*)(Arow + nX + kb * 32);
        #pragma unroll
        for (int nt = 0; nt < NT; ++nt) {
            const size_t fi = ((size_t)(d * NT + nt) * KB + kb) * 64 + l4 * 16 + l15;
            const bf16x8 bh = ((const bf16x8*)Wf)[fi];
            const bf16x8 bl = ((const bf16x8*)Wf)[fi + PLANEFRAG];
            acc[nt] = __builtin_amdgcn_mfma_f32_16x16x32_bf16(ah, bh, acc[nt], 0, 0, 0);
            acc[nt] = __builtin_amdgcn_mfma_f32_16x16x32_bf16(ah, bl, acc[nt], 0, 0, 0);
            acc[nt] = __builtin_amdgcn_mfma_f32_16x16x32_bf16(al, bh, acc[nt], 0, 0, 0);
        }
    }

    const int m0 = mtile * 16 + l4 * 4;
    #pragma unroll
    for (int nt = 0; nt < NT; ++nt) {
        const int f = nt * 16 + l15;
        #pragma unroll
        for (int r = 0; r < 4; ++r)
            Y[((size_t)d * M + m0 + r) * F + f] = acc[nt][r];
    }
}

// ============ stage-1: scatter-sum Zp + compute (s, src) ====================
__global__ __launch_bounds__(256) void k_sparams_z1(
    const float* __restrict__ Zp, const float* __restrict__ OB,
    float* __restrict__ SW, int* __restrict__ SIDX)
{
    const int gid = blockIdx.x * 256 + threadIdx.x;
    if (gid >= 1024 * K49) return;
    const int pixL = gid / K49;
    const int k = gid - pixL * K49;
    const int b   = pixL >> 9;
    const int rem = pixL & 511;
    const int hp  = rem >> 5;
    const int wp  = rem & 31;

    float accy = OB[2 * k], accx = OB[2 * k + 1];
    const int di0 = (hp + 1) & 1, dj0 = (wp + 1) & 1;
    for (int di = di0; di < 7; di += 2) {
        const int yp = hp + di - 3;
        if ((unsigned)yp >= 16u) continue;
        const int ys = yp >> 1;
        for (int dj = dj0; dj < 7; dj += 2) {
            const int xp = wp + dj - 3;
            if ((unsigned)xp >= 32u) continue;
            const int xs = xp >> 1;
            const size_t o = ((size_t)((di * 7 + dj) * 256 + (b * 8 + ys) * 16 + xs)) * 98 + 2 * k;
            accy += Zp[o];
            accx += Zp[o + 1];
        }
    }
    const float y = (float)(hp + (k / 7) - 3) + accy;
    const float x = (float)(wp + (k % 7) - 3) + accx;
    const float fy0 = floorf(y), fx0 = floorf(x);
    const int iy0 = (int)fy0, ix0 = (int)fx0;
    const float wy1 = y - fy0, wx1 = x - fx0;
    int ye, xe; float wy, wx;
    if (iy0 & 1) { ye = iy0 + 1; wy = wy1; } else { ye = iy0; wy = 1.f - wy1; }
    if (ix0 & 1) { xe = ix0 + 1; wx = wx1; } else { xe = ix0; wx = 1.f - wx1; }
    float s = wy * wx;
    int src = 0;
    if (ye >= 0 && ye < 16 && xe >= 0 && xe < 32)
        src = (b * 8 + (ye >> 1)) * 16 + (xe >> 1);
    else
        s = 0.f;
    SW[gid] = s;
    SIDX[gid] = src;
}

// ============ offset conv via implicit-GEMM MFMA (stages 2-4) ===============
template<int C>
__global__ __launch_bounds__(256) void k_offmfma(
    const short* __restrict__ Xbf,    // hi plane, lo plane at +nX
    const short* __restrict__ OWf,
    float* __restrict__ off,          // [npix_chunk][98]
    const int H, const int W, const int Hp, const int Wp,
    const int rowbase, const int pix0off, const int nX)
{
    const int tid = threadIdx.x;
    const int wv = tid >> 6;
    const int l  = tid & 63;
    const int l15 = l & 15, l4 = l >> 4;
    const int cls = blockIdx.y;
    const int pi = cls >> 1, rho = cls & 1;
    const int NRc = pi ? 4 : 3, NCc = rho ? 4 : 3;
    const int T = NRc * NCc;
    int nkb, clsoff;
    if (C == 64)      { nkb = T * 2;        clsoff = cls == 0 ? 0 : cls == 1 ? 18 : cls == 2 ? 42 : 66; }
    else if (C == 32) { nkb = T;            clsoff = cls == 0 ? 0 : cls == 1 ? 9  : cls == 2 ? 21 : 33; }
    else              { nkb = (T + 1) >> 1; clsoff = cls == 0 ? 0 : cls == 1 ? 5  : cls == 2 ? 11 : 17; }

    const int Wt16 = W >> 4;
    const int mt = blockIdx.x * 4 + wv;
    const int rloc = mt / Wt16, xt = mt - rloc * Wt16;
    const int g = rowbase + rloc;
    const int b = g / H;
    const int ysp = g - b * H;

    f32x4 acc[7];
    #pragma unroll
    for (int nt = 0; nt < 7; ++nt) acc[nt] = (f32x4){0.f, 0.f, 0.f, 0.f};

    const bf16x8* Bbase = (const bf16x8*)OWf + ((size_t)clsoff * 7) * 64 + l4 * 16 + l15;

    for (int kb = 0; kb < nkb; ++kb) {
        int tl, c0;
        if (C == 64)      { tl = kb >> 1;            c0 = ((kb & 1) << 5) + l4 * 8; }
        else if (C == 32) { tl = kb;                 c0 = l4 * 8; }
        else              { tl = kb * 2 + (l4 >> 1); c0 = (l4 & 1) * 8; if (tl >= T) tl = T - 1; }
        int iy, ix;
        if (NCc == 4) { iy = tl >> 2; ix = tl & 3; }
        else          { iy = tl / 3;  ix = tl - iy * 3; }
        const int ys = ysp + iy - 1;
        const int xs = xt * 16 + l15 + ix - 1;
        bf16x8 ah = {0, 0, 0, 0, 0, 0, 0, 0};
        bf16x8 al = {0, 0, 0, 0, 0, 0, 0, 0};
        if ((unsigned)ys < (unsigned)H && (unsigned)xs < (unsigned)W) {
            const size_t a = ((size_t)(b * H + ys) * W + xs) * C + c0;
            ah = *(const bf16x8*)(Xbf + a);
            al = *(const bf16x8*)(Xbf + nX + a);
        }
        const bf16x8* Bb = Bbase + (size_t)kb * 7 * 64;
        #pragma unroll
        for (int nt = 0; nt < 7; ++nt) {
            const bf16x8 bf = Bb[nt * 64];
            acc[nt] = __builtin_amdgcn_mfma_f32_16x16x32_bf16(ah, bf, acc[nt], 0, 0, 0);
            acc[nt] = __builtin_amdgcn_mfma_f32_16x16x32_bf16(al, bf, acc[nt], 0, 0, 0);
        }
    }

    const int hp = 2 * ysp + pi;
    const int wpbase = (xt << 5) + rho;
    const int pixrow = (b * Hp + hp) * Wp + wpbase - pix0off;
    #pragma unroll
    for (int nt = 0; nt < 7; ++nt) {
        const int oc = nt * 16 + l15;
        if (oc < 98) {
            #pragma unroll
            for (int r = 0; r < 4; ++r) {
                const int m = l4 * 4 + r;
                off[(size_t)(pixrow + 2 * m) * 98 + oc] = acc[nt][r];
            }
        }
    }
}

// ============ reduce offset + compute (s, src) per (pixel, tap) ====
__global__ __launch_bounds__(256) void k_sparams(
    const float* __restrict__ part_off, const float* __restrict__ OB,
    float* __restrict__ SW, int* __restrict__ SIDX,
    const int npix, const int CG,
    const int H, const int W, const int Hp, const int Wp, const int pix0)
{
    const int gid = blockIdx.x * 256 + threadIdx.x;
    if (gid >= npix * K49) return;
    const int pixL = gid / K49;
    const int k = gid - pixL * K49;
    float accy = OB[2 * k], accx = OB[2 * k + 1];
    for (int g = 0; g < CG; ++g) {
        const size_t base = ((size_t)g * npix + pixL) * 98 + 2 * k;
        accy += part_off[base];
        accx += part_off[base + 1];
    }
    const int pixg = pix0 + pixL;
    const int HWp = Hp * Wp;
    const int b = pixg / HWp;
    const int rem = pixg - b * HWp;
    const int hp = rem / Wp;
    const int wp = rem - hp * Wp;

    const float y = (float)(hp + (k / 7) - 3) + accy;
    const float x = (float)(wp + (k % 7) - 3) + accx;
    const float fy0 = floorf(y), fx0 = floorf(x);
    const int iy0 = (int)fy0, ix0 = (int)fx0;
    const float wy1 = y - fy0, wx1 = x - fx0;
    int ye, xe; float wy, wx;
    if (iy0 & 1) { ye = iy0 + 1; wy = wy1; } else { ye = iy0; wy = 1.f - wy1; }
    if (ix0 & 1) { xe = ix0 + 1; wx = wx1; } else { xe = ix0; wx = 1.f - wx1; }
    float s = wy * wx;
    int src = 0;
    if (ye >= 0 && ye < Hp && xe >= 0 && xe < Wp)
        src = (b * H + (ye >> 1)) * W + (xe >> 1);
    else
        s = 0.f;
    SW[gid] = s;
    SIDX[gid] = src;
}

// ============ combine + emit bf16 hi/lo planes (+optional fp32) ============
template<int F, bool WF32>
__global__ __launch_bounds__(256) void k_combine(
    const float* __restrict__ Y,   // [49][nsrc*F]
    const float* __restrict__ SW, const int* __restrict__ SIDX,
    const float* __restrict__ bias,
    float* __restrict__ xf32, short* __restrict__ xhi, short* __restrict__ xlo,
    const int nsrc)
{
    constexpr int PPB = 256 / F;
    const int tid = threadIdx.x;
    const int f = tid % F;
    const int pix = blockIdx.x * PPB + tid / F;
    const size_t strideY = (size_t)nsrc * F;
    float acc = bias[f];
    #pragma unroll 7
    for (int k = 0; k < K49; ++k) {
        const float s = SW[(size_t)pix * K49 + k];
        const int src = SIDX[(size_t)pix * K49 + k];
        acc = fmaf(s, Y[(size_t)k * strideY + (size_t)src * F + f], acc);
    }
    const float v = fmaxf(acc, 0.f);
    const size_t o = (size_t)pix * F + f;
    if (WF32) xf32[o] = v;
    const short h = f2bf(v);
    xhi[o] = h;
    xlo[o] = f2bf(v - bf2f(h));
}

// ============ stage 4 Y: Y4[k][src] = X3[src,:16] . W4[k,:16] ============
__global__ __launch_bounds__(256) void k_y4(
    const float* __restrict__ X,   // [M,16]
    const float* __restrict__ Wt,  // [49,16]
    float* __restrict__ Y,         // [49][M]
    const int M)
{
    __shared__ float Ws[K49 * 16];
    const int tid = threadIdx.x;
    for (int t = tid; t < K49 * 16; t += 256) Ws[t] = Wt[t];
    __syncthreads();
    const int src = blockIdx.x * 256 + tid;
    const float4* xr = (const float4*)(X + (size_t)src * 16);
    const float4 a0 = xr[0], a1 = xr[1], a2 = xr[2], a3 = xr[3];
    for (int k = 0; k < K49; ++k) {
        const float* wr = Ws + k * 16;
        float d = a0.x*wr[0]  + a0.y*wr[1]  + a0.z*wr[2]  + a0.w*wr[3]
                + a1.x*wr[4]  + a1.y*wr[5]  + a1.z*wr[6]  + a1.w*wr[7]
                + a2.x*wr[8]  + a2.y*wr[9]  + a2.z*wr[10] + a2.w*wr[11]
                + a3.x*wr[12] + a3.y*wr[13] + a3.z*wr[14] + a3.w*wr[15];
        Y[(size_t)k * M + src] = d;
    }
}

// ============ stage 4: fused sparams + gather-combine via Y4, 4-lane split ===
__global__ __launch_bounds__(256) void k_dconv_f1_y(
    const float* __restrict__ Y4,       // [49][nsrc]
    const float* __restrict__ part,     // [npix, 98] raw offset conv
    const float* __restrict__ OB,       // [98]
    const float* __restrict__ bias, float* __restrict__ out,
    const int H, const int W, const int Hp, const int Wp,
    const int pix0, const int nsrc)
{
    __shared__ float OBs[98];
    const int tid = threadIdx.x;
    if (tid < 98) OBs[tid] = OB[tid];
    __syncthreads();

    const int pixL = blockIdx.x * 64 + (tid >> 2);
    const int tq = tid & 3;
    const int t0 = (tq == 0) ? 0 : 13 + (tq - 1) * 12;
    const int t1 = t0 + ((tq == 0) ? 13 : 12);

    const int pixg = pix0 + pixL;
    const int HWp = Hp * Wp;
    const int b = pixg / HWp;
    const int rem = pixg - b * HWp;
    const int hp = rem / Wp;
    const int wp = rem - hp * Wp;

    float acc = 0.f;
    for (int k = t0; k < t1; ++k) {
        const float offy = part[(size_t)pixL * 98 + 2 * k]     + OBs[2 * k];
        const float offx = part[(size_t)pixL * 98 + 2 * k + 1] + OBs[2 * k + 1];
        const float y = (float)(hp + (k / 7) - 3) + offy;
        const float x = (float)(wp + (k % 7) - 3) + offx;
        const float fy0 = floorf(y), fx0 = floorf(x);
        const int iy0 = (int)fy0, ix0 = (int)fx0;
        const float wy1 = y - fy0, wx1 = x - fx0;
        int ye, xe; float wy, wx;
        if (iy0 & 1) { ye = iy0 + 1; wy = wy1; } else { ye = iy0; wy = 1.f - wy1; }
        if (ix0 & 1) { xe = ix0 + 1; wx = wx1; } else { xe = ix0; wx = 1.f - wx1; }
        float s = wy * wx;
        int src = 0;
        if (ye >= 0 && ye < Hp && xe >= 0 && xe < Wp)
            src = (b * H + (ye >> 1)) * W + (xe >> 1);
        else
            s = 0.f;
        acc = fmaf(s, Y4[(size_t)k * nsrc + src], acc);
    }
    acc += __shfl_xor(acc, 1);
    acc += __shfl_xor(acc, 2);
    if (tq == 0) out[pixg] = acc + bias[0];
}

extern "C" void kernel_launch(void* const* d_in, const int* in_sizes, int n_in,
                              void* d_out, int out_size, void* d_ws, size_t ws_size,
                              hipStream_t stream) {
    const float* z   = (const float*)d_in[0];
    const float* dw  = (const float*)d_in[1];
    const float* db  = (const float*)d_in[2];
    const float* ow1 = (const float*)d_in[3];
    const float* ob1 = (const float*)d_in[4];
    const float* w1  = (const float*)d_in[5];
    const float* b1  = (const float*)d_in[6];
    const float* ow2 = (const float*)d_in[7];
    const float* ob2 = (const float*)d_in[8];
    const float* w2  = (const float*)d_in[9];
    const float* b2  = (const float*)d_in[10];
    const float* ow3 = (const float*)d_in[11];
    const float* ob3 = (const float*)d_in[12];
    const float* w3  = (const float*)d_in[13];
    const float* b3  = (const float*)d_in[14];
    const float* ow4 = (const float*)d_in[15];
    const float* ob4 = (const float*)d_in[16];
    const float* w4  = (const float*)d_in[17];
    const float* b4  = (const float*)d_in[18];

    // workspace layout: ~100 MB, no aliasing (ws_size = 256 MiB per profile)
    float* ws   = (float*)d_ws;
    short* Xf   = (short*)ws;                    // 524,288 sh (262,144 f)
    float* sw   = ws + 262144;                   // 802,816
    int*   sidx = (int*)(sw + 802816);           // 802,816
    float* Zp   = (float*)(sidx + 802816);       // 1,229,312
    float* Y1   = Zp + 1229312;                  // 802,816
    float* Y2   = Y1 + 802816;                   // 1,605,632
    float* Y3   = Y2 + 1605632;                  // 3,211,264
    float* Y4   = Y3 + 3211264;                  // 802,816
    short* Xbf1 = (short*)(Y4 + 802816);         // 131,072 sh
    short* Xbf2 = Xbf1 + 131072;                 // 262,144 sh
    short* Xbf3 = Xbf2 + 262144;                 // 524,288 sh
    float* x3   = (float*)(Xbf3 + 524288);       // 262,144
    float* off2 = x3 + 262144;                   // 401,408
    float* off3 = off2 + 401408;                 // 1,605,632
    float* off4 = off3 + 1605632;                // 6,422,528
    short* OWbf = (short*)(off4 + 6422528);      // 5,619,712 sh
    short* W1f  = OWbf + 5619712;                // 6,422,528 sh
    short* OWf2 = W1f + 6422528;                 // 351,232 sh
    short* W2f  = OWf2 + 351232;                 // 200,704 sh
    short* OWf3 = W2f + 200704;                  // 175,616 sh
    short* W3f  = OWf3 + 175616;                 // 50,176 sh
    short* OWf4 = W3f + 50176;                   // 89,600 sh

    float* out = (float*)d_out;

    // ---- pack all weights (one launch) ----
    k_pack_weights<<<6782, 256, 0, stream>>>(ow1, w1, ow2, w2, ow3, w3, ow4,
                                             OWbf, W1f, OWf2, W2f, OWf3, W3f, OWf4);

    // ---- dense + relu + frag-pack ----
    k_dense_cvt<<<512, 256, 0, stream>>>(z, dw, db, Xf);

    // ---- stage 1: Xf -> Xbf1 planes (nsrc=256, npix=1024) ----
    k_zgemm1_mfma<<<dim3(4, 49), 256, 0, stream>>>(Xf, OWbf, Zp);
    k_sparams_z1<<<196, 256, 0, stream>>>(Zp, ob1, sw, sidx);
    k_ygemm1_mfma<<<dim3(4, 49), 256, 0, stream>>>(Xf, W1f, Y1);
    k_combine<64, false><<<256, 256, 0, stream>>>(Y1, sw, sidx, b1, nullptr, Xbf1, Xbf1 + 65536, 256);

    // ---- stage 2: Xbf1 -> Xbf2 (nsrc=1024, npix=4096, C=64) ----
    k_offmfma<64><<<dim3(16, 4), 256, 0, stream>>>(Xbf1, OWf2, off2, 16, 32, 32, 64, 0, 0, 65536);
    k_sparams<<<784, 256, 0, stream>>>(off2, ob2, sw, sidx, 4096, 1, 16, 32, 32, 64, 0);
    k_ygemm23_mfma<64, 32><<<dim3(16, 49), 256, 0, stream>>>(Xbf1, W2f, Y2, 1024, 65536);
    k_combine<32, false><<<512, 256, 0, stream>>>(Y2, sw, sidx, b2, nullptr, Xbf2, Xbf2 + 131072, 1024);

    // ---- stage 3: Xbf2 -> Xbf3 + x3 (nsrc=4096, npix=16384, C=32) ----
    k_offmfma<32><<<dim3(64, 4), 256, 0, stream>>>(Xbf2, OWf3, off3, 32, 64, 64, 128, 0, 0, 131072);
    k_sparams<<<3136, 256, 0, stream>>>(off3, ob3, sw, sidx, 16384, 1, 32, 64, 64, 128, 0);
    k_ygemm23_mfma<32, 16><<<dim3(64, 49), 256, 0, stream>>>(Xbf2, W3f, Y3, 4096, 131072);
    k_combine<16, true><<<1024, 256, 0, stream>>>(Y3, sw, sidx, b3, x3, Xbf3, Xbf3 + 262144, 4096);

    // ---- stage 4: x3/Xbf3 -> out (nsrc=16384, npix=65536, C=16), one chunk ----
    k_y4<<<64, 256, 0, stream>>>(x3, w4, Y4, 16384);
    k_offmfma<16><<<dim3(256, 4), 256, 0, stream>>>(Xbf3, OWf4, off4, 64, 128, 128, 256, 0, 0, 262144);
    k_dconv_f1_y<<<1024, 256, 0, stream>>>(Y4, off4, ob4, b4, out, 64, 128, 128, 256, 0, 16384);
}

// Round 11
// 187.506 us; speedup vs baseline: 1.7552x; 1.0202x over previous
//
#include <hip/hip_runtime.h>
#include <hip/hip_bf16.h>

#define K49 49

typedef short bf16x8 __attribute__((ext_vector_type(8)));
typedef float f32x4 __attribute__((ext_vector_type(4)));

__device__ __forceinline__ short f2bf(float x) {
    __hip_bfloat16 h = __float2bfloat16(x);
    return __builtin_bit_cast(short, h);
}
__device__ __forceinline__ float bf2f(short s) {
    unsigned u = ((unsigned)(unsigned short)s) << 16;
    return __builtin_bit_cast(float, u);
}

// ==================== weight packing (device fns) ====================
__device__ __forceinline__ void d_pack_ow1(
    const int gid, const float* __restrict__ OW, short* __restrict__ OWbf)
{
    const int ni = gid & 15;
    int t = gid >> 4;
    const int kg = t & 3;  t >>= 2;
    const int kb = t & 31; t >>= 5;
    const int nt = t % 7;
    const int d  = t / 7;
    const int oc = nt * 16 + ni;
    short h[8];
    if (oc < 98) {
        const int c0 = kb * 32 + kg * 8;
        #pragma unroll
        for (int j = 0; j < 8; ++j)
            h[j] = f2bf(OW[((size_t)d * 1024 + c0 + j) * 98 + oc]);
    } else {
        #pragma unroll
        for (int j = 0; j < 8; ++j) h[j] = 0;
    }
    *(bf16x8*)(OWbf + (size_t)gid * 8) = *(bf16x8*)h;
}

template<int C, int F>
__device__ __forceinline__ void d_pack_w(
    const int gid, const float* __restrict__ Wt, short* __restrict__ Wf)
{
    constexpr int KB = C / 32;
    constexpr int NT = F / 16;
    constexpr int PLANE = 49 * NT * KB * 4 * 16 * 8;   // shorts
    const int ni = gid & 15;
    int t = gid >> 4;
    const int kg = t & 3; t >>= 2;
    const int kb = t % KB; t /= KB;
    const int nt = t % NT;
    const int d  = t / NT;
    const int f = nt * 16 + ni;
    const int c0 = kb * 32 + kg * 8;
    short hi[8], lo[8];
    #pragma unroll
    for (int j = 0; j < 8; ++j) {
        const float v = Wt[((size_t)d * C + c0 + j) * F + f];
        hi[j] = f2bf(v);
        lo[j] = f2bf(v - bf2f(hi[j]));
    }
    *(bf16x8*)(Wf + (size_t)gid * 8) = *(bf16x8*)hi;
    *(bf16x8*)(Wf + PLANE + (size_t)gid * 8) = *(bf16x8*)lo;
}

template<int C>
__device__ __forceinline__ void d_pack_owf(
    const int gid, const float* __restrict__ OW, short* __restrict__ OWf)
{
    const int j = gid & 7;
    int t = gid >> 3;
    const int fi = t & 63; t >>= 6;
    const int nt = t % 7;
    const int kbg = t / 7;
    const int ni = fi & 15, kg = fi >> 4;

    int cum1, cum2, cum3;
    if (C == 64)      { cum1 = 18; cum2 = 42; cum3 = 66; }
    else if (C == 32) { cum1 = 9;  cum2 = 21; cum3 = 33; }
    else              { cum1 = 5;  cum2 = 11; cum3 = 17; }
    int cls, kb0;
    if (kbg < cum1)      { cls = 0; kb0 = 0; }
    else if (kbg < cum2) { cls = 1; kb0 = cum1; }
    else if (kbg < cum3) { cls = 2; kb0 = cum2; }
    else                 { cls = 3; kb0 = cum3; }
    const int kbl = kbg - kb0;
    const int pi = cls >> 1, rho = cls & 1;
    const int NRc = pi ? 4 : 3, NCc = rho ? 4 : 3;
    const int T = NRc * NCc;

    const int k = kbl * 32 + kg * 8 + j;
    const int tl = k / C, c = k - tl * C;
    const int oc = nt * 16 + ni;
    float v = 0.f;
    if (tl < T && oc < 98) {
        const int iy = tl / NCc, ix = tl - iy * NCc;
        const int d = (1 - pi + 2 * iy) * 7 + (1 - rho + 2 * ix);
        v = OW[((size_t)d * C + c) * 98 + oc];
    }
    OWf[gid] = f2bf(v);
}

// ==================== mega prep kernel: dense+cvt AND all weight packs =====
// Xf layout (bf16): [plane(2)][mtile(16)][kb(32)][kg(4)][mi(16)][8]
__global__ __launch_bounds__(256) void k_prep(
    const float* __restrict__ z, const float* __restrict__ Wd,
    const float* __restrict__ bd, short* __restrict__ Xf,
    const float* __restrict__ ow1, const float* __restrict__ w1,
    const float* __restrict__ ow2, const float* __restrict__ w2,
    const float* __restrict__ ow3, const float* __restrict__ w3,
    const float* __restrict__ ow4,
    short* OWbf, short* W1f, short* OWf2, short* W2f,
    short* OWf3, short* W3f, short* OWf4)
{
    const int bid0 = blockIdx.x;
    const int tid = threadIdx.x;
    __shared__ float zs[256];
    if (bid0 < 512) {
        const int D = 131072;
        zs[tid] = z[tid];
        __syncthreads();
        const int n = bid0 * 256 + tid;
        const float bb = bd[n];
        float a0 = bb, a1 = bb;
        #pragma unroll 8
        for (int kk = 0; kk < 128; ++kk) {
            const float w = Wd[kk * D + n];
            a0 = fmaf(zs[kk], w, a0);
            a1 = fmaf(zs[128 + kk], w, a1);
        }
        a0 = fmaxf(a0, 0.f);
        a1 = fmaxf(a1, 0.f);
        const int c = n & 1023;
        const int m0 = n >> 10;
        const int kb = c >> 5, kg = (c >> 3) & 3, j = c & 7;
        const size_t base = ((size_t)kb * 4 + kg) * 16 * 8 + j;
        {
            const size_t dst = ((size_t)(m0 >> 4) * 2048) * 8 + base + (size_t)(m0 & 15) * 8;
            const short h = f2bf(a0);
            Xf[dst] = h;
            Xf[262144 + dst] = f2bf(a0 - bf2f(h));
        }
        {
            const int m1 = m0 + 128;
            const size_t dst = ((size_t)(m1 >> 4) * 2048) * 8 + base + (size_t)(m1 & 15) * 8;
            const short h = f2bf(a1);
            Xf[dst] = h;
            Xf[262144 + dst] = f2bf(a1 - bf2f(h));
        }
        return;
    }
    const int bid = bid0 - 512;
    if (bid < 2744)      d_pack_ow1((bid) * 256 + tid, ow1, OWbf);
    else if (bid < 4312) d_pack_w<1024, 64>((bid - 2744) * 256 + tid, w1, W1f);
    else if (bid < 5684) d_pack_owf<64>((bid - 4312) * 256 + tid, ow2, OWf2);
    else if (bid < 5733) d_pack_w<64, 32>((bid - 5684) * 256 + tid, w2, W2f);
    else if (bid < 6419) d_pack_owf<32>((bid - 5733) * 256 + tid, ow3, OWf3);
    else if (bid < 6432) { const int g = (bid - 6419) * 256 + tid; if (g < 3136) d_pack_w<32, 16>(g, w3, W3f); }
    else                 d_pack_owf<16>((bid - 6432) * 256 + tid, ow4, OWf4);
}

// ============ stage-1 GEMMs (offset + Y) merged: grid (4, 98) ============
__global__ __launch_bounds__(256) void k_gemms1(
    const short* __restrict__ Xf, const short* __restrict__ OWbf,
    const short* __restrict__ W1f,
    float* __restrict__ Zp, float* __restrict__ Y1)
{
    const int tid = threadIdx.x;
    const int wv = tid >> 6;
    const int l  = tid & 63;
    const int l15 = l & 15, l4 = l >> 4;
    const int mtile = blockIdx.x * 4 + wv;
    const int by = blockIdx.y;

    const bf16x8* Ah = (const bf16x8*)Xf + (size_t)mtile * 2048 + l4 * 16 + l15;
    const bf16x8* Al = Ah + 32768;
    const int m0 = mtile * 16 + l4 * 4;

    if (by < 49) {
        const int d = by;
        const bf16x8* Bb = (const bf16x8*)OWbf + (size_t)d * 7 * 2048 + l4 * 16 + l15;
        f32x4 acc[7];
        #pragma unroll
        for (int nt = 0; nt < 7; ++nt) acc[nt] = (f32x4){0.f, 0.f, 0.f, 0.f};
        for (int kb = 0; kb < 32; ++kb) {
            const bf16x8 ah = Ah[kb * 64];
            const bf16x8 al = Al[kb * 64];
            #pragma unroll
            for (int nt = 0; nt < 7; ++nt) {
                const bf16x8 b = Bb[(size_t)nt * 2048 + kb * 64];
                acc[nt] = __builtin_amdgcn_mfma_f32_16x16x32_bf16(ah, b, acc[nt], 0, 0, 0);
                acc[nt] = __builtin_amdgcn_mfma_f32_16x16x32_bf16(al, b, acc[nt], 0, 0, 0);
            }
        }
        #pragma unroll
        for (int nt = 0; nt < 7; ++nt) {
            const int oc = nt * 16 + l15;
            if (oc < 98) {
                #pragma unroll
                for (int r = 0; r < 4; ++r)
                    Zp[((size_t)d * 256 + m0 + r) * 98 + oc] = acc[nt][r];
            }
        }
    } else {
        const int d = by - 49;
        const bf16x8* Bh = (const bf16x8*)W1f + (size_t)d * 4 * 2048 + l4 * 16 + l15;
        const bf16x8* Bl = Bh + 401408;
        f32x4 acc[4];
        #pragma unroll
        for (int nt = 0; nt < 4; ++nt) acc[nt] = (f32x4){0.f, 0.f, 0.f, 0.f};
        for (int kb = 0; kb < 32; ++kb) {
            const bf16x8 ah = Ah[kb * 64];
            const bf16x8 al = Al[kb * 64];
            #pragma unroll
            for (int nt = 0; nt < 4; ++nt) {
                const bf16x8 bh = Bh[nt * 2048 + kb * 64];
                const bf16x8 bl = Bl[nt * 2048 + kb * 64];
                acc[nt] = __builtin_amdgcn_mfma_f32_16x16x32_bf16(ah, bh, acc[nt], 0, 0, 0);
                acc[nt] = __builtin_amdgcn_mfma_f32_16x16x32_bf16(ah, bl, acc[nt], 0, 0, 0);
                acc[nt] = __builtin_amdgcn_mfma_f32_16x16x32_bf16(al, bh, acc[nt], 0, 0, 0);
            }
        }
        #pragma unroll
        for (int nt = 0; nt < 4; ++nt) {
            const int f = nt * 16 + l15;
            #pragma unroll
            for (int r = 0; r < 4; ++r)
                Y1[((size_t)d * 256 + m0 + r) * 64 + f] = acc[nt][r];
        }
    }
}

// ============ sparams device fns ============
__device__ __forceinline__ void d_bilin(
    const float accy, const float accx, const int hp, const int wp,
    const int b, const int k, const int H, const int W, const int Hp, const int Wp,
    float& s_out, int& src_out)
{
    const float y = (float)(hp + (k / 7) - 3) + accy;
    const float x = (float)(wp + (k % 7) - 3) + accx;
    const float fy0 = floorf(y), fx0 = floorf(x);
    const int iy0 = (int)fy0, ix0 = (int)fx0;
    const float wy1 = y - fy0, wx1 = x - fx0;
    int ye, xe; float wy, wx;
    if (iy0 & 1) { ye = iy0 + 1; wy = wy1; } else { ye = iy0; wy = 1.f - wy1; }
    if (ix0 & 1) { xe = ix0 + 1; wx = wx1; } else { xe = ix0; wx = 1.f - wx1; }
    float s = wy * wx;
    int src = 0;
    if (ye >= 0 && ye < Hp && xe >= 0 && xe < Wp)
        src = (b * H + (ye >> 1)) * W + (xe >> 1);
    else
        s = 0.f;
    s_out = s;
    src_out = src;
}

// ============ stage-1 combine (fused sparams_z1): grid 256, PPB=4, F=64 =====
__global__ __launch_bounds__(256) void k_combine1(
    const float* __restrict__ Y, const float* __restrict__ Zp,
    const float* __restrict__ OB, const float* __restrict__ bias,
    short* __restrict__ xhi, short* __restrict__ xlo)
{
    __shared__ float ss[4][49];
    __shared__ int   isrc[4][49];
    const int tid = threadIdx.x;

    if (tid < 196) {
        const int p = tid / 49, k = tid - p * 49;
        const int pixg = blockIdx.x * 4 + p;
        const int b   = pixg >> 9;
        const int rem = pixg & 511;
        const int hp  = rem >> 5;
        const int wp  = rem & 31;
        float accy = OB[2 * k], accx = OB[2 * k + 1];
        const int di0 = (hp + 1) & 1, dj0 = (wp + 1) & 1;
        for (int di = di0; di < 7; di += 2) {
            const int yp = hp + di - 3;
            if ((unsigned)yp >= 16u) continue;
            const int ys = yp >> 1;
            for (int dj = dj0; dj < 7; dj += 2) {
                const int xp = wp + dj - 3;
                if ((unsigned)xp >= 32u) continue;
                const int xs = xp >> 1;
                const size_t o = ((size_t)((di * 7 + dj) * 256 + (b * 8 + ys) * 16 + xs)) * 98 + 2 * k;
                accy += Zp[o];
                accx += Zp[o + 1];
            }
        }
        d_bilin(accy, accx, hp, wp, b, k, 8, 16, 16, 32, ss[p][k], isrc[p][k]);
    }
    __syncthreads();

    const int f = tid & 63;
    const int p = tid >> 6;
    const int pixg = blockIdx.x * 4 + p;
    float acc = bias[f];
    #pragma unroll 7
    for (int k = 0; k < K49; ++k)
        acc = fmaf(ss[p][k], Y[((size_t)k * 256 + isrc[p][k]) * 64 + f], acc);
    const float v = fmaxf(acc, 0.f);
    const size_t o = (size_t)pixg * 64 + f;
    const short h = f2bf(v);
    xhi[o] = h;
    xlo[o] = f2bf(v - bf2f(h));
}

// ============ stages 2-3 GEMMs merged (offmfma + ygemm23): grid (gx, 53) ====
template<int C, int F>
__global__ __launch_bounds__(256) void k_gemms23(
    const short* __restrict__ Xbf, const short* __restrict__ OWf,
    const short* __restrict__ Wf,
    float* __restrict__ off, float* __restrict__ Y,
    const int H, const int W, const int Hp, const int Wp,
    const int M, const int nX)
{
    const int tid = threadIdx.x;
    const int wv = tid >> 6;
    const int l  = tid & 63;
    const int l15 = l & 15, l4 = l >> 4;
    const int by = blockIdx.y;

    if (by < 4) {
        // ---- offset conv, class by ----
        const int cls = by;
        const int pi = cls >> 1, rho = cls & 1;
        const int NRc = pi ? 4 : 3, NCc = rho ? 4 : 3;
        const int T = NRc * NCc;
        int nkb, clsoff;
        if (C == 64) { nkb = T * 2; clsoff = cls == 0 ? 0 : cls == 1 ? 18 : cls == 2 ? 42 : 66; }
        else         { nkb = T;     clsoff = cls == 0 ? 0 : cls == 1 ? 9  : cls == 2 ? 21 : 33; }

        const int Wt16 = W >> 4;
        const int mt = blockIdx.x * 4 + wv;
        const int rloc = mt / Wt16, xt = mt - rloc * Wt16;
        const int b = rloc / H;
        const int ysp = rloc - b * H;

        f32x4 acc[7];
        #pragma unroll
        for (int nt = 0; nt < 7; ++nt) acc[nt] = (f32x4){0.f, 0.f, 0.f, 0.f};

        const bf16x8* Bbase = (const bf16x8*)OWf + ((size_t)clsoff * 7) * 64 + l4 * 16 + l15;

        for (int kb = 0; kb < nkb; ++kb) {
            int tl, c0;
            if (C == 64) { tl = kb >> 1; c0 = ((kb & 1) << 5) + l4 * 8; }
            else         { tl = kb;      c0 = l4 * 8; }
            int iy, ix;
            if (NCc == 4) { iy = tl >> 2; ix = tl & 3; }
            else          { iy = tl / 3;  ix = tl - iy * 3; }
            const int ys = ysp + iy - 1;
            const int xs = xt * 16 + l15 + ix - 1;
            bf16x8 ah = {0, 0, 0, 0, 0, 0, 0, 0};
            bf16x8 al = {0, 0, 0, 0, 0, 0, 0, 0};
            if ((unsigned)ys < (unsigned)H && (unsigned)xs < (unsigned)W) {
                const size_t a = ((size_t)(b * H + ys) * W + xs) * C + c0;
                ah = *(const bf16x8*)(Xbf + a);
                al = *(const bf16x8*)(Xbf + nX + a);
            }
            const bf16x8* Bb = Bbase + (size_t)kb * 7 * 64;
            #pragma unroll
            for (int nt = 0; nt < 7; ++nt) {
                const bf16x8 bf = Bb[nt * 64];
                acc[nt] = __builtin_amdgcn_mfma_f32_16x16x32_bf16(ah, bf, acc[nt], 0, 0, 0);
                acc[nt] = __builtin_amdgcn_mfma_f32_16x16x32_bf16(al, bf, acc[nt], 0, 0, 0);
            }
        }

        const int hp = 2 * ysp + pi;
        const int wpbase = (xt << 5) + rho;
        const int pixrow = (b * Hp + hp) * Wp + wpbase;
        #pragma unroll
        for (int nt = 0; nt < 7; ++nt) {
            const int oc = nt * 16 + l15;
            if (oc < 98) {
                #pragma unroll
                for (int r = 0; r < 4; ++r) {
                    const int m = l4 * 4 + r;
                    off[(size_t)(pixrow + 2 * m) * 98 + oc] = acc[nt][r];
                }
            }
        }
    } else {
        // ---- Y GEMM, tap d ----
        constexpr int KB = C / 32;
        constexpr int NT = F / 16;
        constexpr int PLANEFRAG = 49 * NT * KB * 64;
        const int d = by - 4;
        const int mtile = blockIdx.x * 4 + wv;
        const short* Arow = Xbf + (size_t)(mtile * 16 + l15) * C + l4 * 8;

        f32x4 acc[NT];
        #pragma unroll
        for (int nt = 0; nt < NT; ++nt) acc[nt] = (f32x4){0.f, 0.f, 0.f, 0.f};

        #pragma unroll
        for (int kb = 0; kb < KB; ++kb) {
            const bf16x8 ah = *(const bf16x8*)(Arow + kb * 32);
            const bf16x8 al = *(const bf16x8*)(Arow + nX + kb * 32);
            #pragma unroll
            for (int nt = 0; nt < NT; ++nt) {
                const size_t fi = ((size_t)(d * NT + nt) * KB + kb) * 64 + l4 * 16 + l15;
                const bf16x8 bh = ((const bf16x8*)Wf)[fi];
                const bf16x8 bl = ((const bf16x8*)Wf)[fi + PLANEFRAG];
                acc[nt] = __builtin_amdgcn_mfma_f32_16x16x32_bf16(ah, bh, acc[nt], 0, 0, 0);
                acc[nt] = __builtin_amdgcn_mfma_f32_16x16x32_bf16(ah, bl, acc[nt], 0, 0, 0);
                acc[nt] = __builtin_amdgcn_mfma_f32_16x16x32_bf16(al, bh, acc[nt], 0, 0, 0);
            }
        }

        const int m0 = mtile * 16 + l4 * 4;
        #pragma unroll
        for (int nt = 0; nt < NT; ++nt) {
            const int f = nt * 16 + l15;
            #pragma unroll
            for (int r = 0; r < 4; ++r)
                Y[((size_t)d * M + m0 + r) * F + f] = acc[nt][r];
        }
    }
}

// ============ stages 2-3 combine (fused sparams, optional Y4) ============
template<int F, bool DO_Y4>
__global__ __launch_bounds__(256) void k_combine23(
    const float* __restrict__ Y, const float* __restrict__ off,
    const float* __restrict__ OB, const float* __restrict__ bias,
    short* __restrict__ xhi, short* __restrict__ xlo,
    const float* __restrict__ w4, float* __restrict__ Y4,
    const int npix, const int nsrc,
    const int H, const int W, const int Hp, const int Wp)
{
    constexpr int PPB = 256 / F;
    __shared__ float ss[PPB][49];
    __shared__ int   isrc[PPB][49];
    __shared__ float xv[DO_Y4 ? PPB : 1][DO_Y4 ? 17 : 1];
    __shared__ float w4s[DO_Y4 ? 784 : 1];
    const int tid = threadIdx.x;
    const int HWp = Hp * Wp;

    if (DO_Y4) {
        for (int t = tid; t < 784; t += 256) w4s[t] = w4[t];
    }
    for (int t = tid; t < PPB * 49; t += 256) {
        const int p = t / 49, k = t - p * 49;
        const int pixg = blockIdx.x * PPB + p;
        const float accy = OB[2 * k]     + off[(size_t)pixg * 98 + 2 * k];
        const float accx = OB[2 * k + 1] + off[(size_t)pixg * 98 + 2 * k + 1];
        const int b = pixg / HWp;
        const int rem = pixg - b * HWp;
        const int hp = rem / Wp;
        const int wp = rem - hp * Wp;
        d_bilin(accy, accx, hp, wp, b, k, H, W, Hp, Wp, ss[p][k], isrc[p][k]);
    }
    __syncthreads();

    const int f = tid % F;
    const int p2 = tid / F;
    const int pixg2 = blockIdx.x * PPB + p2;
    float acc = bias[f];
    #pragma unroll 7
    for (int k = 0; k < K49; ++k)
        acc = fmaf(ss[p2][k], Y[((size_t)k * nsrc + isrc[p2][k]) * F + f], acc);
    const float v = fmaxf(acc, 0.f);
    const size_t o = (size_t)pixg2 * F + f;
    const short h = f2bf(v);
    xhi[o] = h;
    xlo[o] = f2bf(v - bf2f(h));

    if (DO_Y4) {
        xv[p2][f] = v;
        __syncthreads();
        for (int t = tid; t < PPB * 49; t += 256) {
            const int p = t / 49, k = t - p * 49;
            float d = 0.f;
            #pragma unroll
            for (int f2 = 0; f2 < 16; ++f2)
                d = fmaf(xv[p][f2], w4s[k * 16 + f2], d);
            Y4[(size_t)k * npix + blockIdx.x * PPB + p] = d;
        }
    }
}

// ============ stage-4 offset conv via implicit-GEMM MFMA ===============
__global__ __launch_bounds__(256) void k_offmfma4(
    const short* __restrict__ Xbf, const short* __restrict__ OWf,
    float* __restrict__ off,
    const int H, const int W, const int Hp, const int Wp, const int nX)
{
    constexpr int C = 16;
    const int tid = threadIdx.x;
    const int wv = tid >> 6;
    const int l  = tid & 63;
    const int l15 = l & 15, l4 = l >> 4;
    const int cls = blockIdx.y;
    const int pi = cls >> 1, rho = cls & 1;
    const int NRc = pi ? 4 : 3, NCc = rho ? 4 : 3;
    const int T = NRc * NCc;
    const int nkb = (T + 1) >> 1;
    const int clsoff = cls == 0 ? 0 : cls == 1 ? 5 : cls == 2 ? 11 : 17;

    const int Wt16 = W >> 4;
    const int mt = blockIdx.x * 4 + wv;
    const int rloc = mt / Wt16, xt = mt - rloc * Wt16;
    const int b = rloc / H;
    const int ysp = rloc - b * H;

    f32x4 acc[7];
    #pragma unroll
    for (int nt = 0; nt < 7; ++nt) acc[nt] = (f32x4){0.f, 0.f, 0.f, 0.f};

    const bf16x8* Bbase = (const bf16x8*)OWf + ((size_t)clsoff * 7) * 64 + l4 * 16 + l15;

    for (int kb = 0; kb < nkb; ++kb) {
        int tl = kb * 2 + (l4 >> 1);
        const int c0 = (l4 & 1) * 8;
        if (tl >= T) tl = T - 1;
        int iy, ix;
        if (NCc == 4) { iy = tl >> 2; ix = tl & 3; }
        else          { iy = tl / 3;  ix = tl - iy * 3; }
        const int ys = ysp + iy - 1;
        const int xs = xt * 16 + l15 + ix - 1;
        bf16x8 ah = {0, 0, 0, 0, 0, 0, 0, 0};
        bf16x8 al = {0, 0, 0, 0, 0, 0, 0, 0};
        if ((unsigned)ys < (unsigned)H && (unsigned)xs < (unsigned)W) {
            const size_t a = ((size_t)(b * H + ys) * W + xs) * C + c0;
            ah = *(const bf16x8*)(Xbf + a);
            al = *(const bf16x8*)(Xbf + nX + a);
        }
        const bf16x8* Bb = Bbase + (size_t)kb * 7 * 64;
        #pragma unroll
        for (int nt = 0; nt < 7; ++nt) {
            const bf16x8 bf = Bb[nt * 64];
            acc[nt] = __builtin_amdgcn_mfma_f32_16x16x32_bf16(ah, bf, acc[nt], 0, 0, 0);
            acc[nt] = __builtin_amdgcn_mfma_f32_16x16x32_bf16(al, bf, acc[nt], 0, 0, 0);
        }
    }

    const int hp = 2 * ysp + pi;
    const int wpbase = (xt << 5) + rho;
    const int pixrow = (b * Hp + hp) * Wp + wpbase;
    #pragma unroll
    for (int nt = 0; nt < 7; ++nt) {
        const int oc = nt * 16 + l15;
        if (oc < 98) {
            #pragma unroll
            for (int r = 0; r < 4; ++r) {
                const int m = l4 * 4 + r;
                off[(size_t)(pixrow + 2 * m) * 98 + oc] = acc[nt][r];
            }
        }
    }
}

// ============ stage 4: fused sparams + gather-combine via Y4 ===
__global__ __launch_bounds__(256) void k_dconv_f1_y(
    const float* __restrict__ Y4,       // [49][nsrc]
    const float* __restrict__ part,     // [npix, 98] raw offset conv
    const float* __restrict__ OB,       // [98]
    const float* __restrict__ bias, float* __restrict__ out,
    const int H, const int W, const int Hp, const int Wp,
    const int nsrc)
{
    __shared__ float OBs[98];
    const int tid = threadIdx.x;
    if (tid < 98) OBs[tid] = OB[tid];
    __syncthreads();

    const int pixL = blockIdx.x * 64 + (tid >> 2);
    const int tq = tid & 3;
    const int t0 = (tq == 0) ? 0 : 13 + (tq - 1) * 12;
    const int t1 = t0 + ((tq == 0) ? 13 : 12);

    const int HWp = Hp * Wp;
    const int b = pixL / HWp;
    const int rem = pixL - b * HWp;
    const int hp = rem / Wp;
    const int wp = rem - hp * Wp;

    float acc = 0.f;
    for (int k = t0; k < t1; ++k) {
        const float offy = part[(size_t)pixL * 98 + 2 * k]     + OBs[2 * k];
        const float offx = part[(size_t)pixL * 98 + 2 * k + 1] + OBs[2 * k + 1];
        float s; int src;
        d_bilin(offy, offx, hp, wp, b, k, H, W, Hp, Wp, s, src);
        acc = fmaf(s, Y4[(size_t)k * nsrc + src], acc);
    }
    acc += __shfl_xor(acc, 1);
    acc += __shfl_xor(acc, 2);
    if (tq == 0) out[pixL] = acc + bias[0];
}

extern "C" void kernel_launch(void* const* d_in, const int* in_sizes, int n_in,
                              void* d_out, int out_size, void* d_ws, size_t ws_size,
                              hipStream_t stream) {
    const float* z   = (const float*)d_in[0];
    const float* dw  = (const float*)d_in[1];
    const float* db  = (const float*)d_in[2];
    const float* ow1 = (const float*)d_in[3];
    const float* ob1 = (const float*)d_in[4];
    const float* w1  = (const float*)d_in[5];
    const float* b1  = (const float*)d_in[6];
    const float* ow2 = (const float*)d_in[7];
    const float* ob2 = (const float*)d_in[8];
    const float* w2  = (const float*)d_in[9];
    const float* b2  = (const float*)d_in[10];
    const float* ow3 = (const float*)d_in[11];
    const float* ob3 = (const float*)d_in[12];
    const float* w3  = (const float*)d_in[13];
    const float* b3  = (const float*)d_in[14];
    const float* ow4 = (const float*)d_in[15];
    const float* ob4 = (const float*)d_in[16];
    const float* w4  = (const float*)d_in[17];
    const float* b4  = (const float*)d_in[18];

    // workspace layout: ~95 MB, no aliasing (ws_size = 256 MiB)
    float* ws   = (float*)d_ws;
    short* Xf   = (short*)ws;                    // 524,288 sh
    float* Zp   = ws + 262144;                   // 1,229,312
    float* Y1   = Zp + 1229312;                  // 802,816
    float* Y2   = Y1 + 802816;                   // 1,605,632
    float* Y3   = Y2 + 1605632;                  // 3,211,264
    float* Y4   = Y3 + 3211264;                  // 802,816
    short* Xbf1 = (short*)(Y4 + 802816);         // 131,072 sh
    short* Xbf2 = Xbf1 + 131072;                 // 262,144 sh
    short* Xbf3 = Xbf2 + 262144;                 // 524,288 sh
    float* off2 = (float*)(Xbf3 + 524288);       // 401,408
    float* off3 = off2 + 401408;                 // 1,605,632
    float* off4 = off3 + 1605632;                // 6,422,528
    short* OWbf = (short*)(off4 + 6422528);      // 5,619,712 sh
    short* W1f  = OWbf + 5619712;                // 6,422,528 sh
    short* OWf2 = W1f + 6422528;                 // 351,232 sh
    short* W2f  = OWf2 + 351232;                 // 200,704 sh
    short* OWf3 = W2f + 200704;                  // 175,616 sh
    short* W3f  = OWf3 + 175616;                 // 50,176 sh
    short* OWf4 = W3f + 50176;                   // 89,600 sh

    float* out = (float*)d_out;

    // 1) dense+cvt AND all weight packing (independent, one launch)
    k_prep<<<7294, 256, 0, stream>>>(z, dw, db, Xf, ow1, w1, ow2, w2, ow3, w3, ow4,
                                     OWbf, W1f, OWf2, W2f, OWf3, W3f, OWf4);

    // 2) stage-1 GEMMs (offset + Y, merged)
    k_gemms1<<<dim3(4, 98), 256, 0, stream>>>(Xf, OWbf, W1f, Zp, Y1);

    // 3) stage-1 combine (fused sparams_z1) -> Xbf1
    k_combine1<<<256, 256, 0, stream>>>(Y1, Zp, ob1, b1, Xbf1, Xbf1 + 65536);

    // 4) stage-2 GEMMs (offmfma + ygemm, merged)
    k_gemms23<64, 32><<<dim3(16, 53), 256, 0, stream>>>(
        Xbf1, OWf2, W2f, off2, Y2, 16, 32, 32, 64, 1024, 65536);

    // 5) stage-2 combine -> Xbf2
    k_combine23<32, false><<<512, 256, 0, stream>>>(
        Y2, off2, ob2, b2, Xbf2, Xbf2 + 131072, nullptr, nullptr, 4096, 1024, 16, 32, 32, 64);

    // 6) stage-3 GEMMs
    k_gemms23<32, 16><<<dim3(64, 53), 256, 0, stream>>>(
        Xbf2, OWf3, W3f, off3, Y3, 32, 64, 64, 128, 4096, 131072);

    // 7) stage-3 combine + Y4 -> Xbf3, Y4
    k_combine23<16, true><<<1024, 256, 0, stream>>>(
        Y3, off3, ob3, b3, Xbf3, Xbf3 + 262144, w4, Y4, 16384, 4096, 32, 64, 64, 128);

    // 8) stage-4 offset conv
    k_offmfma4<<<dim3(256, 4), 256, 0, stream>>>(Xbf3, OWf4, off4, 64, 128, 128, 256, 262144);

    // 9) stage-4 dconv -> out
    k_dconv_f1_y<<<1024, 256, 0, stream>>>(Y4, off4, ob4, b4, out, 64, 128, 128, 256, 16384);
}

// Round 12
// 153.788 us; speedup vs baseline: 2.1401x; 1.2193x over previous
//
#include <hip/hip_runtime.h>
#include <hip/hip_bf16.h>

#define K49 49

typedef short bf16x8 __attribute__((ext_vector_type(8)));
typedef float f32x4 __attribute__((ext_vector_type(4)));

__device__ __forceinline__ short f2bf(float x) {
    __hip_bfloat16 h = __float2bfloat16(x);
    return __builtin_bit_cast(short, h);
}
__device__ __forceinline__ float bf2f(short s) {
    unsigned u = ((unsigned)(unsigned short)s) << 16;
    return __builtin_bit_cast(float, u);
}

// ==================== weight packing (device fns) ====================
__device__ __forceinline__ void d_pack_ow1(
    const int gid, const float* __restrict__ OW, short* __restrict__ OWbf)
{
    const int ni = gid & 15;
    int t = gid >> 4;
    const int kg = t & 3;  t >>= 2;
    const int kb = t & 31; t >>= 5;
    const int nt = t % 7;
    const int d  = t / 7;
    const int oc = nt * 16 + ni;
    short h[8];
    if (oc < 98) {
        const int c0 = kb * 32 + kg * 8;
        #pragma unroll
        for (int j = 0; j < 8; ++j)
            h[j] = f2bf(OW[((size_t)d * 1024 + c0 + j) * 98 + oc]);
    } else {
        #pragma unroll
        for (int j = 0; j < 8; ++j) h[j] = 0;
    }
    *(bf16x8*)(OWbf + (size_t)gid * 8) = *(bf16x8*)h;
}

template<int C, int F>
__device__ __forceinline__ void d_pack_w(
    const int gid, const float* __restrict__ Wt, short* __restrict__ Wf)
{
    constexpr int KB = C / 32;
    constexpr int NT = F / 16;
    constexpr int PLANE = 49 * NT * KB * 4 * 16 * 8;   // shorts
    const int ni = gid & 15;
    int t = gid >> 4;
    const int kg = t & 3; t >>= 2;
    const int kb = t % KB; t /= KB;
    const int nt = t % NT;
    const int d  = t / NT;
    const int f = nt * 16 + ni;
    const int c0 = kb * 32 + kg * 8;
    short hi[8], lo[8];
    #pragma unroll
    for (int j = 0; j < 8; ++j) {
        const float v = Wt[((size_t)d * C + c0 + j) * F + f];
        hi[j] = f2bf(v);
        lo[j] = f2bf(v - bf2f(hi[j]));
    }
    *(bf16x8*)(Wf + (size_t)gid * 8) = *(bf16x8*)hi;
    *(bf16x8*)(Wf + PLANE + (size_t)gid * 8) = *(bf16x8*)lo;
}

template<int C>
__device__ __forceinline__ void d_pack_owf(
    const int gid, const float* __restrict__ OW, short* __restrict__ OWf)
{
    const int j = gid & 7;
    int t = gid >> 3;
    const int fi = t & 63; t >>= 6;
    const int nt = t % 7;
    const int kbg = t / 7;
    const int ni = fi & 15, kg = fi >> 4;

    int cum1, cum2, cum3;
    if (C == 64)      { cum1 = 18; cum2 = 42; cum3 = 66; }
    else if (C == 32) { cum1 = 9;  cum2 = 21; cum3 = 33; }
    else              { cum1 = 5;  cum2 = 11; cum3 = 17; }
    int cls, kb0;
    if (kbg < cum1)      { cls = 0; kb0 = 0; }
    else if (kbg < cum2) { cls = 1; kb0 = cum1; }
    else if (kbg < cum3) { cls = 2; kb0 = cum2; }
    else                 { cls = 3; kb0 = cum3; }
    const int kbl = kbg - kb0;
    const int pi = cls >> 1, rho = cls & 1;
    const int NRc = pi ? 4 : 3, NCc = rho ? 4 : 3;
    const int T = NRc * NCc;

    const int k = kbl * 32 + kg * 8 + j;
    const int tl = k / C, c = k - tl * C;
    const int oc = nt * 16 + ni;
    float v = 0.f;
    if (tl < T && oc < 98) {
        const int iy = tl / NCc, ix = tl - iy * NCc;
        const int d = (1 - pi + 2 * iy) * 7 + (1 - rho + 2 * ix);
        v = OW[((size_t)d * C + c) * 98 + oc];
    }
    OWf[gid] = f2bf(v);
}

// ==================== mega prep kernel: dense+cvt AND all weight packs =====
// Xf layout (bf16): [plane(2)][mtile(16)][kb(32)][kg(4)][mi(16)][8]
__global__ __launch_bounds__(256) void k_prep(
    const float* __restrict__ z, const float* __restrict__ Wd,
    const float* __restrict__ bd, short* __restrict__ Xf,
    const float* __restrict__ ow1, const float* __restrict__ w1,
    const float* __restrict__ ow2, const float* __restrict__ w2,
    const float* __restrict__ ow3, const float* __restrict__ w3,
    const float* __restrict__ ow4,
    short* OWbf, short* W1f, short* OWf2, short* W2f,
    short* OWf3, short* W3f, short* OWf4)
{
    const int bid0 = blockIdx.x;
    const int tid = threadIdx.x;
    __shared__ float zs[256];
    if (bid0 < 512) {
        const int D = 131072;
        zs[tid] = z[tid];
        __syncthreads();
        const int n = bid0 * 256 + tid;
        const float bb = bd[n];
        float a0 = bb, a1 = bb;
        #pragma unroll 8
        for (int kk = 0; kk < 128; ++kk) {
            const float w = Wd[kk * D + n];
            a0 = fmaf(zs[kk], w, a0);
            a1 = fmaf(zs[128 + kk], w, a1);
        }
        a0 = fmaxf(a0, 0.f);
        a1 = fmaxf(a1, 0.f);
        const int c = n & 1023;
        const int m0 = n >> 10;
        const int kb = c >> 5, kg = (c >> 3) & 3, j = c & 7;
        const size_t base = ((size_t)kb * 4 + kg) * 16 * 8 + j;
        {
            const size_t dst = ((size_t)(m0 >> 4) * 2048) * 8 + base + (size_t)(m0 & 15) * 8;
            const short h = f2bf(a0);
            Xf[dst] = h;
            Xf[262144 + dst] = f2bf(a0 - bf2f(h));
        }
        {
            const int m1 = m0 + 128;
            const size_t dst = ((size_t)(m1 >> 4) * 2048) * 8 + base + (size_t)(m1 & 15) * 8;
            const short h = f2bf(a1);
            Xf[dst] = h;
            Xf[262144 + dst] = f2bf(a1 - bf2f(h));
        }
        return;
    }
    const int bid = bid0 - 512;
    if (bid < 2744)      d_pack_ow1((bid) * 256 + tid, ow1, OWbf);
    else if (bid < 4312) d_pack_w<1024, 64>((bid - 2744) * 256 + tid, w1, W1f);
    else if (bid < 5684) d_pack_owf<64>((bid - 4312) * 256 + tid, ow2, OWf2);
    else if (bid < 5733) d_pack_w<64, 32>((bid - 5684) * 256 + tid, w2, W2f);
    else if (bid < 6419) d_pack_owf<32>((bid - 5733) * 256 + tid, ow3, OWf3);
    else if (bid < 6432) { const int g = (bid - 6419) * 256 + tid; if (g < 3136) d_pack_w<32, 16>(g, w3, W3f); }
    else                 d_pack_owf<16>((bid - 6432) * 256 + tid, ow4, OWf4);
}

// ============ stage-1 GEMMs, K-split x4 + XCD swizzle: grid (4, 98, 4) =====
// Zp partial: [ks][49][256][98]; Y1 partial: [ks][49][256][64]
__global__ __launch_bounds__(256) void k_gemms1(
    const short* __restrict__ Xf, const short* __restrict__ OWbf,
    const short* __restrict__ W1f,
    float* __restrict__ Zp, float* __restrict__ Y1)
{
    const int tid = threadIdx.x;
    const int wv = tid >> 6;
    const int l  = tid & 63;
    const int l15 = l & 15, l4 = l >> 4;

    // XCD-aware swizzle: 4 M-sibling blocks (same B-slice) -> same XCD
    const int wid = blockIdx.x + 4 * (blockIdx.y + 98 * blockIdx.z);  // 0..1567
    const int work = (wid & 7) * 196 + (wid >> 3);
    const int x    = work & 3;
    const int rest = work >> 2;          // 0..391
    const int ks   = rest / 98;
    const int by   = rest - ks * 98;

    const int mtile = x * 4 + wv;
    const int kb0 = ks * 8;

    const bf16x8* Ah = (const bf16x8*)Xf + (size_t)mtile * 2048 + l4 * 16 + l15;
    const bf16x8* Al = Ah + 32768;
    const int m0 = mtile * 16 + l4 * 4;

    if (by < 49) {
        const int d = by;
        const bf16x8* Bb = (const bf16x8*)OWbf + (size_t)d * 7 * 2048 + l4 * 16 + l15;
        f32x4 acc[7];
        #pragma unroll
        for (int nt = 0; nt < 7; ++nt) acc[nt] = (f32x4){0.f, 0.f, 0.f, 0.f};
        #pragma unroll
        for (int i = 0; i < 8; ++i) {
            const int kb = kb0 + i;
            const bf16x8 ah = Ah[kb * 64];
            const bf16x8 al = Al[kb * 64];
            #pragma unroll
            for (int nt = 0; nt < 7; ++nt) {
                const bf16x8 b = Bb[(size_t)nt * 2048 + kb * 64];
                acc[nt] = __builtin_amdgcn_mfma_f32_16x16x32_bf16(ah, b, acc[nt], 0, 0, 0);
                acc[nt] = __builtin_amdgcn_mfma_f32_16x16x32_bf16(al, b, acc[nt], 0, 0, 0);
            }
        }
        float* Zo = Zp + (size_t)ks * 1229312;
        #pragma unroll
        for (int nt = 0; nt < 7; ++nt) {
            const int oc = nt * 16 + l15;
            if (oc < 98) {
                #pragma unroll
                for (int r = 0; r < 4; ++r)
                    Zo[((size_t)d * 256 + m0 + r) * 98 + oc] = acc[nt][r];
            }
        }
    } else {
        const int d = by - 49;
        const bf16x8* Bh = (const bf16x8*)W1f + (size_t)d * 4 * 2048 + l4 * 16 + l15;
        const bf16x8* Bl = Bh + 401408;
        f32x4 acc[4];
        #pragma unroll
        for (int nt = 0; nt < 4; ++nt) acc[nt] = (f32x4){0.f, 0.f, 0.f, 0.f};
        #pragma unroll
        for (int i = 0; i < 8; ++i) {
            const int kb = kb0 + i;
            const bf16x8 ah = Ah[kb * 64];
            const bf16x8 al = Al[kb * 64];
            #pragma unroll
            for (int nt = 0; nt < 4; ++nt) {
                const bf16x8 bh = Bh[nt * 2048 + kb * 64];
                const bf16x8 bl = Bl[nt * 2048 + kb * 64];
                acc[nt] = __builtin_amdgcn_mfma_f32_16x16x32_bf16(ah, bh, acc[nt], 0, 0, 0);
                acc[nt] = __builtin_amdgcn_mfma_f32_16x16x32_bf16(ah, bl, acc[nt], 0, 0, 0);
                acc[nt] = __builtin_amdgcn_mfma_f32_16x16x32_bf16(al, bh, acc[nt], 0, 0, 0);
            }
        }
        float* Yo = Y1 + (size_t)ks * 802816;
        #pragma unroll
        for (int nt = 0; nt < 4; ++nt) {
            const int f = nt * 16 + l15;
            #pragma unroll
            for (int r = 0; r < 4; ++r)
                Yo[((size_t)d * 256 + m0 + r) * 64 + f] = acc[nt][r];
        }
    }
}

// ============ sparams device fn ============
__device__ __forceinline__ void d_bilin(
    const float accy, const float accx, const int hp, const int wp,
    const int b, const int k, const int H, const int W, const int Hp, const int Wp,
    float& s_out, int& src_out)
{
    const float y = (float)(hp + (k / 7) - 3) + accy;
    const float x = (float)(wp + (k % 7) - 3) + accx;
    const float fy0 = floorf(y), fx0 = floorf(x);
    const int iy0 = (int)fy0, ix0 = (int)fx0;
    const float wy1 = y - fy0, wx1 = x - fx0;
    int ye, xe; float wy, wx;
    if (iy0 & 1) { ye = iy0 + 1; wy = wy1; } else { ye = iy0; wy = 1.f - wy1; }
    if (ix0 & 1) { xe = ix0 + 1; wx = wx1; } else { xe = ix0; wx = 1.f - wx1; }
    float s = wy * wx;
    int src = 0;
    if (ye >= 0 && ye < Hp && xe >= 0 && xe < Wp)
        src = (b * H + (ye >> 1)) * W + (xe >> 1);
    else
        s = 0.f;
    s_out = s;
    src_out = src;
}

// ============ stage-1 combine (fused sparams_z1, 4 partials) ============
__global__ __launch_bounds__(256) void k_combine1(
    const float* __restrict__ Y, const float* __restrict__ Zp,
    const float* __restrict__ OB, const float* __restrict__ bias,
    short* __restrict__ xhi, short* __restrict__ xlo)
{
    __shared__ float ss[4][49];
    __shared__ int   isrc[4][49];
    const int tid = threadIdx.x;

    if (tid < 196) {
        const int p = tid / 49, k = tid - p * 49;
        const int pixg = blockIdx.x * 4 + p;
        const int b   = pixg >> 9;
        const int rem = pixg & 511;
        const int hp  = rem >> 5;
        const int wp  = rem & 31;
        float accy = OB[2 * k], accx = OB[2 * k + 1];
        const int di0 = (hp + 1) & 1, dj0 = (wp + 1) & 1;
        for (int di = di0; di < 7; di += 2) {
            const int yp = hp + di - 3;
            if ((unsigned)yp >= 16u) continue;
            const int ys = yp >> 1;
            for (int dj = dj0; dj < 7; dj += 2) {
                const int xp = wp + dj - 3;
                if ((unsigned)xp >= 32u) continue;
                const int xs = xp >> 1;
                const size_t o = ((size_t)((di * 7 + dj) * 256 + (b * 8 + ys) * 16 + xs)) * 98 + 2 * k;
                accy += (Zp[o] + Zp[o + 1229312]) + (Zp[o + 2458624] + Zp[o + 3687936]);
                accx += (Zp[o + 1] + Zp[o + 1229313]) + (Zp[o + 2458625] + Zp[o + 3687937]);
            }
        }
        d_bilin(accy, accx, hp, wp, b, k, 8, 16, 16, 32, ss[p][k], isrc[p][k]);
    }
    __syncthreads();

    const int f = tid & 63;
    const int p = tid >> 6;
    const int pixg = blockIdx.x * 4 + p;
    float acc = bias[f];
    #pragma unroll 7
    for (int k = 0; k < K49; ++k) {
        const size_t yo = ((size_t)k * 256 + isrc[p][k]) * 64 + f;
        const float yv = (Y[yo] + Y[yo + 802816]) + (Y[yo + 1605632] + Y[yo + 2408448]);
        acc = fmaf(ss[p][k], yv, acc);
    }
    const float v = fmaxf(acc, 0.f);
    const size_t o = (size_t)pixg * 64 + f;
    const short h = f2bf(v);
    xhi[o] = h;
    xlo[o] = f2bf(v - bf2f(h));
}

// ============ stages 2-3 GEMMs merged (offmfma + ygemm23): grid (gx, 53) ====
template<int C, int F>
__global__ __launch_bounds__(256) void k_gemms23(
    const short* __restrict__ Xbf, const short* __restrict__ OWf,
    const short* __restrict__ Wf,
    float* __restrict__ off, float* __restrict__ Y,
    const int H, const int W, const int Hp, const int Wp,
    const int M, const int nX)
{
    const int tid = threadIdx.x;
    const int wv = tid >> 6;
    const int l  = tid & 63;
    const int l15 = l & 15, l4 = l >> 4;
    const int by = blockIdx.y;

    if (by < 4) {
        const int cls = by;
        const int pi = cls >> 1, rho = cls & 1;
        const int NRc = pi ? 4 : 3, NCc = rho ? 4 : 3;
        const int T = NRc * NCc;
        int nkb, clsoff;
        if (C == 64) { nkb = T * 2; clsoff = cls == 0 ? 0 : cls == 1 ? 18 : cls == 2 ? 42 : 66; }
        else         { nkb = T;     clsoff = cls == 0 ? 0 : cls == 1 ? 9  : cls == 2 ? 21 : 33; }

        const int Wt16 = W >> 4;
        const int mt = blockIdx.x * 4 + wv;
        const int rloc = mt / Wt16, xt = mt - rloc * Wt16;
        const int b = rloc / H;
        const int ysp = rloc - b * H;

        f32x4 acc[7];
        #pragma unroll
        for (int nt = 0; nt < 7; ++nt) acc[nt] = (f32x4){0.f, 0.f, 0.f, 0.f};

        const bf16x8* Bbase = (const bf16x8*)OWf + ((size_t)clsoff * 7) * 64 + l4 * 16 + l15;

        for (int kb = 0; kb < nkb; ++kb) {
            int tl, c0;
            if (C == 64) { tl = kb >> 1; c0 = ((kb & 1) << 5) + l4 * 8; }
            else         { tl = kb;      c0 = l4 * 8; }
            int iy, ix;
            if (NCc == 4) { iy = tl >> 2; ix = tl & 3; }
            else          { iy = tl / 3;  ix = tl - iy * 3; }
            const int ys = ysp + iy - 1;
            const int xs = xt * 16 + l15 + ix - 1;
            bf16x8 ah = {0, 0, 0, 0, 0, 0, 0, 0};
            bf16x8 al = {0, 0, 0, 0, 0, 0, 0, 0};
            if ((unsigned)ys < (unsigned)H && (unsigned)xs < (unsigned)W) {
                const size_t a = ((size_t)(b * H + ys) * W + xs) * C + c0;
                ah = *(const bf16x8*)(Xbf + a);
                al = *(const bf16x8*)(Xbf + nX + a);
            }
            const bf16x8* Bb = Bbase + (size_t)kb * 7 * 64;
            #pragma unroll
            for (int nt = 0; nt < 7; ++nt) {
                const bf16x8 bf = Bb[nt * 64];
                acc[nt] = __builtin_amdgcn_mfma_f32_16x16x32_bf16(ah, bf, acc[nt], 0, 0, 0);
                acc[nt] = __builtin_amdgcn_mfma_f32_16x16x32_bf16(al, bf, acc[nt], 0, 0, 0);
            }
        }

        const int hp = 2 * ysp + pi;
        const int wpbase = (xt << 5) + rho;
        const int pixrow = (b * Hp + hp) * Wp + wpbase;
        #pragma unroll
        for (int nt = 0; nt < 7; ++nt) {
            const int oc = nt * 16 + l15;
            if (oc < 98) {
                #pragma unroll
                for (int r = 0; r < 4; ++r) {
                    const int m = l4 * 4 + r;
                    off[(size_t)(pixrow + 2 * m) * 98 + oc] = acc[nt][r];
                }
            }
        }
    } else {
        constexpr int KB = C / 32;
        constexpr int NT = F / 16;
        constexpr int PLANEFRAG = 49 * NT * KB * 64;
        const int d = by - 4;
        const int mtile = blockIdx.x * 4 + wv;
        const short* Arow = Xbf + (size_t)(mtile * 16 + l15) * C + l4 * 8;

        f32x4 acc[NT];
        #pragma unroll
        for (int nt = 0; nt < NT; ++nt) acc[nt] = (f32x4){0.f, 0.f, 0.f, 0.f};

        #pragma unroll
        for (int kb = 0; kb < KB; ++kb) {
            const bf16x8 ah = *(const bf16x8*)(Arow + kb * 32);
            const bf16x8 al = *(const bf16x8*)(Arow + nX + kb * 32);
            #pragma unroll
            for (int nt = 0; nt < NT; ++nt) {
                const size_t fi = ((size_t)(d * NT + nt) * KB + kb) * 64 + l4 * 16 + l15;
                const bf16x8 bh = ((const bf16x8*)Wf)[fi];
                const bf16x8 bl = ((const bf16x8*)Wf)[fi + PLANEFRAG];
                acc[nt] = __builtin_amdgcn_mfma_f32_16x16x32_bf16(ah, bh, acc[nt], 0, 0, 0);
                acc[nt] = __builtin_amdgcn_mfma_f32_16x16x32_bf16(ah, bl, acc[nt], 0, 0, 0);
                acc[nt] = __builtin_amdgcn_mfma_f32_16x16x32_bf16(al, bh, acc[nt], 0, 0, 0);
            }
        }

        const int m0 = mtile * 16 + l4 * 4;
        #pragma unroll
        for (int nt = 0; nt < NT; ++nt) {
            const int f = nt * 16 + l15;
            #pragma unroll
            for (int r = 0; r < 4; ++r)
                Y[((size_t)d * M + m0 + r) * F + f] = acc[nt][r];
        }
    }
}

// ============ stages 2-3 combine (fused sparams, optional Y4) ============
template<int F, bool DO_Y4>
__global__ __launch_bounds__(256) void k_combine23(
    const float* __restrict__ Y, const float* __restrict__ off,
    const float* __restrict__ OB, const float* __restrict__ bias,
    short* __restrict__ xhi, short* __restrict__ xlo,
    const float* __restrict__ w4, float* __restrict__ Y4,
    const int npix, const int nsrc,
    const int H, const int W, const int Hp, const int Wp)
{
    constexpr int PPB = 256 / F;
    __shared__ float ss[PPB][49];
    __shared__ int   isrc[PPB][49];
    __shared__ float xv[DO_Y4 ? PPB : 1][DO_Y4 ? 17 : 1];
    __shared__ float w4s[DO_Y4 ? 784 : 1];
    const int tid = threadIdx.x;
    const int HWp = Hp * Wp;

    if (DO_Y4) {
        for (int t = tid; t < 784; t += 256) w4s[t] = w4[t];
    }
    for (int t = tid; t < PPB * 49; t += 256) {
        const int p = t / 49, k = t - p * 49;
        const int pixg = blockIdx.x * PPB + p;
        const float accy = OB[2 * k]     + off[(size_t)pixg * 98 + 2 * k];
        const float accx = OB[2 * k + 1] + off[(size_t)pixg * 98 + 2 * k + 1];
        const int b = pixg / HWp;
        const int rem = pixg - b * HWp;
        const int hp = rem / Wp;
        const int wp = rem - hp * Wp;
        d_bilin(accy, accx, hp, wp, b, k, H, W, Hp, Wp, ss[p][k], isrc[p][k]);
    }
    __syncthreads();

    const int f = tid % F;
    const int p2 = tid / F;
    const int pixg2 = blockIdx.x * PPB + p2;
    float acc = bias[f];
    #pragma unroll 7
    for (int k = 0; k < K49; ++k)
        acc = fmaf(ss[p2][k], Y[((size_t)k * nsrc + isrc[p2][k]) * F + f], acc);
    const float v = fmaxf(acc, 0.f);
    const size_t o = (size_t)pixg2 * F + f;
    const short h = f2bf(v);
    xhi[o] = h;
    xlo[o] = f2bf(v - bf2f(h));

    if (DO_Y4) {
        xv[p2][f] = v;
        __syncthreads();
        for (int t = tid; t < PPB * 49; t += 256) {
            const int p = t / 49, k = t - p * 49;
            float d = 0.f;
            #pragma unroll
            for (int f2 = 0; f2 < 16; ++f2)
                d = fmaf(xv[p][f2], w4s[k * 16 + f2], d);
            Y4[(size_t)k * npix + blockIdx.x * PPB + p] = d;
        }
    }
}

// ============ stage-4 offset conv via implicit-GEMM MFMA ===============
__global__ __launch_bounds__(256) void k_offmfma4(
    const short* __restrict__ Xbf, const short* __restrict__ OWf,
    float* __restrict__ off,
    const int H, const int W, const int Hp, const int Wp, const int nX)
{
    constexpr int C = 16;
    const int tid = threadIdx.x;
    const int wv = tid >> 6;
    const int l  = tid & 63;
    const int l15 = l & 15, l4 = l >> 4;
    const int cls = blockIdx.y;
    const int pi = cls >> 1, rho = cls & 1;
    const int NRc = pi ? 4 : 3, NCc = rho ? 4 : 3;
    const int T = NRc * NCc;
    const int nkb = (T + 1) >> 1;
    const int clsoff = cls == 0 ? 0 : cls == 1 ? 5 : cls == 2 ? 11 : 17;

    const int Wt16 = W >> 4;
    const int mt = blockIdx.x * 4 + wv;
    const int rloc = mt / Wt16, xt = mt - rloc * Wt16;
    const int b = rloc / H;
    const int ysp = rloc - b * H;

    f32x4 acc[7];
    #pragma unroll
    for (int nt = 0; nt < 7; ++nt) acc[nt] = (f32x4){0.f, 0.f, 0.f, 0.f};

    const bf16x8* Bbase = (const bf16x8*)OWf + ((size_t)clsoff * 7) * 64 + l4 * 16 + l15;

    for (int kb = 0; kb < nkb; ++kb) {
        int tl = kb * 2 + (l4 >> 1);
        const int c0 = (l4 & 1) * 8;
        if (tl >= T) tl = T - 1;
        int iy, ix;
        if (NCc == 4) { iy = tl >> 2; ix = tl & 3; }
        else          { iy = tl / 3;  ix = tl - iy * 3; }
        const int ys = ysp + iy - 1;
        const int xs = xt * 16 + l15 + ix - 1;
        bf16x8 ah = {0, 0, 0, 0, 0, 0, 0, 0};
        bf16x8 al = {0, 0, 0, 0, 0, 0, 0, 0};
        if ((unsigned)ys < (unsigned)H && (unsigned)xs < (unsigned)W) {
            const size_t a = ((size_t)(b * H + ys) * W + xs) * C + c0;
            ah = *(const bf16x8*)(Xbf + a);
            al = *(const bf16x8*)(Xbf + nX + a);
        }
        const bf16x8* Bb = Bbase + (size_t)kb * 7 * 64;
        #pragma unroll
        for (int nt = 0; nt < 7; ++nt) {
            const bf16x8 bf = Bb[nt * 64];
            acc[nt] = __builtin_amdgcn_mfma_f32_16x16x32_bf16(ah, bf, acc[nt], 0, 0, 0);
            acc[nt] = __builtin_amdgcn_mfma_f32_16x16x32_bf16(al, bf, acc[nt], 0, 0, 0);
        }
    }

    const int hp = 2 * ysp + pi;
    const int wpbase = (xt << 5) + rho;
    const int pixrow = (b * Hp + hp) * Wp + wpbase;
    #pragma unroll
    for (int nt = 0; nt < 7; ++nt) {
        const int oc = nt * 16 + l15;
        if (oc < 98) {
            #pragma unroll
            for (int r = 0; r < 4; ++r) {
                const int m = l4 * 4 + r;
                off[(size_t)(pixrow + 2 * m) * 98 + oc] = acc[nt][r];
            }
        }
    }
}

// ============ stage 4: fused sparams + gather-combine via Y4 ===
__global__ __launch_bounds__(256) void k_dconv_f1_y(
    const float* __restrict__ Y4,       // [49][nsrc]
    const float* __restrict__ part,     // [npix, 98] raw offset conv
    const float* __restrict__ OB,       // [98]
    const float* __restrict__ bias, float* __restrict__ out,
    const int H, const int W, const int Hp, const int Wp,
    const int nsrc)
{
    __shared__ float OBs[98];
    const int tid = threadIdx.x;
    if (tid < 98) OBs[tid] = OB[tid];
    __syncthreads();

    const int pixL = blockIdx.x * 64 + (tid >> 2);
    const int tq = tid & 3;
    const int t0 = (tq == 0) ? 0 : 13 + (tq - 1) * 12;
    const int t1 = t0 + ((tq == 0) ? 13 : 12);

    const int HWp = Hp * Wp;
    const int b = pixL / HWp;
    const int rem = pixL - b * HWp;
    const int hp = rem / Wp;
    const int wp = rem - hp * Wp;

    float acc = 0.f;
    for (int k = t0; k < t1; ++k) {
        const float offy = part[(size_t)pixL * 98 + 2 * k]     + OBs[2 * k];
        const float offx = part[(size_t)pixL * 98 + 2 * k + 1] + OBs[2 * k + 1];
        float s; int src;
        d_bilin(offy, offx, hp, wp, b, k, H, W, Hp, Wp, s, src);
        acc = fmaf(s, Y4[(size_t)k * nsrc + src], acc);
    }
    acc += __shfl_xor(acc, 1);
    acc += __shfl_xor(acc, 2);
    if (tq == 0) out[pixL] = acc + bias[0];
}

extern "C" void kernel_launch(void* const* d_in, const int* in_sizes, int n_in,
                              void* d_out, int out_size, void* d_ws, size_t ws_size,
                              hipStream_t stream) {
    const float* z   = (const float*)d_in[0];
    const float* dw  = (const float*)d_in[1];
    const float* db  = (const float*)d_in[2];
    const float* ow1 = (const float*)d_in[3];
    const float* ob1 = (const float*)d_in[4];
    const float* w1  = (const float*)d_in[5];
    const float* b1  = (const float*)d_in[6];
    const float* ow2 = (const float*)d_in[7];
    const float* ob2 = (const float*)d_in[8];
    const float* w2  = (const float*)d_in[9];
    const float* b2  = (const float*)d_in[10];
    const float* ow3 = (const float*)d_in[11];
    const float* ob3 = (const float*)d_in[12];
    const float* w3  = (const float*)d_in[13];
    const float* b3  = (const float*)d_in[14];
    const float* ow4 = (const float*)d_in[15];
    const float* ob4 = (const float*)d_in[16];
    const float* w4  = (const float*)d_in[17];
    const float* b4  = (const float*)d_in[18];

    // workspace layout: ~118 MB, no aliasing (ws_size = 256 MiB)
    float* ws   = (float*)d_ws;
    short* Xf   = (short*)ws;                    // 524,288 sh
    float* Zp   = ws + 262144;                   // 4 x 1,229,312 = 4,917,248
    float* Y1   = Zp + 4917248;                  // 4 x 802,816 = 3,211,264
    float* Y2   = Y1 + 3211264;                  // 1,605,632
    float* Y3   = Y2 + 1605632;                  // 3,211,264
    float* Y4   = Y3 + 3211264;                  // 802,816
    short* Xbf1 = (short*)(Y4 + 802816);         // 131,072 sh
    short* Xbf2 = Xbf1 + 131072;                 // 262,144 sh
    short* Xbf3 = Xbf2 + 262144;                 // 524,288 sh
    float* off2 = (float*)(Xbf3 + 524288);       // 401,408
    float* off3 = off2 + 401408;                 // 1,605,632
    float* off4 = off3 + 1605632;                // 6,422,528
    short* OWbf = (short*)(off4 + 6422528);      // 5,619,712 sh
    short* W1f  = OWbf + 5619712;                // 6,422,528 sh
    short* OWf2 = W1f + 6422528;                 // 351,232 sh
    short* W2f  = OWf2 + 351232;                 // 200,704 sh
    short* OWf3 = W2f + 200704;                  // 175,616 sh
    short* W3f  = OWf3 + 175616;                 // 50,176 sh
    short* OWf4 = W3f + 50176;                   // 89,600 sh

    float* out = (float*)d_out;

    // 1) dense+cvt AND all weight packing (independent, one launch)
    k_prep<<<7294, 256, 0, stream>>>(z, dw, db, Xf, ow1, w1, ow2, w2, ow3, w3, ow4,
                                     OWbf, W1f, OWf2, W2f, OWf3, W3f, OWf4);

    // 2) stage-1 GEMMs (offset + Y, merged; K-split x4, XCD-swizzled)
    k_gemms1<<<dim3(4, 98, 4), 256, 0, stream>>>(Xf, OWbf, W1f, Zp, Y1);

    // 3) stage-1 combine (fused sparams_z1, sums 4 partials) -> Xbf1
    k_combine1<<<256, 256, 0, stream>>>(Y1, Zp, ob1, b1, Xbf1, Xbf1 + 65536);

    // 4) stage-2 GEMMs (offmfma + ygemm, merged)
    k_gemms23<64, 32><<<dim3(16, 53), 256, 0, stream>>>(
        Xbf1, OWf2, W2f, off2, Y2, 16, 32, 32, 64, 1024, 65536);

    // 5) stage-2 combine -> Xbf2
    k_combine23<32, false><<<512, 256, 0, stream>>>(
        Y2, off2, ob2, b2, Xbf2, Xbf2 + 131072, nullptr, nullptr, 4096, 1024, 16, 32, 32, 64);

    // 6) stage-3 GEMMs
    k_gemms23<32, 16><<<dim3(64, 53), 256, 0, stream>>>(
        Xbf2, OWf3, W3f, off3, Y3, 32, 64, 64, 128, 4096, 131072);

    // 7) stage-3 combine + Y4 -> Xbf3, Y4
    k_combine23<16, true><<<1024, 256, 0, stream>>>(
        Y3, off3, ob3, b3, Xbf3, Xbf3 + 262144, w4, Y4, 16384, 4096, 32, 64, 64, 128);

    // 8) stage-4 offset conv
    k_offmfma4<<<dim3(256, 4), 256, 0, stream>>>(Xbf3, OWf4, off4, 64, 128, 128, 256, 262144);

    // 9) stage-4 dconv -> out
    k_dconv_f1_y<<<1024, 256, 0, stream>>>(Y4, off4, ob4, b4, out, 64, 128, 128, 256, 16384);
}

// Round 13
// 137.177 us; speedup vs baseline: 2.3992x; 1.1211x over previous
//
#include <hip/hip_runtime.h>
#include <hip/hip_bf16.h>

#define K49 49

typedef short bf16x8 __attribute__((ext_vector_type(8)));
typedef float f32x4 __attribute__((ext_vector_type(4)));

__device__ __forceinline__ short f2bf(float x) {
    __hip_bfloat16 h = __float2bfloat16(x);
    return __builtin_bit_cast(short, h);
}
__device__ __forceinline__ float bf2f(short s) {
    unsigned u = ((unsigned)(unsigned short)s) << 16;
    return __builtin_bit_cast(float, u);
}

// ==================== weight packing (device fns) ====================
__device__ __forceinline__ void d_pack_ow1(
    const int gid, const float* __restrict__ OW, short* __restrict__ OWbf)
{
    const int ni = gid & 15;
    int t = gid >> 4;
    const int kg = t & 3;  t >>= 2;
    const int kb = t & 31; t >>= 5;
    const int nt = t % 7;
    const int d  = t / 7;
    const int oc = nt * 16 + ni;
    short h[8];
    if (oc < 98) {
        const int c0 = kb * 32 + kg * 8;
        #pragma unroll
        for (int j = 0; j < 8; ++j)
            h[j] = f2bf(OW[((size_t)d * 1024 + c0 + j) * 98 + oc]);
    } else {
        #pragma unroll
        for (int j = 0; j < 8; ++j) h[j] = 0;
    }
    *(bf16x8*)(OWbf + (size_t)gid * 8) = *(bf16x8*)h;
}

template<int C, int F>
__device__ __forceinline__ void d_pack_w(
    const int gid, const float* __restrict__ Wt, short* __restrict__ Wf)
{
    constexpr int KB = C / 32;
    constexpr int NT = F / 16;
    constexpr int PLANE = 49 * NT * KB * 4 * 16 * 8;   // shorts
    const int ni = gid & 15;
    int t = gid >> 4;
    const int kg = t & 3; t >>= 2;
    const int kb = t % KB; t /= KB;
    const int nt = t % NT;
    const int d  = t / NT;
    const int f = nt * 16 + ni;
    const int c0 = kb * 32 + kg * 8;
    short hi[8], lo[8];
    #pragma unroll
    for (int j = 0; j < 8; ++j) {
        const float v = Wt[((size_t)d * C + c0 + j) * F + f];
        hi[j] = f2bf(v);
        lo[j] = f2bf(v - bf2f(hi[j]));
    }
    *(bf16x8*)(Wf + (size_t)gid * 8) = *(bf16x8*)hi;
    *(bf16x8*)(Wf + PLANE + (size_t)gid * 8) = *(bf16x8*)lo;
}

template<int C>
__device__ __forceinline__ void d_pack_owf(
    const int gid, const float* __restrict__ OW, short* __restrict__ OWf)
{
    const int j = gid & 7;
    int t = gid >> 3;
    const int fi = t & 63; t >>= 6;
    const int nt = t % 7;
    const int kbg = t / 7;
    const int ni = fi & 15, kg = fi >> 4;

    int cum1, cum2, cum3;
    if (C == 64)      { cum1 = 18; cum2 = 42; cum3 = 66; }
    else if (C == 32) { cum1 = 9;  cum2 = 21; cum3 = 33; }
    else              { cum1 = 5;  cum2 = 11; cum3 = 17; }
    int cls, kb0;
    if (kbg < cum1)      { cls = 0; kb0 = 0; }
    else if (kbg < cum2) { cls = 1; kb0 = cum1; }
    else if (kbg < cum3) { cls = 2; kb0 = cum2; }
    else                 { cls = 3; kb0 = cum3; }
    const int kbl = kbg - kb0;
    const int pi = cls >> 1, rho = cls & 1;
    const int NRc = pi ? 4 : 3, NCc = rho ? 4 : 3;
    const int T = NRc * NCc;

    const int k = kbl * 32 + kg * 8 + j;
    const int tl = k / C, c = k - tl * C;
    const int oc = nt * 16 + ni;
    float v = 0.f;
    if (tl < T && oc < 98) {
        const int iy = tl / NCc, ix = tl - iy * NCc;
        const int d = (1 - pi + 2 * iy) * 7 + (1 - rho + 2 * ix);
        v = OW[((size_t)d * C + c) * 98 + oc];
    }
    OWf[gid] = f2bf(v);
}

// ==================== mega prep kernel: dense+cvt AND all weight packs =====
// Xf layout (bf16): [plane(2)][mtile(16)][kb(32)][kg(4)][mi(16)][8]
__global__ __launch_bounds__(256) void k_prep(
    const float* __restrict__ z, const float* __restrict__ Wd,
    const float* __restrict__ bd, short* __restrict__ Xf,
    const float* __restrict__ ow1, const float* __restrict__ w1,
    const float* __restrict__ ow2, const float* __restrict__ w2,
    const float* __restrict__ ow3, const float* __restrict__ w3,
    const float* __restrict__ ow4,
    short* OWbf, short* W1f, short* OWf2, short* W2f,
    short* OWf3, short* W3f, short* OWf4)
{
    const int bid0 = blockIdx.x;
    const int tid = threadIdx.x;
    __shared__ float zs[256];
    if (bid0 < 512) {
        const int D = 131072;
        zs[tid] = z[tid];
        __syncthreads();
        const int n = bid0 * 256 + tid;
        const float bb = bd[n];
        float a0 = bb, a1 = bb;
        #pragma unroll 8
        for (int kk = 0; kk < 128; ++kk) {
            const float w = Wd[kk * D + n];
            a0 = fmaf(zs[kk], w, a0);
            a1 = fmaf(zs[128 + kk], w, a1);
        }
        a0 = fmaxf(a0, 0.f);
        a1 = fmaxf(a1, 0.f);
        const int c = n & 1023;
        const int m0 = n >> 10;
        const int kb = c >> 5, kg = (c >> 3) & 3, j = c & 7;
        const size_t base = ((size_t)kb * 4 + kg) * 16 * 8 + j;
        {
            const size_t dst = ((size_t)(m0 >> 4) * 2048) * 8 + base + (size_t)(m0 & 15) * 8;
            const short h = f2bf(a0);
            Xf[dst] = h;
            Xf[262144 + dst] = f2bf(a0 - bf2f(h));
        }
        {
            const int m1 = m0 + 128;
            const size_t dst = ((size_t)(m1 >> 4) * 2048) * 8 + base + (size_t)(m1 & 15) * 8;
            const short h = f2bf(a1);
            Xf[dst] = h;
            Xf[262144 + dst] = f2bf(a1 - bf2f(h));
        }
        return;
    }
    const int bid = bid0 - 512;
    if (bid < 2744)      d_pack_ow1((bid) * 256 + tid, ow1, OWbf);
    else if (bid < 4312) d_pack_w<1024, 64>((bid - 2744) * 256 + tid, w1, W1f);
    else if (bid < 5684) d_pack_owf<64>((bid - 4312) * 256 + tid, ow2, OWf2);
    else if (bid < 5733) d_pack_w<64, 32>((bid - 5684) * 256 + tid, w2, W2f);
    else if (bid < 6419) d_pack_owf<32>((bid - 5733) * 256 + tid, ow3, OWf3);
    else if (bid < 6432) { const int g = (bid - 6419) * 256 + tid; if (g < 3136) d_pack_w<32, 16>(g, w3, W3f); }
    else                 d_pack_owf<16>((bid - 6432) * 256 + tid, ow4, OWf4);
}

// ============ stage-1 GEMMs, K-split x4 + XCD swizzle: grid (4, 98, 4) =====
// Zp partial: [ks][49][256][98]; Y1 partial: [ks][49][256][64]
__global__ __launch_bounds__(256) void k_gemms1(
    const short* __restrict__ Xf, const short* __restrict__ OWbf,
    const short* __restrict__ W1f,
    float* __restrict__ Zp, float* __restrict__ Y1)
{
    const int tid = threadIdx.x;
    const int wv = tid >> 6;
    const int l  = tid & 63;
    const int l15 = l & 15, l4 = l >> 4;

    // XCD-aware swizzle: 4 M-sibling blocks (same B-slice) -> same XCD
    const int wid = blockIdx.x + 4 * (blockIdx.y + 98 * blockIdx.z);  // 0..1567
    const int work = (wid & 7) * 196 + (wid >> 3);
    const int x    = work & 3;
    const int rest = work >> 2;          // 0..391
    const int ks   = rest / 98;
    const int by   = rest - ks * 98;

    const int mtile = x * 4 + wv;
    const int kb0 = ks * 8;

    const bf16x8* Ah = (const bf16x8*)Xf + (size_t)mtile * 2048 + l4 * 16 + l15;
    const bf16x8* Al = Ah + 32768;
    const int m0 = mtile * 16 + l4 * 4;

    if (by < 49) {
        const int d = by;
        const bf16x8* Bb = (const bf16x8*)OWbf + (size_t)d * 7 * 2048 + l4 * 16 + l15;
        f32x4 acc[7];
        #pragma unroll
        for (int nt = 0; nt < 7; ++nt) acc[nt] = (f32x4){0.f, 0.f, 0.f, 0.f};
        #pragma unroll
        for (int i = 0; i < 8; ++i) {
            const int kb = kb0 + i;
            const bf16x8 ah = Ah[kb * 64];
            const bf16x8 al = Al[kb * 64];
            #pragma unroll
            for (int nt = 0; nt < 7; ++nt) {
                const bf16x8 b = Bb[(size_t)nt * 2048 + kb * 64];
                acc[nt] = __builtin_amdgcn_mfma_f32_16x16x32_bf16(ah, b, acc[nt], 0, 0, 0);
                acc[nt] = __builtin_amdgcn_mfma_f32_16x16x32_bf16(al, b, acc[nt], 0, 0, 0);
            }
        }
        float* Zo = Zp + (size_t)ks * 1229312;
        #pragma unroll
        for (int nt = 0; nt < 7; ++nt) {
            const int oc = nt * 16 + l15;
            if (oc < 98) {
                #pragma unroll
                for (int r = 0; r < 4; ++r)
                    Zo[((size_t)d * 256 + m0 + r) * 98 + oc] = acc[nt][r];
            }
        }
    } else {
        const int d = by - 49;
        const bf16x8* Bh = (const bf16x8*)W1f + (size_t)d * 4 * 2048 + l4 * 16 + l15;
        const bf16x8* Bl = Bh + 401408;
        f32x4 acc[4];
        #pragma unroll
        for (int nt = 0; nt < 4; ++nt) acc[nt] = (f32x4){0.f, 0.f, 0.f, 0.f};
        #pragma unroll
        for (int i = 0; i < 8; ++i) {
            const int kb = kb0 + i;
            const bf16x8 ah = Ah[kb * 64];
            const bf16x8 al = Al[kb * 64];
            #pragma unroll
            for (int nt = 0; nt < 4; ++nt) {
                const bf16x8 bh = Bh[nt * 2048 + kb * 64];
                const bf16x8 bl = Bl[nt * 2048 + kb * 64];
                acc[nt] = __builtin_amdgcn_mfma_f32_16x16x32_bf16(ah, bh, acc[nt], 0, 0, 0);
                acc[nt] = __builtin_amdgcn_mfma_f32_16x16x32_bf16(ah, bl, acc[nt], 0, 0, 0);
                acc[nt] = __builtin_amdgcn_mfma_f32_16x16x32_bf16(al, bh, acc[nt], 0, 0, 0);
            }
        }
        float* Yo = Y1 + (size_t)ks * 802816;
        #pragma unroll
        for (int nt = 0; nt < 4; ++nt) {
            const int f = nt * 16 + l15;
            #pragma unroll
            for (int r = 0; r < 4; ++r)
                Yo[((size_t)d * 256 + m0 + r) * 64 + f] = acc[nt][r];
        }
    }
}

// ============ sparams device fn ============
__device__ __forceinline__ void d_bilin(
    const float accy, const float accx, const int hp, const int wp,
    const int b, const int k, const int H, const int W, const int Hp, const int Wp,
    float& s_out, int& src_out)
{
    const float y = (float)(hp + (k / 7) - 3) + accy;
    const float x = (float)(wp + (k % 7) - 3) + accx;
    const float fy0 = floorf(y), fx0 = floorf(x);
    const int iy0 = (int)fy0, ix0 = (int)fx0;
    const float wy1 = y - fy0, wx1 = x - fx0;
    int ye, xe; float wy, wx;
    if (iy0 & 1) { ye = iy0 + 1; wy = wy1; } else { ye = iy0; wy = 1.f - wy1; }
    if (ix0 & 1) { xe = ix0 + 1; wx = wx1; } else { xe = ix0; wx = 1.f - wx1; }
    float s = wy * wx;
    int src = 0;
    if (ye >= 0 && ye < Hp && xe >= 0 && xe < Wp)
        src = (b * H + (ye >> 1)) * W + (xe >> 1);
    else
        s = 0.f;
    s_out = s;
    src_out = src;
}

// ============ stage-1 combine (fused sparams_z1, 4 partials) ============
__global__ __launch_bounds__(256) void k_combine1(
    const float* __restrict__ Y, const float* __restrict__ Zp,
    const float* __restrict__ OB, const float* __restrict__ bias,
    short* __restrict__ xhi, short* __restrict__ xlo)
{
    __shared__ float ss[4][49];
    __shared__ int   isrc[4][49];
    const int tid = threadIdx.x;

    if (tid < 196) {
        const int p = tid / 49, k = tid - p * 49;
        const int pixg = blockIdx.x * 4 + p;
        const int b   = pixg >> 9;
        const int rem = pixg & 511;
        const int hp  = rem >> 5;
        const int wp  = rem & 31;
        float accy = OB[2 * k], accx = OB[2 * k + 1];
        const int di0 = (hp + 1) & 1, dj0 = (wp + 1) & 1;
        for (int di = di0; di < 7; di += 2) {
            const int yp = hp + di - 3;
            if ((unsigned)yp >= 16u) continue;
            const int ys = yp >> 1;
            for (int dj = dj0; dj < 7; dj += 2) {
                const int xp = wp + dj - 3;
                if ((unsigned)xp >= 32u) continue;
                const int xs = xp >> 1;
                const size_t o = ((size_t)((di * 7 + dj) * 256 + (b * 8 + ys) * 16 + xs)) * 98 + 2 * k;
                accy += (Zp[o] + Zp[o + 1229312]) + (Zp[o + 2458624] + Zp[o + 3687936]);
                accx += (Zp[o + 1] + Zp[o + 1229313]) + (Zp[o + 2458625] + Zp[o + 3687937]);
            }
        }
        d_bilin(accy, accx, hp, wp, b, k, 8, 16, 16, 32, ss[p][k], isrc[p][k]);
    }
    __syncthreads();

    const int f = tid & 63;
    const int p = tid >> 6;
    const int pixg = blockIdx.x * 4 + p;
    float acc = bias[f];
    #pragma unroll 7
    for (int k = 0; k < K49; ++k) {
        const size_t yo = ((size_t)k * 256 + isrc[p][k]) * 64 + f;
        const float yv = (Y[yo] + Y[yo + 802816]) + (Y[yo + 1605632] + Y[yo + 2408448]);
        acc = fmaf(ss[p][k], yv, acc);
    }
    const float v = fmaxf(acc, 0.f);
    const size_t o = (size_t)pixg * 64 + f;
    const short h = f2bf(v);
    xhi[o] = h;
    xlo[o] = f2bf(v - bf2f(h));
}

// ============ stages 2-3 GEMMs merged (offmfma + ygemm23): grid (gx, 53) ====
template<int C, int F>
__global__ __launch_bounds__(256) void k_gemms23(
    const short* __restrict__ Xbf, const short* __restrict__ OWf,
    const short* __restrict__ Wf,
    float* __restrict__ off, float* __restrict__ Y,
    const int H, const int W, const int Hp, const int Wp,
    const int M, const int nX)
{
    const int tid = threadIdx.x;
    const int wv = tid >> 6;
    const int l  = tid & 63;
    const int l15 = l & 15, l4 = l >> 4;
    const int by = blockIdx.y;

    if (by < 4) {
        const int cls = by;
        const int pi = cls >> 1, rho = cls & 1;
        const int NRc = pi ? 4 : 3, NCc = rho ? 4 : 3;
        const int T = NRc * NCc;
        int nkb, clsoff;
        if (C == 64) { nkb = T * 2; clsoff = cls == 0 ? 0 : cls == 1 ? 18 : cls == 2 ? 42 : 66; }
        else         { nkb = T;     clsoff = cls == 0 ? 0 : cls == 1 ? 9  : cls == 2 ? 21 : 33; }

        const int Wt16 = W >> 4;
        const int mt = blockIdx.x * 4 + wv;
        const int rloc = mt / Wt16, xt = mt - rloc * Wt16;
        const int b = rloc / H;
        const int ysp = rloc - b * H;

        f32x4 acc[7];
        #pragma unroll
        for (int nt = 0; nt < 7; ++nt) acc[nt] = (f32x4){0.f, 0.f, 0.f, 0.f};

        const bf16x8* Bbase = (const bf16x8*)OWf + ((size_t)clsoff * 7) * 64 + l4 * 16 + l15;

        for (int kb = 0; kb < nkb; ++kb) {
            int tl, c0;
            if (C == 64) { tl = kb >> 1; c0 = ((kb & 1) << 5) + l4 * 8; }
            else         { tl = kb;      c0 = l4 * 8; }
            int iy, ix;
            if (NCc == 4) { iy = tl >> 2; ix = tl & 3; }
            else          { iy = tl / 3;  ix = tl - iy * 3; }
            const int ys = ysp + iy - 1;
            const int xs = xt * 16 + l15 + ix - 1;
            bf16x8 ah = {0, 0, 0, 0, 0, 0, 0, 0};
            bf16x8 al = {0, 0, 0, 0, 0, 0, 0, 0};
            if ((unsigned)ys < (unsigned)H && (unsigned)xs < (unsigned)W) {
                const size_t a = ((size_t)(b * H + ys) * W + xs) * C + c0;
                ah = *(const bf16x8*)(Xbf + a);
                al = *(const bf16x8*)(Xbf + nX + a);
            }
            const bf16x8* Bb = Bbase + (size_t)kb * 7 * 64;
            #pragma unroll
            for (int nt = 0; nt < 7; ++nt) {
                const bf16x8 bf = Bb[nt * 64];
                acc[nt] = __builtin_amdgcn_mfma_f32_16x16x32_bf16(ah, bf, acc[nt], 0, 0, 0);
                acc[nt] = __builtin_amdgcn_mfma_f32_16x16x32_bf16(al, bf, acc[nt], 0, 0, 0);
            }
        }

        const int hp = 2 * ysp + pi;
        const int wpbase = (xt << 5) + rho;
        const int pixrow = (b * Hp + hp) * Wp + wpbase;
        #pragma unroll
        for (int nt = 0; nt < 7; ++nt) {
            const int oc = nt * 16 + l15;
            if (oc < 98) {
                #pragma unroll
                for (int r = 0; r < 4; ++r) {
                    const int m = l4 * 4 + r;
                    off[(size_t)(pixrow + 2 * m) * 98 + oc] = acc[nt][r];
                }
            }
        }
    } else {
        constexpr int KB = C / 32;
        constexpr int NT = F / 16;
        constexpr int PLANEFRAG = 49 * NT * KB * 64;
        const int d = by - 4;
        const int mtile = blockIdx.x * 4 + wv;
        const short* Arow = Xbf + (size_t)(mtile * 16 + l15) * C + l4 * 8;

        f32x4 acc[NT];
        #pragma unroll
        for (int nt = 0; nt < NT; ++nt) acc[nt] = (f32x4){0.f, 0.f, 0.f, 0.f};

        #pragma unroll
        for (int kb = 0; kb < KB; ++kb) {
            const bf16x8 ah = *(const bf16x8*)(Arow + kb * 32);
            const bf16x8 al = *(const bf16x8*)(Arow + nX + kb * 32);
            #pragma unroll
            for (int nt = 0; nt < NT; ++nt) {
                const size_t fi = ((size_t)(d * NT + nt) * KB + kb) * 64 + l4 * 16 + l15;
                const bf16x8 bh = ((const bf16x8*)Wf)[fi];
                const bf16x8 bl = ((const bf16x8*)Wf)[fi + PLANEFRAG];
                acc[nt] = __builtin_amdgcn_mfma_f32_16x16x32_bf16(ah, bh, acc[nt], 0, 0, 0);
                acc[nt] = __builtin_amdgcn_mfma_f32_16x16x32_bf16(ah, bl, acc[nt], 0, 0, 0);
                acc[nt] = __builtin_amdgcn_mfma_f32_16x16x32_bf16(al, bh, acc[nt], 0, 0, 0);
            }
        }

        const int m0 = mtile * 16 + l4 * 4;
        #pragma unroll
        for (int nt = 0; nt < NT; ++nt) {
            const int f = nt * 16 + l15;
            #pragma unroll
            for (int r = 0; r < 4; ++r)
                Y[((size_t)d * M + m0 + r) * F + f] = acc[nt][r];
        }
    }
}

// ============ stages 2-3 combine (fused sparams, optional Y4) ============
template<int F, bool DO_Y4>
__global__ __launch_bounds__(256) void k_combine23(
    const float* __restrict__ Y, const float* __restrict__ off,
    const float* __restrict__ OB, const float* __restrict__ bias,
    short* __restrict__ xhi, short* __restrict__ xlo,
    const float* __restrict__ w4, float* __restrict__ Y4,
    const int npix, const int nsrc,
    const int H, const int W, const int Hp, const int Wp)
{
    constexpr int PPB = 256 / F;
    __shared__ float ss[PPB][49];
    __shared__ int   isrc[PPB][49];
    __shared__ float xv[DO_Y4 ? PPB : 1][DO_Y4 ? 17 : 1];
    __shared__ float w4s[DO_Y4 ? 784 : 1];
    const int tid = threadIdx.x;
    const int HWp = Hp * Wp;

    if (DO_Y4) {
        for (int t = tid; t < 784; t += 256) w4s[t] = w4[t];
    }
    for (int t = tid; t < PPB * 49; t += 256) {
        const int p = t / 49, k = t - p * 49;
        const int pixg = blockIdx.x * PPB + p;
        const float accy = OB[2 * k]     + off[(size_t)pixg * 98 + 2 * k];
        const float accx = OB[2 * k + 1] + off[(size_t)pixg * 98 + 2 * k + 1];
        const int b = pixg / HWp;
        const int rem = pixg - b * HWp;
        const int hp = rem / Wp;
        const int wp = rem - hp * Wp;
        d_bilin(accy, accx, hp, wp, b, k, H, W, Hp, Wp, ss[p][k], isrc[p][k]);
    }
    __syncthreads();

    const int f = tid % F;
    const int p2 = tid / F;
    const int pixg2 = blockIdx.x * PPB + p2;
    float acc = bias[f];
    #pragma unroll 7
    for (int k = 0; k < K49; ++k)
        acc = fmaf(ss[p2][k], Y[((size_t)k * nsrc + isrc[p2][k]) * F + f], acc);
    const float v = fmaxf(acc, 0.f);
    const size_t o = (size_t)pixg2 * F + f;
    const short h = f2bf(v);
    xhi[o] = h;
    xlo[o] = f2bf(v - bf2f(h));

    if (DO_Y4) {
        xv[p2][f] = v;
        __syncthreads();
        for (int t = tid; t < PPB * 49; t += 256) {
            const int p = t / 49, k = t - p * 49;
            float d = 0.f;
            #pragma unroll
            for (int f2 = 0; f2 < 16; ++f2)
                d = fmaf(xv[p][f2], w4s[k * 16 + f2], d);
            Y4[(size_t)k * npix + blockIdx.x * PPB + p] = d;
        }
    }
}

// ============ stage 4 FUSED: implicit-GEMM offsets (LDS) + sparams + dconv ==
// grid (256, 4); block handles 64 pixels of one parity class.
__global__ __launch_bounds__(256) void k_stage4(
    const short* __restrict__ Xbf, const short* __restrict__ OWf,
    const float* __restrict__ Y4,       // [49][nsrc]
    const float* __restrict__ OB, const float* __restrict__ bias,
    float* __restrict__ out, const int nX)
{
    constexpr int C = 16, H = 64, W = 128, Hp = 128, Wp = 256;
    __shared__ float offs[64][98];
    __shared__ float OBs[98];

    const int tid = threadIdx.x;
    const int wv = tid >> 6;
    const int l  = tid & 63;
    const int l15 = l & 15, l4 = l >> 4;
    const int cls = blockIdx.y;
    const int pi = cls >> 1, rho = cls & 1;
    const int NRc = pi ? 4 : 3, NCc = rho ? 4 : 3;
    const int T = NRc * NCc;
    const int nkb = (T + 1) >> 1;
    const int clsoff = cls == 0 ? 0 : cls == 1 ? 5 : cls == 2 ? 11 : 17;

    if (tid < 98) OBs[tid] = OB[tid];

    // ---- phase 1: implicit-GEMM MFMA, acc -> LDS ----
    const int mt = blockIdx.x * 4 + wv;
    const int rloc = mt >> 3, xt = mt & 7;     // Wt16 = 8
    const int b = rloc / H;
    const int ysp = rloc - b * H;

    f32x4 acc[7];
    #pragma unroll
    for (int nt = 0; nt < 7; ++nt) acc[nt] = (f32x4){0.f, 0.f, 0.f, 0.f};

    const bf16x8* Bbase = (const bf16x8*)OWf + ((size_t)clsoff * 7) * 64 + l4 * 16 + l15;

    for (int kb = 0; kb < nkb; ++kb) {
        int tl = kb * 2 + (l4 >> 1);
        const int c0 = (l4 & 1) * 8;
        if (tl >= T) tl = T - 1;               // B is zero there; A clamp for bounds only
        int iy, ix;
        if (NCc == 4) { iy = tl >> 2; ix = tl & 3; }
        else          { iy = tl / 3;  ix = tl - iy * 3; }
        const int ys = ysp + iy - 1;
        const int xs = xt * 16 + l15 + ix - 1;
        bf16x8 ah = {0, 0, 0, 0, 0, 0, 0, 0};
        bf16x8 al = {0, 0, 0, 0, 0, 0, 0, 0};
        if ((unsigned)ys < (unsigned)H && (unsigned)xs < (unsigned)W) {
            const size_t a = ((size_t)(b * H + ys) * W + xs) * C + c0;
            ah = *(const bf16x8*)(Xbf + a);
            al = *(const bf16x8*)(Xbf + nX + a);
        }
        const bf16x8* Bb = Bbase + (size_t)kb * 7 * 64;
        #pragma unroll
        for (int nt = 0; nt < 7; ++nt) {
            const bf16x8 bf = Bb[nt * 64];
            acc[nt] = __builtin_amdgcn_mfma_f32_16x16x32_bf16(ah, bf, acc[nt], 0, 0, 0);
            acc[nt] = __builtin_amdgcn_mfma_f32_16x16x32_bf16(al, bf, acc[nt], 0, 0, 0);
        }
    }

    #pragma unroll
    for (int nt = 0; nt < 7; ++nt) {
        const int oc = nt * 16 + l15;
        if (oc < 98) {
            #pragma unroll
            for (int r = 0; r < 4; ++r)
                offs[wv * 16 + l4 * 4 + r][oc] = acc[nt][r];
        }
    }
    __syncthreads();

    // ---- phase 2: sparams + gather-combine (4 lanes per pixel) ----
    const int p  = tid >> 2;                   // 0..63 block-local pixel
    const int tq = tid & 3;
    const int t0 = (tq == 0) ? 0 : 13 + (tq - 1) * 12;
    const int t1 = t0 + ((tq == 0) ? 13 : 12);

    const int wv_p = p >> 4;
    const int m_p  = p & 15;
    const int mt_p = blockIdx.x * 4 + wv_p;
    const int rloc_p = mt_p >> 3, xt_p = mt_p & 7;
    const int b_p = rloc_p / H;
    const int ysp_p = rloc_p - b_p * H;
    const int hp = 2 * ysp_p + pi;
    const int wp = (xt_p << 5) + rho + 2 * m_p;
    const int pixg = (b_p * Hp + hp) * Wp + wp;

    float acc2 = 0.f;
    for (int k = t0; k < t1; ++k) {
        const float offy = offs[p][2 * k]     + OBs[2 * k];
        const float offx = offs[p][2 * k + 1] + OBs[2 * k + 1];
        float s; int src;
        d_bilin(offy, offx, hp, wp, b_p, k, H, W, Hp, Wp, s, src);
        acc2 = fmaf(s, Y4[(size_t)k * 16384 + src], acc2);
    }
    acc2 += __shfl_xor(acc2, 1);
    acc2 += __shfl_xor(acc2, 2);
    if (tq == 0) out[pixg] = acc2 + bias[0];
}

extern "C" void kernel_launch(void* const* d_in, const int* in_sizes, int n_in,
                              void* d_out, int out_size, void* d_ws, size_t ws_size,
                              hipStream_t stream) {
    const float* z   = (const float*)d_in[0];
    const float* dw  = (const float*)d_in[1];
    const float* db  = (const float*)d_in[2];
    const float* ow1 = (const float*)d_in[3];
    const float* ob1 = (const float*)d_in[4];
    const float* w1  = (const float*)d_in[5];
    const float* b1  = (const float*)d_in[6];
    const float* ow2 = (const float*)d_in[7];
    const float* ob2 = (const float*)d_in[8];
    const float* w2  = (const float*)d_in[9];
    const float* b2  = (const float*)d_in[10];
    const float* ow3 = (const float*)d_in[11];
    const float* ob3 = (const float*)d_in[12];
    const float* w3  = (const float*)d_in[13];
    const float* b3  = (const float*)d_in[14];
    const float* ow4 = (const float*)d_in[15];
    const float* ob4 = (const float*)d_in[16];
    const float* w4  = (const float*)d_in[17];
    const float* b4  = (const float*)d_in[18];

    // workspace layout: ~92 MB, no aliasing (ws_size = 256 MiB)
    float* ws   = (float*)d_ws;
    short* Xf   = (short*)ws;                    // 524,288 sh
    float* Zp   = ws + 262144;                   // 4 x 1,229,312 = 4,917,248
    float* Y1   = Zp + 4917248;                  // 4 x 802,816 = 3,211,264
    float* Y2   = Y1 + 3211264;                  // 1,605,632
    float* Y3   = Y2 + 1605632;                  // 3,211,264
    float* Y4   = Y3 + 3211264;                  // 802,816
    short* Xbf1 = (short*)(Y4 + 802816);         // 131,072 sh
    short* Xbf2 = Xbf1 + 131072;                 // 262,144 sh
    short* Xbf3 = Xbf2 + 262144;                 // 524,288 sh
    float* off2 = (float*)(Xbf3 + 524288);       // 401,408
    float* off3 = off2 + 401408;                 // 1,605,632
    short* OWbf = (short*)(off3 + 1605632);      // 5,619,712 sh
    short* W1f  = OWbf + 5619712;                // 6,422,528 sh
    short* OWf2 = W1f + 6422528;                 // 351,232 sh
    short* W2f  = OWf2 + 351232;                 // 200,704 sh
    short* OWf3 = W2f + 200704;                  // 175,616 sh
    short* W3f  = OWf3 + 175616;                 // 50,176 sh
    short* OWf4 = W3f + 50176;                   // 89,600 sh

    float* out = (float*)d_out;

    // 1) dense+cvt AND all weight packing (independent, one launch)
    k_prep<<<7294, 256, 0, stream>>>(z, dw, db, Xf, ow1, w1, ow2, w2, ow3, w3, ow4,
                                     OWbf, W1f, OWf2, W2f, OWf3, W3f, OWf4);

    // 2) stage-1 GEMMs (offset + Y, merged; K-split x4, XCD-swizzled)
    k_gemms1<<<dim3(4, 98, 4), 256, 0, stream>>>(Xf, OWbf, W1f, Zp, Y1);

    // 3) stage-1 combine (fused sparams_z1, sums 4 partials) -> Xbf1
    k_combine1<<<256, 256, 0, stream>>>(Y1, Zp, ob1, b1, Xbf1, Xbf1 + 65536);

    // 4) stage-2 GEMMs (offmfma + ygemm, merged)
    k_gemms23<64, 32><<<dim3(16, 53), 256, 0, stream>>>(
        Xbf1, OWf2, W2f, off2, Y2, 16, 32, 32, 64, 1024, 65536);

    // 5) stage-2 combine -> Xbf2
    k_combine23<32, false><<<512, 256, 0, stream>>>(
        Y2, off2, ob2, b2, Xbf2, Xbf2 + 131072, nullptr, nullptr, 4096, 1024, 16, 32, 32, 64);

    // 6) stage-3 GEMMs
    k_gemms23<32, 16><<<dim3(64, 53), 256, 0, stream>>>(
        Xbf2, OWf3, W3f, off3, Y3, 32, 64, 64, 128, 4096, 131072);

    // 7) stage-3 combine + Y4 -> Xbf3, Y4
    k_combine23<16, true><<<1024, 256, 0, stream>>>(
        Y3, off3, ob3, b3, Xbf3, Xbf3 + 262144, w4, Y4, 16384, 4096, 32, 64, 64, 128);

    // 8) stage-4 fused: offsets (MFMA->LDS) + sparams + dconv -> out
    k_stage4<<<dim3(256, 4), 256, 0, stream>>>(Xbf3, OWf4, Y4, ob4, b4, out, 262144);
}